// Round 6
// baseline (261.429 us; speedup 1.0000x reference)
//
#include <hip/hip_runtime.h>

#define N_NODES 10000
#define E_EDGES 160000
#define IN_DIM  512
#define HID_DIM 512
#define OUT_DIM 256

typedef __attribute__((ext_vector_type(8))) short short8;
typedef __attribute__((ext_vector_type(4))) float f32x4;
typedef __attribute__((ext_vector_type(16))) float f32x16;
typedef unsigned short u16;

__device__ __forceinline__ u16 f2bh(float f) {
  union { float f; unsigned u; } v; v.f = f;
  return (u16)((v.u + 0x7FFFu + ((v.u >> 16) & 1u)) >> 16);
}
__device__ __forceinline__ float bh2f(u16 h) {
  union { unsigned u; float f; } v; v.u = ((unsigned)h) << 16;
  return v.f;
}

// async global->LDS: 16B per lane, dest = wave-uniform base + lane*16
#define GL_LDS(gsrc, ldst)                                                      \
  __builtin_amdgcn_global_load_lds(                                             \
      (const __attribute__((address_space(1))) unsigned int*)(gsrc),            \
      (__attribute__((address_space(3))) unsigned int*)(ldst), 16, 0, 0)

// ===========================================================================
// CSR build: count -> exclusive scan (+dis) -> place
// ===========================================================================
__global__ void count_kernel(const int* __restrict__ dst, int* __restrict__ cnt) {
  int e = blockIdx.x * 256 + threadIdx.x;
  if (e < E_EDGES) atomicAdd(&cnt[dst[e]], 1);
}

__global__ __launch_bounds__(1024) void scan_kernel(
    int* __restrict__ cnt, int* __restrict__ row, float* __restrict__ dis) {
  __shared__ int sums[1024];
  const int CH = 10;
  int t = threadIdx.x;
  int c[CH], excl[CH];
  int s = 0;
#pragma unroll
  for (int j = 0; j < CH; ++j) {
    int idx = t * CH + j;
    c[j] = (idx < N_NODES) ? cnt[idx] : 0;
    excl[j] = s;
    s += c[j];
  }
  sums[t] = s;
  __syncthreads();
  for (int off = 1; off < 1024; off <<= 1) {
    int v = (t >= off) ? sums[t - off] : 0;
    __syncthreads();
    if (t >= off) sums[t] += v;
    __syncthreads();
  }
  int base = (t == 0) ? 0 : sums[t - 1];
#pragma unroll
  for (int j = 0; j < CH; ++j) {
    int idx = t * CH + j;
    if (idx < N_NODES) {
      int start = base + excl[j];
      row[idx] = start;
      cnt[idx] = start;  // cursor
      dis[idx] = rsqrtf((float)c[j] + 1.0f);
    }
  }
  if (t == 1023) row[N_NODES] = sums[1023];
}

__global__ void place_kernel(const int* __restrict__ src, const int* __restrict__ dst,
                             int* __restrict__ cursor, int* __restrict__ col) {
  int e = blockIdx.x * 256 + threadIdx.x;
  if (e < E_EDGES) {
    int pos = atomicAdd(&cursor[dst[e]], 1);
    col[pos] = src[e];
  }
}

// ===========================================================================
// fp32 -> bf16 hi/lo elementwise (for x)
// ===========================================================================
__global__ void conv_bf_kernel(const float* __restrict__ in, u16* __restrict__ hi,
                               u16* __restrict__ lo, int n4) {
  int idx = blockIdx.x * 256 + threadIdx.x;
  if (idx >= n4) return;
  float4 v = reinterpret_cast<const float4*>(in)[idx];
  float a[4] = {v.x, v.y, v.z, v.w};
  ushort4 h4, l4;
  u16* hp = &h4.x; u16* lp = &l4.x;
#pragma unroll
  for (int j = 0; j < 4; ++j) {
    u16 hh = f2bh(a[j]);
    hp[j] = hh;
    lp[j] = f2bh(a[j] - bh2f(hh));
  }
  reinterpret_cast<ushort4*>(hi)[idx] = h4;
  reinterpret_cast<ushort4*>(lo)[idx] = l4;
}

// ===========================================================================
// GIN aggregation (gather), writes agg directly as bf16 hi/lo
// ===========================================================================
__global__ __launch_bounds__(128) void gin_gather_bf(
    const float* __restrict__ x, const int* __restrict__ row,
    const int* __restrict__ col, u16* __restrict__ agg_hi,
    u16* __restrict__ agg_lo) {
  int i = blockIdx.x, t = threadIdx.x;
  int beg = row[i], end = row[i + 1];
  float4 acc{0.f, 0.f, 0.f, 0.f};
  for (int e = beg; e < end; ++e) {
    int s = col[e];
    float4 v = *reinterpret_cast<const float4*>(x + (size_t)s * IN_DIM + t * 4);
    acc.x += v.x; acc.y += v.y; acc.z += v.z; acc.w += v.w;
  }
  float a[4] = {acc.x, acc.y, acc.z, acc.w};
  ushort4 h4, l4;
  u16* hp = &h4.x; u16* lp = &l4.x;
#pragma unroll
  for (int j = 0; j < 4; ++j) {
    u16 hh = f2bh(a[j]);
    hp[j] = hh;
    lp[j] = f2bh(a[j] - bh2f(hh));
  }
  size_t o = (size_t)i * IN_DIM / 4 + t;
  reinterpret_cast<ushort4*>(agg_hi)[o] = h4;
  reinterpret_cast<ushort4*>(agg_lo)[o] = l4;
}

// ===========================================================================
// GCN aggregation (gather) fused with self-loop + bias
// ===========================================================================
__global__ __launch_bounds__(64) void gcn_gather_kernel(
    const float* __restrict__ h, const int* __restrict__ row,
    const int* __restrict__ col, const float* __restrict__ dis,
    const float* __restrict__ gcn_b, float* __restrict__ outg) {
  int i = blockIdx.x, t = threadIdx.x;
  int beg = row[i], end = row[i + 1];
  float di = dis[i];
  float4 acc{0.f, 0.f, 0.f, 0.f};
  for (int e = beg; e < end; ++e) {
    int s = col[e];
    float w = dis[s];
    float4 v = *reinterpret_cast<const float4*>(h + (size_t)s * OUT_DIM + t * 4);
    acc.x += w * v.x; acc.y += w * v.y; acc.z += w * v.z; acc.w += w * v.w;
  }
  float4 hv = *reinterpret_cast<const float4*>(h + (size_t)i * OUT_DIM + t * 4);
  float4 bv = *reinterpret_cast<const float4*>(gcn_b + t * 4);
  float self = di * di;
  float4 o{di * acc.x + self * hv.x + bv.x, di * acc.y + self * hv.y + bv.y,
           di * acc.z + self * hv.z + bv.z, di * acc.w + self * hv.w + bv.w};
  *reinterpret_cast<float4*>(outg + (size_t)i * OUT_DIM + t * 4) = o;
}

// ===========================================================================
// Weight transpose + split, LDS-tiled (coalesced both sides):
// W [K][N] fp32 -> Wt_hi/lo [N][K] bf16.  Grid (K/64, N/64), 256 thr.
// ===========================================================================
__global__ __launch_bounds__(256) void convT_kernel3(
    const float* __restrict__ W, u16* __restrict__ hi, u16* __restrict__ lo,
    int K, int N) {
  __shared__ float tile[64][65];
  int k0 = blockIdx.x * 64, n0 = blockIdx.y * 64;
  int t = threadIdx.x;
  int lk = t >> 4, ln = (t & 15) * 4;
#pragma unroll
  for (int p = 0; p < 4; ++p) {
    float4 v = *reinterpret_cast<const float4*>(W + (size_t)(k0 + p * 16 + lk) * N + n0 + ln);
    tile[p * 16 + lk][ln + 0] = v.x;
    tile[p * 16 + lk][ln + 1] = v.y;
    tile[p * 16 + lk][ln + 2] = v.z;
    tile[p * 16 + lk][ln + 3] = v.w;
  }
  __syncthreads();
  int on = t >> 2;         // 0..63
  int ok = (t & 3) * 16;   // 0,16,32,48
  u16* hp = hi + (size_t)(n0 + on) * K + k0 + ok;
  u16* lp = lo + (size_t)(n0 + on) * K + k0 + ok;
#pragma unroll
  for (int q = 0; q < 4; ++q) {
    ushort4 h4, l4;
    u16* hq = &h4.x; u16* lq = &l4.x;
#pragma unroll
    for (int j = 0; j < 4; ++j) {
      float v = tile[ok + q * 4 + j][on];
      u16 hh = f2bh(v);
      hq[j] = hh;
      lq[j] = f2bh(v - bh2f(hh));
    }
    *reinterpret_cast<ushort4*>(hp + q * 4) = h4;
    *reinterpret_cast<ushort4*>(lp + q * 4) = l4;
  }
}

// ===========================================================================
// Split-bf16 MFMA GEMM v3: all-bf16 inputs, global_load_lds staging,
// double-buffered LDS, BM=64 BN=64 BK=32, 4 waves 2x2 (32x32 tile each).
// LDS chunk layout per plane: c = mt*128 + si*64 + kh*32 + lr  (16B chunks).
// Stage: wave w -> chunks [w*64, w*64+64) of each plane (lane-linear DMA).
// A source: k<kSplit from (Ah0,Al0) lda=kSplit else (Ah1,Al1) lda=K-kSplit.
// Output: fp32 C (+bias) or bf16 hi/lo pair (+bias).
// ===========================================================================
template <bool BIAS, bool OUT_BF16>
__global__ __launch_bounds__(256) void mfma_gemm3(
    const u16* __restrict__ Ah0, const u16* __restrict__ Al0,
    const u16* __restrict__ Ah1, const u16* __restrict__ Al1, int kSplit,
    const u16* __restrict__ Bh, const u16* __restrict__ Bl,
    const float* __restrict__ bias, float* __restrict__ C,
    u16* __restrict__ Ch, u16* __restrict__ Cl, int M, int K, int N) {
  __shared__ short8 S[2][1024];  // [buf][plane*256 + chunk], 32 KB

  int t = threadIdx.x, w = t >> 6, l = t & 63;
  int wr = w >> 1, wc = w & 1;
  int brow = blockIdx.y * 64, bcol = blockIdx.x * 64;

  // per-lane staging geometry (wave-uniform parts: w>>1, w&1)
  int lr = l & 31, kh = l >> 5;
  int arow = brow + (w >> 1) * 32 + lr;
  if (arow >= M) arow = M - 1;
  int bcolv = bcol + (w >> 1) * 32 + lr;
  int ksub = (w & 1) * 16 + kh * 8;

  f32x16 acc;
#pragma unroll
  for (int r = 0; r < 16; ++r) acc[r] = 0.f;

  int nt = K / 32;

#define STAGE(BUF, K0)                                                         \
  {                                                                            \
    const u16 *Ah, *Al; int kloc, lda;                                         \
    if ((K0) < kSplit) { Ah = Ah0; Al = Al0; kloc = (K0); lda = kSplit; }      \
    else { Ah = Ah1; Al = Al1; kloc = (K0) - kSplit; lda = K - kSplit; }       \
    size_t aoff = (size_t)arow * lda + kloc + ksub;                            \
    size_t boff = (size_t)bcolv * K + (K0) + ksub;                             \
    short8* base = &S[BUF][0] + w * 64;                                        \
    GL_LDS(Ah + aoff, base);                                                   \
    GL_LDS(Al + aoff, base + 256);                                             \
    GL_LDS(Bh + boff, base + 512);                                             \
    GL_LDS(Bl + boff, base + 768);                                             \
  }

  STAGE(0, 0)
  for (int ti = 0; ti < nt; ++ti) {
    int b = ti & 1;
    __syncthreads();  // drains DMA for buf b (compiler emits vmcnt(0))
    if (ti + 1 < nt) STAGE(b ^ 1, (ti + 1) * 32)
#pragma unroll
    for (int si = 0; si < 2; ++si) {
      short8 ah = S[b][wr * 128 + si * 64 + l];
      short8 al = S[b][256 + wr * 128 + si * 64 + l];
      short8 bh = S[b][512 + wc * 128 + si * 64 + l];
      short8 bl = S[b][768 + wc * 128 + si * 64 + l];
      acc = __builtin_amdgcn_mfma_f32_32x32x16_bf16(ah, bh, acc, 0, 0, 0);
      acc = __builtin_amdgcn_mfma_f32_32x32x16_bf16(al, bh, acc, 0, 0, 0);
      acc = __builtin_amdgcn_mfma_f32_32x32x16_bf16(ah, bl, acc, 0, 0, 0);
    }
  }
#undef STAGE

  // epilogue: C/D layout col=lane&31, row=(r&3)+8*(r>>2)+4*(lane>>5)
  int r0 = brow + wr * 32 + 4 * (l >> 5);
  int colg = bcol + wc * 32 + (l & 31);
  float badd = BIAS ? bias[colg] : 0.f;
#pragma unroll
  for (int r = 0; r < 16; ++r) {
    int rowg = r0 + (r & 3) + 8 * (r >> 2);
    if (rowg < M) {
      float v = acc[r] + badd;
      if (OUT_BF16) {
        u16 hh = f2bh(v);
        Ch[(size_t)rowg * N + colg] = hh;
        Cl[(size_t)rowg * N + colg] = f2bh(v - bh2f(hh));
      } else {
        C[(size_t)rowg * N + colg] = v;
      }
    }
  }
}

// ===========================================================================
// decode MLP: 8 nodes per block
// ===========================================================================
#define DEC_NODES 8
__global__ __launch_bounds__(128) void decode_kernel(
    const float* __restrict__ outg, const float* __restrict__ d1_W,
    const float* __restrict__ d1_b, const float* __restrict__ d2_W,
    const float* __restrict__ d2_b, float* __restrict__ z1) {
  __shared__ float rows[DEC_NODES][OUT_DIM];
  __shared__ float s0[128], s1[128];
  int t = threadIdx.x;
  int n0 = blockIdx.x * DEC_NODES;
#pragma unroll
  for (int j = 0; j < 4; ++j) {
    int idx = j * 512 + t * 4;
    *reinterpret_cast<float4*>(&rows[0][idx]) =
        *reinterpret_cast<const float4*>(outg + (size_t)n0 * OUT_DIM + idx);
  }
  __syncthreads();
  float acc[DEC_NODES];
  float b1 = d1_b[t];
#pragma unroll
  for (int n = 0; n < DEC_NODES; ++n) acc[n] = b1;
#pragma unroll 4
  for (int k = 0; k < OUT_DIM; ++k) {
    float wv = d1_W[k * 128 + t];
#pragma unroll
    for (int n = 0; n < DEC_NODES; ++n) acc[n] += rows[n][k] * wv;
  }
  float w0 = d2_W[t * 2 + 0], w1 = d2_W[t * 2 + 1];
  for (int n = 0; n < DEC_NODES; ++n) {
    float a = fmaxf(acc[n], 0.f);
    s0[t] = a * w0;
    s1[t] = a * w1;
    __syncthreads();
    for (int off = 64; off > 0; off >>= 1) {
      if (t < off) {
        s0[t] += s0[t + off];
        s1[t] += s1[t + off];
      }
      __syncthreads();
    }
    if (t == 0) {
      z1[(size_t)(n0 + n) * 2 + 0] = s0[0] + d2_b[0];
      z1[(size_t)(n0 + n) * 2 + 1] = s1[0] + d2_b[1];
    }
    __syncthreads();
  }
}

// ===========================================================================
// Tier-2 fallback kernels (round-5 proven path)
// ===========================================================================
__global__ __launch_bounds__(128) void gin_gather_kernel(
    const float* __restrict__ x, const int* __restrict__ row,
    const int* __restrict__ col, float* __restrict__ agg) {
  int i = blockIdx.x, t = threadIdx.x;
  int beg = row[i], end = row[i + 1];
  float4 acc{0.f, 0.f, 0.f, 0.f};
  for (int e = beg; e < end; ++e) {
    int s = col[e];
    float4 v = *reinterpret_cast<const float4*>(x + (size_t)s * IN_DIM + t * 4);
    acc.x += v.x; acc.y += v.y; acc.z += v.z; acc.w += v.w;
  }
  *reinterpret_cast<float4*>(agg + (size_t)i * IN_DIM + t * 4) = acc;
}

__global__ void convT_kernel(const float* __restrict__ W, u16* __restrict__ hi,
                             u16* __restrict__ lo, int K, int N) {
  int k = blockIdx.x * 256 + threadIdx.x;
  int n = blockIdx.y;
  float a = W[(size_t)k * N + n];
  u16 h = f2bh(a);
  hi[(size_t)n * K + k] = h;
  lo[(size_t)n * K + k] = f2bh(a - bh2f(h));
}

template <bool BIAS, int NW>
__global__ __launch_bounds__(256) void mfma_gemm_kernel(
    const float* __restrict__ A0, const float* __restrict__ A1, int kSplit,
    const u16* __restrict__ Wt_hi, const u16* __restrict__ Wt_lo,
    const float* __restrict__ bias, float* __restrict__ C,
    int M, int K, int N) {
  __shared__ short8 Ahi[512];
  __shared__ short8 Alo[512];
  __shared__ short8 Bhi[NW * 256];
  __shared__ short8 Blo[NW * 256];

  int t = threadIdx.x;
  int w = t >> 6, l = t & 63;
  int wr = w >> 1, wc = w & 1;
  int brow = blockIdx.y * 128, bcol = blockIdx.x * (NW * 64);

  f32x16 acc[2][NW];
#pragma unroll
  for (int m = 0; m < 2; ++m)
#pragma unroll
    for (int n = 0; n < NW; ++n)
#pragma unroll
      for (int r = 0; r < 16; ++r) acc[m][n][r] = 0.f;

  for (int k0 = 0; k0 < K; k0 += 32) {
    const float* Ap; int kk, lda;
    if (k0 < kSplit) { Ap = A0; kk = k0; lda = kSplit; }
    else             { Ap = A1; kk = k0 - kSplit; lda = K - kSplit; }
#pragma unroll
    for (int cc = 0; cc < 2; ++cc) {
      int c = t + cc * 256;
      int mt = c >> 7, si = (c >> 6) & 1, kh = (c >> 5) & 1, lr = c & 31;
      int arow = brow + mt * 32 + lr;
      int ak = kk + si * 16 + kh * 8;
      short8 ph, pl;
      if (arow < M) {
        const float* p = Ap + (size_t)arow * lda + ak;
        float4 u0 = *reinterpret_cast<const float4*>(p);
        float4 u1 = *reinterpret_cast<const float4*>(p + 4);
        float va[8] = {u0.x, u0.y, u0.z, u0.w, u1.x, u1.y, u1.z, u1.w};
#pragma unroll
        for (int j = 0; j < 8; ++j) {
          u16 hh = f2bh(va[j]);
          ph[j] = (short)hh;
          pl[j] = (short)f2bh(va[j] - bh2f(hh));
        }
      } else {
#pragma unroll
        for (int j = 0; j < 8; ++j) { ph[j] = 0; pl[j] = 0; }
      }
      Ahi[c] = ph;
      Alo[c] = pl;
    }
#pragma unroll
    for (int cc = 0; cc < NW; ++cc) {
      int c = t + cc * 256;
      int nt = c >> 7, si = (c >> 6) & 1, kh = (c >> 5) & 1, lc = c & 31;
      int bcl = bcol + nt * 32 + lc;
      size_t off = (size_t)bcl * K + k0 + si * 16 + kh * 8;
      Bhi[c] = *reinterpret_cast<const short8*>(Wt_hi + off);
      Blo[c] = *reinterpret_cast<const short8*>(Wt_lo + off);
    }
    __syncthreads();
#pragma unroll
    for (int si = 0; si < 2; ++si) {
      short8 ah[2], al[2], bh[NW], bl[NW];
#pragma unroll
      for (int m = 0; m < 2; ++m) {
        int c = (wr * 2 + m) * 128 + si * 64 + l;
        ah[m] = Ahi[c];
        al[m] = Alo[c];
      }
#pragma unroll
      for (int n = 0; n < NW; ++n) {
        int c = (wc * NW + n) * 128 + si * 64 + l;
        bh[n] = Bhi[c];
        bl[n] = Blo[c];
      }
#pragma unroll
      for (int m = 0; m < 2; ++m)
#pragma unroll
        for (int n = 0; n < NW; ++n) {
          acc[m][n] = __builtin_amdgcn_mfma_f32_32x32x16_bf16(ah[m], bh[n], acc[m][n], 0, 0, 0);
          acc[m][n] = __builtin_amdgcn_mfma_f32_32x32x16_bf16(al[m], bh[n], acc[m][n], 0, 0, 0);
          acc[m][n] = __builtin_amdgcn_mfma_f32_32x32x16_bf16(ah[m], bl[n], acc[m][n], 0, 0, 0);
        }
    }
    __syncthreads();
  }
#pragma unroll
  for (int m = 0; m < 2; ++m) {
    int r0 = brow + (wr * 2 + m) * 32 + 4 * (l >> 5);
#pragma unroll
    for (int n = 0; n < NW; ++n) {
      int colg = bcol + (wc * NW + n) * 32 + (l & 31);
      float badd = BIAS ? bias[colg] : 0.f;
#pragma unroll
      for (int r = 0; r < 16; ++r) {
        int rowg = r0 + (r & 3) + 8 * (r >> 2);
        if (rowg < M) C[(size_t)rowg * N + colg] = acc[m][n][r] + badd;
      }
    }
  }
}

// ===========================================================================
extern "C" void kernel_launch(void* const* d_in, const int* in_sizes, int n_in,
                              void* d_out, int out_size, void* d_ws, size_t ws_size,
                              hipStream_t stream) {
  const float* x     = (const float*)d_in[0];
  const int*   edge  = (const int*)d_in[1];
  const float* f_W   = (const float*)d_in[2];
  const float* f_b   = (const float*)d_in[3];
  const float* gcn_W = (const float*)d_in[4];
  const float* gcn_b = (const float*)d_in[5];
  const float* d1_W  = (const float*)d_in[6];
  const float* d1_b  = (const float*)d_in[7];
  const float* d2_W  = (const float*)d_in[8];
  const float* d2_b  = (const float*)d_in[9];
  float* out = (float*)d_out;
  char*  wsb = (char*)d_ws;

  const int* src = edge;
  const int* dst = edge + E_EDGES;

  // ---------------- v3 layout (bytes) ----------------
  const size_t SZ = (size_t)512 * N_NODES * sizeof(u16);  // 10,240,000
  u16*   x_hi   = (u16*)(wsb + 0 * SZ);
  u16*   x_lo   = (u16*)(wsb + 1 * SZ);
  u16*   agg_hi = (u16*)(wsb + 2 * SZ);
  u16*   agg_lo = (u16*)(wsb + 3 * SZ);
  u16*   h1_hi  = (u16*)(wsb + 4 * SZ);
  u16*   h1_lo  = (u16*)(wsb + 5 * SZ);
  float* outg3  = (float*)(wsb + 2 * SZ);  // overlays agg_hi (dead after GEMM1)
  float* hbuf3  = (float*)(wsb + 3 * SZ);  // overlays agg_lo (dead after GEMM1)
  size_t o = 6 * SZ;
  float* dis3   = (float*)(wsb + o); o += (size_t)N_NODES * 4;
  int*   icnt3  = (int*)(wsb + o);   o += (size_t)N_NODES * 4;
  int*   irow3  = (int*)(wsb + o);   o += (size_t)(N_NODES + 1) * 4 + 12;  // pad to 16
  int*   icol3  = (int*)(wsb + o);   o += (size_t)E_EDGES * 4;
  u16*   fWt_hi3 = (u16*)(wsb + o);  o += (size_t)IN_DIM * HID_DIM * 2;
  u16*   fWt_lo3 = (u16*)(wsb + o);  o += (size_t)IN_DIM * HID_DIM * 2;
  u16*   gWt_hi3 = (u16*)(wsb + o);  o += (size_t)(IN_DIM + HID_DIM) * OUT_DIM * 2;
  u16*   gWt_lo3 = (u16*)(wsb + o);  o += (size_t)(IN_DIM + HID_DIM) * OUT_DIM * 2;
  const size_t v3_needed = o;

  // ---------------- tier-2 layout (floats) ----------------
  float* ws = (float*)d_ws;
  float* agg  = ws;
  float* h1   = ws + (size_t)512 * N_NODES;
  float* dis  = ws + (size_t)1024 * N_NODES;
  float* h    = ws;
  float* outg = ws + (size_t)256 * N_NODES;
  int* icount = (int*)(ws + (size_t)1025 * N_NODES);
  int* irow   = icount + N_NODES;
  int* icol   = irow + N_NODES + 1;
  size_t csr_needed = (size_t)1025 * N_NODES * sizeof(float) +
                      (size_t)(2 * N_NODES + 1 + E_EDGES) * sizeof(int);
  const size_t WELEMS = 512 * 512;
  size_t usOff = (csr_needed + 15) & ~(size_t)15;
  u16* fWt_hi = (u16*)(wsb + usOff);
  u16* fWt_lo = fWt_hi + WELEMS;
  u16* gWt_hi = fWt_lo + WELEMS;
  u16* gWt_lo = gWt_hi + WELEMS;
  size_t t2_needed = usOff + 4 * WELEMS * sizeof(u16);

  if (ws_size >= v3_needed) {
    // ======================= v3 path =======================
    hipMemsetAsync(icnt3, 0, (size_t)N_NODES * sizeof(int), stream);
    count_kernel<<<(E_EDGES + 255) / 256, 256, 0, stream>>>(dst, icnt3);
    scan_kernel<<<1, 1024, 0, stream>>>(icnt3, irow3, dis3);
    place_kernel<<<(E_EDGES + 255) / 256, 256, 0, stream>>>(src, dst, icnt3, icol3);

    // conversions (independent)
    conv_bf_kernel<<<(N_NODES * IN_DIM / 4 + 255) / 256, 256, 0, stream>>>(
        x, x_hi, x_lo, N_NODES * IN_DIM / 4);
    convT_kernel3<<<dim3(IN_DIM / 64, HID_DIM / 64), 256, 0, stream>>>(
        f_W, fWt_hi3, fWt_lo3, IN_DIM, HID_DIM);
    convT_kernel3<<<dim3((IN_DIM + HID_DIM) / 64, OUT_DIM / 64), 256, 0, stream>>>(
        gcn_W, gWt_hi3, gWt_lo3, IN_DIM + HID_DIM, OUT_DIM);

    // GIN gather -> bf16 pair
    gin_gather_bf<<<N_NODES, 128, 0, stream>>>(x, irow3, icol3, agg_hi, agg_lo);

    // h1 = agg @ f_W + f_b  -> bf16 pair output
    mfma_gemm3<true, true><<<dim3(HID_DIM / 64, (N_NODES + 63) / 64), 256, 0, stream>>>(
        agg_hi, agg_lo, agg_hi, agg_lo, IN_DIM, fWt_hi3, fWt_lo3, f_b,
        nullptr, h1_hi, h1_lo, N_NODES, IN_DIM, HID_DIM);

    // h = [x | h1] @ gcn_W  -> fp32 (bias added in gcn_gather)
    mfma_gemm3<false, false><<<dim3(OUT_DIM / 64, (N_NODES + 63) / 64), 256, 0, stream>>>(
        x_hi, x_lo, h1_hi, h1_lo, IN_DIM, gWt_hi3, gWt_lo3, nullptr,
        hbuf3, nullptr, nullptr, N_NODES, IN_DIM + HID_DIM, OUT_DIM);

    gcn_gather_kernel<<<N_NODES, 64, 0, stream>>>(hbuf3, irow3, icol3, dis3, gcn_b, outg3);
    decode_kernel<<<N_NODES / DEC_NODES, 128, 0, stream>>>(outg3, d1_W, d1_b, d2_W, d2_b, out);
  } else {
    // ======================= tier-2 (round-5 proven) =======================
    hipMemsetAsync(icount, 0, (size_t)N_NODES * sizeof(int), stream);
    count_kernel<<<(E_EDGES + 255) / 256, 256, 0, stream>>>(dst, icount);
    scan_kernel<<<1, 1024, 0, stream>>>(icount, irow, dis);
    place_kernel<<<(E_EDGES + 255) / 256, 256, 0, stream>>>(src, dst, icount, icol);
    gin_gather_kernel<<<N_NODES, 128, 0, stream>>>(x, irow, icol, agg);
    if (ws_size >= t2_needed) {
      convT_kernel<<<dim3(IN_DIM / 256, HID_DIM), 256, 0, stream>>>(
          f_W, fWt_hi, fWt_lo, IN_DIM, HID_DIM);
      convT_kernel<<<dim3((IN_DIM + HID_DIM) / 256, OUT_DIM), 256, 0, stream>>>(
          gcn_W, gWt_hi, gWt_lo, IN_DIM + HID_DIM, OUT_DIM);
      mfma_gemm_kernel<true, 2><<<dim3(HID_DIM / 128, (N_NODES + 127) / 128), 256, 0, stream>>>(
          agg, agg, IN_DIM, fWt_hi, fWt_lo, f_b, h1, N_NODES, IN_DIM, HID_DIM);
      mfma_gemm_kernel<false, 1><<<dim3(OUT_DIM / 64, (N_NODES + 127) / 128), 256, 0, stream>>>(
          x, h1, IN_DIM, gWt_hi, gWt_lo, nullptr, h, N_NODES, IN_DIM + HID_DIM, OUT_DIM);
    }
    gcn_gather_kernel<<<N_NODES, 64, 0, stream>>>(h, irow, icol, dis, gcn_b, outg);
    decode_kernel<<<N_NODES / DEC_NODES, 128, 0, stream>>>(outg, d1_W, d1_b, d2_W, d2_b, out);
  }
}

// Round 7
// 236.983 us; speedup vs baseline: 1.1032x; 1.1032x over previous
//
#include <hip/hip_runtime.h>

#define N_NODES 10000
#define E_EDGES 160000
#define IN_DIM  512
#define HID_DIM 512
#define OUT_DIM 256
#define MB_T    157   // ceil(10000/64) row tiles

typedef __attribute__((ext_vector_type(8))) short short8;
typedef __attribute__((ext_vector_type(16))) float f32x16;
typedef unsigned short u16;

__device__ __forceinline__ u16 f2bh(float f) {
  union { float f; unsigned u; } v; v.f = f;
  return (u16)((v.u + 0x7FFFu + ((v.u >> 16) & 1u)) >> 16);
}
__device__ __forceinline__ float bh2f(u16 h) {
  union { unsigned u; float f; } v; v.u = ((unsigned)h) << 16;
  return v.f;
}

// tiled layout: chunk c within tile (mb,kt): row=(c>>7)*32+(c&31),
// k=((c>>6)&1)*16+((c>>5)&1)*8 (+0..7). u16 index of chunk start:
__device__ __forceinline__ size_t tidx(int mb, int ktTot, int kt, int c) {
  return ((size_t)(mb * ktTot + kt) * 256 + c) * 8;
}

#define GL_LDS(gsrc, ldst)                                                      \
  __builtin_amdgcn_global_load_lds(                                             \
      (const __attribute__((address_space(1))) unsigned int*)(gsrc),            \
      (__attribute__((address_space(3))) unsigned int*)(ldst), 16, 0, 0)

// ===========================================================================
// CSR build
// ===========================================================================
__global__ void count_kernel(const int* __restrict__ dst, int* __restrict__ cnt) {
  int e = blockIdx.x * 256 + threadIdx.x;
  if (e < E_EDGES) atomicAdd(&cnt[dst[e]], 1);
}

__global__ __launch_bounds__(1024) void scan_kernel(
    int* __restrict__ cnt, int* __restrict__ row, float* __restrict__ dis) {
  __shared__ int sums[1024];
  const int CH = 10;
  int t = threadIdx.x;
  int c[CH], excl[CH];
  int s = 0;
#pragma unroll
  for (int j = 0; j < CH; ++j) {
    int idx = t * CH + j;
    c[j] = (idx < N_NODES) ? cnt[idx] : 0;
    excl[j] = s;
    s += c[j];
  }
  sums[t] = s;
  __syncthreads();
  for (int off = 1; off < 1024; off <<= 1) {
    int v = (t >= off) ? sums[t - off] : 0;
    __syncthreads();
    if (t >= off) sums[t] += v;
    __syncthreads();
  }
  int base = (t == 0) ? 0 : sums[t - 1];
#pragma unroll
  for (int j = 0; j < CH; ++j) {
    int idx = t * CH + j;
    if (idx < N_NODES) {
      int start = base + excl[j];
      row[idx] = start;
      cnt[idx] = start;
      dis[idx] = rsqrtf((float)c[j] + 1.0f);
    }
  }
  if (t == 1023) row[N_NODES] = sums[1023];
}

__global__ void place_kernel(const int* __restrict__ src, const int* __restrict__ dst,
                             int* __restrict__ cursor, int* __restrict__ col) {
  int e = blockIdx.x * 256 + threadIdx.x;
  if (e < E_EDGES) {
    int pos = atomicAdd(&cursor[dst[e]], 1);
    col[pos] = src[e];
  }
}

// ===========================================================================
// pack x: fp32 row-major -> tiled bf16 hi/lo (ktTot=16). 128 thr/node.
// ===========================================================================
__global__ __launch_bounds__(128) void pack_x_kernel(
    const float* __restrict__ x, u16* __restrict__ hi, u16* __restrict__ lo) {
  int i = blockIdx.x, t = threadIdx.x;
  int k0 = t * 4;
  float4 v = *reinterpret_cast<const float4*>(x + (size_t)i * IN_DIM + k0);
  float a[4] = {v.x, v.y, v.z, v.w};
  ushort4 h4, l4;
  u16* hp = &h4.x; u16* lp = &l4.x;
#pragma unroll
  for (int j = 0; j < 4; ++j) {
    u16 hh = f2bh(a[j]);
    hp[j] = hh;
    lp[j] = f2bh(a[j] - bh2f(hh));
  }
  int mb = i >> 6, rl = i & 63;
  int kt = k0 >> 5, si = (k0 >> 4) & 1, kh = (k0 >> 3) & 1;
  int c = (rl >> 5) * 128 + si * 64 + kh * 32 + (rl & 31);
  size_t idx = tidx(mb, IN_DIM / 32, kt, c) + (k0 & 7);
  *reinterpret_cast<ushort4*>(hi + idx) = h4;
  *reinterpret_cast<ushort4*>(lo + idx) = l4;
}

// ===========================================================================
// GIN gather -> tiled bf16 hi/lo agg
// ===========================================================================
__global__ __launch_bounds__(128) void gin_gather_bf(
    const float* __restrict__ x, const int* __restrict__ row,
    const int* __restrict__ col, u16* __restrict__ agg_hi,
    u16* __restrict__ agg_lo) {
  int i = blockIdx.x, t = threadIdx.x;
  int beg = row[i], end = row[i + 1];
  int k0 = t * 4;
  float4 acc{0.f, 0.f, 0.f, 0.f};
  for (int e = beg; e < end; ++e) {
    int s = col[e];
    float4 v = *reinterpret_cast<const float4*>(x + (size_t)s * IN_DIM + k0);
    acc.x += v.x; acc.y += v.y; acc.z += v.z; acc.w += v.w;
  }
  float a[4] = {acc.x, acc.y, acc.z, acc.w};
  ushort4 h4, l4;
  u16* hp = &h4.x; u16* lp = &l4.x;
#pragma unroll
  for (int j = 0; j < 4; ++j) {
    u16 hh = f2bh(a[j]);
    hp[j] = hh;
    lp[j] = f2bh(a[j] - bh2f(hh));
  }
  int mb = i >> 6, rl = i & 63;
  int kt = k0 >> 5, si = (k0 >> 4) & 1, kh = (k0 >> 3) & 1;
  int c = (rl >> 5) * 128 + si * 64 + kh * 32 + (rl & 31);
  size_t idx = tidx(mb, IN_DIM / 32, kt, c) + (k0 & 7);
  *reinterpret_cast<ushort4*>(agg_hi + idx) = h4;
  *reinterpret_cast<ushort4*>(agg_lo + idx) = l4;
}

// ===========================================================================
// GCN gather (fp32 h), fused self-loop + bias
// ===========================================================================
__global__ __launch_bounds__(64) void gcn_gather_kernel(
    const float* __restrict__ h, const int* __restrict__ row,
    const int* __restrict__ col, const float* __restrict__ dis,
    const float* __restrict__ gcn_b, float* __restrict__ outg) {
  int i = blockIdx.x, t = threadIdx.x;
  int beg = row[i], end = row[i + 1];
  float di = dis[i];
  float4 acc{0.f, 0.f, 0.f, 0.f};
  for (int e = beg; e < end; ++e) {
    int s = col[e];
    float w = dis[s];
    float4 v = *reinterpret_cast<const float4*>(h + (size_t)s * OUT_DIM + t * 4);
    acc.x += w * v.x; acc.y += w * v.y; acc.z += w * v.z; acc.w += w * v.w;
  }
  float4 hv = *reinterpret_cast<const float4*>(h + (size_t)i * OUT_DIM + t * 4);
  float4 bv = *reinterpret_cast<const float4*>(gcn_b + t * 4);
  float self = di * di;
  float4 o{di * acc.x + self * hv.x + bv.x, di * acc.y + self * hv.y + bv.y,
           di * acc.z + self * hv.z + bv.z, di * acc.w + self * hv.w + bv.w};
  *reinterpret_cast<float4*>(outg + (size_t)i * OUT_DIM + t * 4) = o;
}

// ===========================================================================
// Weight transpose + split -> tiled: W [K][N] fp32 -> Wt tiled by col.
// Grid (K/64, N/64), 256 thr, LDS transpose for coalescing.
// ===========================================================================
__global__ __launch_bounds__(256) void convT_tiled(
    const float* __restrict__ W, u16* __restrict__ hi, u16* __restrict__ lo,
    int K, int N) {
  __shared__ float tile[64][65];
  int k0g = blockIdx.x * 64, n0 = blockIdx.y * 64;
  int t = threadIdx.x;
  int lk = t >> 4, ln = (t & 15) * 4;
#pragma unroll
  for (int p = 0; p < 4; ++p) {
    float4 v = *reinterpret_cast<const float4*>(W + (size_t)(k0g + p * 16 + lk) * N + n0 + ln);
    tile[p * 16 + lk][ln + 0] = v.x;
    tile[p * 16 + lk][ln + 1] = v.y;
    tile[p * 16 + lk][ln + 2] = v.z;
    tile[p * 16 + lk][ln + 3] = v.w;
  }
  __syncthreads();
  int on = t >> 2;        // col local 0..63
  int ok = (t & 3) * 16;  // k local
  int colg = n0 + on;
  int nb = colg >> 6, rl = colg & 63;
  int ktTot = K >> 5;
#pragma unroll
  for (int q = 0; q < 4; ++q) {
    int kg = k0g + ok + q * 4;
    ushort4 h4, l4;
    u16* hq = &h4.x; u16* lq = &l4.x;
#pragma unroll
    for (int j = 0; j < 4; ++j) {
      float v = tile[ok + q * 4 + j][on];
      u16 hh = f2bh(v);
      hq[j] = hh;
      lq[j] = f2bh(v - bh2f(hh));
    }
    int kt = kg >> 5, si = (kg >> 4) & 1, kh = (kg >> 3) & 1;
    int c = (rl >> 5) * 128 + si * 64 + kh * 32 + (rl & 31);
    size_t idx = tidx(nb, ktTot, kt, c) + (kg & 7);
    *reinterpret_cast<ushort4*>(hi + idx) = h4;
    *reinterpret_cast<ushort4*>(lo + idx) = l4;
  }
}

// ===========================================================================
// MFMA GEMM v4: tiled bf16 inputs, contiguous global_load_lds staging,
// double-buffered. BM=64 BN=64 BK=32, 4 waves 2x2. 2 acc chains (si split).
// A: K0<kSplit from (Ah0,Al0) else (Ah1,Al1); both tiled with own kt count.
// OUT_TILED: repack через LDS -> tiled bf16 pair.  else fp32 row-major.
// ===========================================================================
template <bool BIAS, bool OUT_TILED>
__global__ __launch_bounds__(256) void mfma_gemm4(
    const u16* __restrict__ Ah0, const u16* __restrict__ Al0,
    const u16* __restrict__ Ah1, const u16* __restrict__ Al1, int kSplit,
    const u16* __restrict__ Bh, const u16* __restrict__ Bl,
    const float* __restrict__ bias, float* __restrict__ C,
    u16* __restrict__ Ch, u16* __restrict__ Cl, int M, int K, int N) {
  __shared__ short8 S[2][1024];  // 32 KB

  int t = threadIdx.x, w = t >> 6, l = t & 63;
  int wr = w >> 1, wc = w & 1;
  int mb = blockIdx.y, nb = blockIdx.x;
  int brow = mb * 64, bcol = nb * 64;
  int cid = w * 64 + l;  // staged chunk id

  f32x16 acc0, acc1;
#pragma unroll
  for (int r = 0; r < 16; ++r) { acc0[r] = 0.f; acc1[r] = 0.f; }

  int nt = K / 32;
  int ktTotB = K >> 5;
  int ktTot0 = kSplit >> 5;
  int ktTot1 = (K - kSplit) >> 5;

#define STAGE(BUF, K0)                                                         \
  {                                                                            \
    const u16 *Ah, *Al; size_t abase;                                          \
    if ((K0) < kSplit) {                                                       \
      Ah = Ah0; Al = Al0; abase = tidx(mb, ktTot0, (K0) >> 5, cid);            \
    } else {                                                                   \
      Ah = Ah1; Al = Al1; abase = tidx(mb, ktTot1, ((K0) - kSplit) >> 5, cid); \
    }                                                                          \
    size_t bbase = tidx(nb, ktTotB, (K0) >> 5, cid);                           \
    short8* base = &S[BUF][0] + w * 64;                                        \
    GL_LDS(Ah + abase, base);                                                  \
    GL_LDS(Al + abase, base + 256);                                            \
    GL_LDS(Bh + bbase, base + 512);                                            \
    GL_LDS(Bl + bbase, base + 768);                                            \
  }

  STAGE(0, 0)
  for (int ti = 0; ti < nt; ++ti) {
    int b = ti & 1;
    __syncthreads();
    if (ti + 1 < nt) STAGE(b ^ 1, (ti + 1) * 32)
    {
      short8 ah = S[b][wr * 128 + l];
      short8 al = S[b][256 + wr * 128 + l];
      short8 bh = S[b][512 + wc * 128 + l];
      short8 bl = S[b][768 + wc * 128 + l];
      acc0 = __builtin_amdgcn_mfma_f32_32x32x16_bf16(ah, bh, acc0, 0, 0, 0);
      acc0 = __builtin_amdgcn_mfma_f32_32x32x16_bf16(al, bh, acc0, 0, 0, 0);
      acc0 = __builtin_amdgcn_mfma_f32_32x32x16_bf16(ah, bl, acc0, 0, 0, 0);
    }
    {
      short8 ah = S[b][wr * 128 + 64 + l];
      short8 al = S[b][256 + wr * 128 + 64 + l];
      short8 bh = S[b][512 + wc * 128 + 64 + l];
      short8 bl = S[b][768 + wc * 128 + 64 + l];
      acc1 = __builtin_amdgcn_mfma_f32_32x32x16_bf16(ah, bh, acc1, 0, 0, 0);
      acc1 = __builtin_amdgcn_mfma_f32_32x32x16_bf16(al, bh, acc1, 0, 0, 0);
      acc1 = __builtin_amdgcn_mfma_f32_32x32x16_bf16(ah, bl, acc1, 0, 0, 0);
    }
  }
#undef STAGE

  f32x16 acc = acc0 + acc1;

  int r0l = wr * 32 + 4 * (l >> 5);
  int c0l = wc * 32 + (l & 31);

  if (OUT_TILED) {
    __syncthreads();  // done reading S; reuse as repack buffer
    u16* Hhi = (u16*)&S[0][0];
    u16* Hlo = Hhi + 4096;
    float badd = BIAS ? bias[bcol + c0l] : 0.f;
#pragma unroll
    for (int r = 0; r < 16; ++r) {
      int rl = r0l + (r & 3) + 8 * (r >> 2);
      float v = acc[r] + badd;
      u16 hh = f2bh(v);
      Hhi[rl * 64 + c0l] = hh;
      Hlo[rl * 64 + c0l] = f2bh(v - bh2f(hh));
    }
    __syncthreads();
    int ktTot = N >> 5;
#pragma unroll
    for (int pl = 0; pl < 2; ++pl) {
      const u16* Hs = pl ? Hlo : Hhi;
      u16* dA = pl ? Cl : Ch;
#pragma unroll
      for (int j = 0; j < 2; ++j) {
        int ci = t + j * 256;
        int ktl = ci >> 8;
        int c = ci & 255;
        int r = ((c >> 7) & 1) * 32 + (c & 31);
        int kloc = ktl * 32 + ((c >> 6) & 1) * 16 + ((c >> 5) & 1) * 8;
        short8 v = *reinterpret_cast<const short8*>(Hs + r * 64 + kloc);
        size_t db = tidx(mb, ktTot, (bcol >> 5) + ktl, c);
        *reinterpret_cast<short8*>(dA + db) = v;
      }
    }
  } else {
    int colg = bcol + c0l;
    float badd = BIAS ? bias[colg] : 0.f;
#pragma unroll
    for (int r = 0; r < 16; ++r) {
      int rowg = brow + r0l + (r & 3) + 8 * (r >> 2);
      if (rowg < M) C[(size_t)rowg * N + colg] = acc[r] + badd;
    }
  }
}

// ===========================================================================
// decode MLP: 8 nodes per block
// ===========================================================================
#define DEC_NODES 8
__global__ __launch_bounds__(128) void decode_kernel(
    const float* __restrict__ outg, const float* __restrict__ d1_W,
    const float* __restrict__ d1_b, const float* __restrict__ d2_W,
    const float* __restrict__ d2_b, float* __restrict__ z1) {
  __shared__ float rows[DEC_NODES][OUT_DIM];
  __shared__ float s0[128], s1[128];
  int t = threadIdx.x;
  int n0 = blockIdx.x * DEC_NODES;
#pragma unroll
  for (int j = 0; j < 4; ++j) {
    int idx = j * 512 + t * 4;
    *reinterpret_cast<float4*>(&rows[0][idx]) =
        *reinterpret_cast<const float4*>(outg + (size_t)n0 * OUT_DIM + idx);
  }
  __syncthreads();
  float acc[DEC_NODES];
  float b1 = d1_b[t];
#pragma unroll
  for (int n = 0; n < DEC_NODES; ++n) acc[n] = b1;
#pragma unroll 4
  for (int k = 0; k < OUT_DIM; ++k) {
    float wv = d1_W[k * 128 + t];
#pragma unroll
    for (int n = 0; n < DEC_NODES; ++n) acc[n] += rows[n][k] * wv;
  }
  float w0 = d2_W[t * 2 + 0], w1 = d2_W[t * 2 + 1];
  for (int n = 0; n < DEC_NODES; ++n) {
    float a = fmaxf(acc[n], 0.f);
    s0[t] = a * w0;
    s1[t] = a * w1;
    __syncthreads();
    for (int off = 64; off > 0; off >>= 1) {
      if (t < off) {
        s0[t] += s0[t + off];
        s1[t] += s1[t + off];
      }
      __syncthreads();
    }
    if (t == 0) {
      z1[(size_t)(n0 + n) * 2 + 0] = s0[0] + d2_b[0];
      z1[(size_t)(n0 + n) * 2 + 1] = s1[0] + d2_b[1];
    }
    __syncthreads();
  }
}

// ===========================================================================
// Tier-2 fallback (round-5 proven path)
// ===========================================================================
__global__ __launch_bounds__(128) void gin_gather_kernel(
    const float* __restrict__ x, const int* __restrict__ row,
    const int* __restrict__ col, float* __restrict__ agg) {
  int i = blockIdx.x, t = threadIdx.x;
  int beg = row[i], end = row[i + 1];
  float4 acc{0.f, 0.f, 0.f, 0.f};
  for (int e = beg; e < end; ++e) {
    int s = col[e];
    float4 v = *reinterpret_cast<const float4*>(x + (size_t)s * IN_DIM + t * 4);
    acc.x += v.x; acc.y += v.y; acc.z += v.z; acc.w += v.w;
  }
  *reinterpret_cast<float4*>(agg + (size_t)i * IN_DIM + t * 4) = acc;
}

__global__ void convT_kernel(const float* __restrict__ W, u16* __restrict__ hi,
                             u16* __restrict__ lo, int K, int N) {
  int k = blockIdx.x * 256 + threadIdx.x;
  int n = blockIdx.y;
  float a = W[(size_t)k * N + n];
  u16 h = f2bh(a);
  hi[(size_t)n * K + k] = h;
  lo[(size_t)n * K + k] = f2bh(a - bh2f(h));
}

template <bool BIAS, int NW>
__global__ __launch_bounds__(256) void mfma_gemm_kernel(
    const float* __restrict__ A0, const float* __restrict__ A1, int kSplit,
    const u16* __restrict__ Wt_hi, const u16* __restrict__ Wt_lo,
    const float* __restrict__ bias, float* __restrict__ C,
    int M, int K, int N) {
  __shared__ short8 Ahi[512];
  __shared__ short8 Alo[512];
  __shared__ short8 Bhi[NW * 256];
  __shared__ short8 Blo[NW * 256];
  int t = threadIdx.x;
  int w = t >> 6, l = t & 63;
  int wr = w >> 1, wc = w & 1;
  int brow = blockIdx.y * 128, bcol = blockIdx.x * (NW * 64);
  f32x16 acc[2][NW];
#pragma unroll
  for (int m = 0; m < 2; ++m)
#pragma unroll
    for (int n = 0; n < NW; ++n)
#pragma unroll
      for (int r = 0; r < 16; ++r) acc[m][n][r] = 0.f;
  for (int k0 = 0; k0 < K; k0 += 32) {
    const float* Ap; int kk, lda;
    if (k0 < kSplit) { Ap = A0; kk = k0; lda = kSplit; }
    else             { Ap = A1; kk = k0 - kSplit; lda = K - kSplit; }
#pragma unroll
    for (int cc = 0; cc < 2; ++cc) {
      int c = t + cc * 256;
      int mt = c >> 7, si = (c >> 6) & 1, kh = (c >> 5) & 1, lr = c & 31;
      int arow = brow + mt * 32 + lr;
      int ak = kk + si * 16 + kh * 8;
      short8 ph, pl;
      if (arow < M) {
        const float* p = Ap + (size_t)arow * lda + ak;
        float4 u0 = *reinterpret_cast<const float4*>(p);
        float4 u1 = *reinterpret_cast<const float4*>(p + 4);
        float va[8] = {u0.x, u0.y, u0.z, u0.w, u1.x, u1.y, u1.z, u1.w};
#pragma unroll
        for (int j = 0; j < 8; ++j) {
          u16 hh = f2bh(va[j]);
          ph[j] = (short)hh;
          pl[j] = (short)f2bh(va[j] - bh2f(hh));
        }
      } else {
#pragma unroll
        for (int j = 0; j < 8; ++j) { ph[j] = 0; pl[j] = 0; }
      }
      Ahi[c] = ph;
      Alo[c] = pl;
    }
#pragma unroll
    for (int cc = 0; cc < NW; ++cc) {
      int c = t + cc * 256;
      int nt2 = c >> 7, si = (c >> 6) & 1, kh = (c >> 5) & 1, lc = c & 31;
      int bcl = bcol + nt2 * 32 + lc;
      size_t off = (size_t)bcl * K + k0 + si * 16 + kh * 8;
      Bhi[c] = *reinterpret_cast<const short8*>(Wt_hi + off);
      Blo[c] = *reinterpret_cast<const short8*>(Wt_lo + off);
    }
    __syncthreads();
#pragma unroll
    for (int si = 0; si < 2; ++si) {
      short8 ah[2], al[2], bh[NW], bl[NW];
#pragma unroll
      for (int m = 0; m < 2; ++m) {
        int c = (wr * 2 + m) * 128 + si * 64 + l;
        ah[m] = Ahi[c];
        al[m] = Alo[c];
      }
#pragma unroll
      for (int n = 0; n < NW; ++n) {
        int c = (wc * NW + n) * 128 + si * 64 + l;
        bh[n] = Bhi[c];
        bl[n] = Blo[c];
      }
#pragma unroll
      for (int m = 0; m < 2; ++m)
#pragma unroll
        for (int n = 0; n < NW; ++n) {
          acc[m][n] = __builtin_amdgcn_mfma_f32_32x32x16_bf16(ah[m], bh[n], acc[m][n], 0, 0, 0);
          acc[m][n] = __builtin_amdgcn_mfma_f32_32x32x16_bf16(al[m], bh[n], acc[m][n], 0, 0, 0);
          acc[m][n] = __builtin_amdgcn_mfma_f32_32x32x16_bf16(ah[m], bl[n], acc[m][n], 0, 0, 0);
        }
    }
    __syncthreads();
  }
#pragma unroll
  for (int m = 0; m < 2; ++m) {
    int r0 = brow + (wr * 2 + m) * 32 + 4 * (l >> 5);
#pragma unroll
    for (int n = 0; n < NW; ++n) {
      int colg = bcol + (wc * NW + n) * 32 + (l & 31);
      float badd = BIAS ? bias[colg] : 0.f;
#pragma unroll
      for (int r = 0; r < 16; ++r) {
        int rowg = r0 + (r & 3) + 8 * (r >> 2);
        if (rowg < M) C[(size_t)rowg * N + colg] = acc[m][n][r] + badd;
      }
    }
  }
}

// ===========================================================================
extern "C" void kernel_launch(void* const* d_in, const int* in_sizes, int n_in,
                              void* d_out, int out_size, void* d_ws, size_t ws_size,
                              hipStream_t stream) {
  const float* x     = (const float*)d_in[0];
  const int*   edge  = (const int*)d_in[1];
  const float* f_W   = (const float*)d_in[2];
  const float* f_b   = (const float*)d_in[3];
  const float* gcn_W = (const float*)d_in[4];
  const float* gcn_b = (const float*)d_in[5];
  const float* d1_W  = (const float*)d_in[6];
  const float* d1_b  = (const float*)d_in[7];
  const float* d2_W  = (const float*)d_in[8];
  const float* d2_b  = (const float*)d_in[9];
  float* out = (float*)d_out;
  char*  wsb = (char*)d_ws;

  const int* src = edge;
  const int* dst = edge + E_EDGES;

  // -------- v4 layout (bytes) --------
  const size_t TS = (size_t)MB_T * 16 * 256 * 8 * sizeof(u16);  // 10,289,152 per plane (K=512 tiled)
  u16* x_hi   = (u16*)(wsb + 0 * TS);
  u16* x_lo   = (u16*)(wsb + 1 * TS);
  u16* agg_hi = (u16*)(wsb + 2 * TS);
  u16* agg_lo = (u16*)(wsb + 3 * TS);
  u16* h1_hi  = (u16*)(wsb + 4 * TS);
  u16* h1_lo  = (u16*)(wsb + 5 * TS);
  float* hbuf4 = (float*)(wsb + 2 * TS);  // overlays agg_hi (dead after GEMM1)
  float* outg4 = (float*)(wsb + 3 * TS);  // overlays agg_lo
  size_t o = 6 * TS;
  float* dis4  = (float*)(wsb + o); o += (size_t)N_NODES * 4;
  int*   icnt4 = (int*)(wsb + o);   o += (size_t)N_NODES * 4;
  int*   irow4 = (int*)(wsb + o);   o += (size_t)(N_NODES + 1) * 4 + 12;
  int*   icol4 = (int*)(wsb + o);   o += (size_t)E_EDGES * 4;
  u16*   fWt_hi4 = (u16*)(wsb + o); o += (size_t)8 * 16 * 256 * 8 * 2;   // 512K B
  u16*   fWt_lo4 = (u16*)(wsb + o); o += (size_t)8 * 16 * 256 * 8 * 2;
  u16*   gWt_hi4 = (u16*)(wsb + o); o += (size_t)4 * 32 * 256 * 8 * 2;
  u16*   gWt_lo4 = (u16*)(wsb + o); o += (size_t)4 * 32 * 256 * 8 * 2;
  const size_t v4_needed = o;

  // -------- tier-2 layout --------
  float* ws = (float*)d_ws;
  float* agg  = ws;
  float* h1   = ws + (size_t)512 * N_NODES;
  float* dis  = ws + (size_t)1024 * N_NODES;
  float* h    = ws;
  float* outg = ws + (size_t)256 * N_NODES;
  int* icount = (int*)(ws + (size_t)1025 * N_NODES);
  int* irow   = icount + N_NODES;
  int* icol   = irow + N_NODES + 1;
  size_t csr_needed = (size_t)1025 * N_NODES * sizeof(float) +
                      (size_t)(2 * N_NODES + 1 + E_EDGES) * sizeof(int);
  const size_t WELEMS = 512 * 512;
  size_t usOff = (csr_needed + 15) & ~(size_t)15;
  u16* fWt_hi = (u16*)(wsb + usOff);
  u16* fWt_lo = fWt_hi + WELEMS;
  u16* gWt_hi = fWt_lo + WELEMS;
  u16* gWt_lo = gWt_hi + WELEMS;
  size_t t2_needed = usOff + 4 * WELEMS * sizeof(u16);

  if (ws_size >= v4_needed) {
    // ======== v4 path ========
    hipMemsetAsync(icnt4, 0, (size_t)N_NODES * sizeof(int), stream);
    count_kernel<<<(E_EDGES + 255) / 256, 256, 0, stream>>>(dst, icnt4);
    scan_kernel<<<1, 1024, 0, stream>>>(icnt4, irow4, dis4);
    place_kernel<<<(E_EDGES + 255) / 256, 256, 0, stream>>>(src, dst, icnt4, icol4);

    pack_x_kernel<<<N_NODES, 128, 0, stream>>>(x, x_hi, x_lo);
    convT_tiled<<<dim3(IN_DIM / 64, HID_DIM / 64), 256, 0, stream>>>(
        f_W, fWt_hi4, fWt_lo4, IN_DIM, HID_DIM);
    convT_tiled<<<dim3((IN_DIM + HID_DIM) / 64, OUT_DIM / 64), 256, 0, stream>>>(
        gcn_W, gWt_hi4, gWt_lo4, IN_DIM + HID_DIM, OUT_DIM);

    gin_gather_bf<<<N_NODES, 128, 0, stream>>>(x, irow4, icol4, agg_hi, agg_lo);

    // h1 = agg @ f_W + f_b  (tiled out)
    mfma_gemm4<true, true><<<dim3(HID_DIM / 64, MB_T), 256, 0, stream>>>(
        agg_hi, agg_lo, agg_hi, agg_lo, IN_DIM, fWt_hi4, fWt_lo4, f_b,
        nullptr, h1_hi, h1_lo, N_NODES, IN_DIM, HID_DIM);

    // h = [x | h1] @ gcn_W  (fp32 out)
    mfma_gemm4<false, false><<<dim3(OUT_DIM / 64, MB_T), 256, 0, stream>>>(
        x_hi, x_lo, h1_hi, h1_lo, IN_DIM, gWt_hi4, gWt_lo4, nullptr,
        hbuf4, nullptr, nullptr, N_NODES, IN_DIM + HID_DIM, OUT_DIM);

    gcn_gather_kernel<<<N_NODES, 64, 0, stream>>>(hbuf4, irow4, icol4, dis4, gcn_b, outg4);
    decode_kernel<<<N_NODES / DEC_NODES, 128, 0, stream>>>(outg4, d1_W, d1_b, d2_W, d2_b, out);
  } else {
    // ======== tier-2 (round-5 proven) ========
    hipMemsetAsync(icount, 0, (size_t)N_NODES * sizeof(int), stream);
    count_kernel<<<(E_EDGES + 255) / 256, 256, 0, stream>>>(dst, icount);
    scan_kernel<<<1, 1024, 0, stream>>>(icount, irow, dis);
    place_kernel<<<(E_EDGES + 255) / 256, 256, 0, stream>>>(src, dst, icount, icol);
    gin_gather_kernel<<<N_NODES, 128, 0, stream>>>(x, irow, icol, agg);
    if (ws_size >= t2_needed) {
      convT_kernel<<<dim3(IN_DIM / 256, HID_DIM), 256, 0, stream>>>(
          f_W, fWt_hi, fWt_lo, IN_DIM, HID_DIM);
      convT_kernel<<<dim3((IN_DIM + HID_DIM) / 256, OUT_DIM), 256, 0, stream>>>(
          gcn_W, gWt_hi, gWt_lo, IN_DIM + HID_DIM, OUT_DIM);
      mfma_gemm_kernel<true, 2><<<dim3(HID_DIM / 128, (N_NODES + 127) / 128), 256, 0, stream>>>(
          agg, agg, IN_DIM, fWt_hi, fWt_lo, f_b, h1, N_NODES, IN_DIM, HID_DIM);
      mfma_gemm_kernel<false, 1><<<dim3(OUT_DIM / 64, (N_NODES + 127) / 128), 256, 0, stream>>>(
          x, h1, IN_DIM, gWt_hi, gWt_lo, nullptr, h, N_NODES, IN_DIM + HID_DIM, OUT_DIM);
    }
    gcn_gather_kernel<<<N_NODES, 64, 0, stream>>>(h, irow, icol, dis, gcn_b, outg);
    decode_kernel<<<N_NODES / DEC_NODES, 128, 0, stream>>>(outg, d1_W, d1_b, d2_W, d2_b, out);
  }
}

// Round 8
// 231.304 us; speedup vs baseline: 1.1302x; 1.0246x over previous
//
#include <hip/hip_runtime.h>

#define N_NODES 10000
#define E_EDGES 160000
#define IN_DIM  512
#define HID_DIM 512
#define OUT_DIM 256
#define MB_T    157   // ceil(10000/64) row tiles

typedef __attribute__((ext_vector_type(8))) short short8;
typedef __attribute__((ext_vector_type(16))) float f32x16;
typedef unsigned short u16;

__device__ __forceinline__ u16 f2bh(float f) {
  union { float f; unsigned u; } v; v.f = f;
  return (u16)((v.u + 0x7FFFu + ((v.u >> 16) & 1u)) >> 16);
}
__device__ __forceinline__ float bh2f(u16 h) {
  union { unsigned u; float f; } v; v.u = ((unsigned)h) << 16;
  return v.f;
}

// tiled layout: chunk c within tile (mb,kt): row=(c>>7)*32+(c&31),
// k=((c>>6)&1)*16+((c>>5)&1)*8 (+0..7). u16 index of chunk start:
__device__ __forceinline__ size_t tidx(int mb, int ktTot, int kt, int c) {
  return ((size_t)(mb * ktTot + kt) * 256 + c) * 8;
}

#define GL_LDS(gsrc, ldst)                                                      \
  __builtin_amdgcn_global_load_lds(                                             \
      (const __attribute__((address_space(1))) unsigned int*)(gsrc),            \
      (__attribute__((address_space(3))) unsigned int*)(ldst), 16, 0, 0)

// ===========================================================================
// CSR build
// ===========================================================================
__global__ void count_kernel(const int* __restrict__ dst, int* __restrict__ cnt) {
  int e = blockIdx.x * 256 + threadIdx.x;
  if (e < E_EDGES) atomicAdd(&cnt[dst[e]], 1);
}

__global__ __launch_bounds__(1024) void scan_kernel(
    int* __restrict__ cnt, int* __restrict__ row, float* __restrict__ dis) {
  __shared__ int sums[1024];
  const int CH = 10;
  int t = threadIdx.x;
  int c[CH], excl[CH];
  int s = 0;
#pragma unroll
  for (int j = 0; j < CH; ++j) {
    int idx = t * CH + j;
    c[j] = (idx < N_NODES) ? cnt[idx] : 0;
    excl[j] = s;
    s += c[j];
  }
  sums[t] = s;
  __syncthreads();
  for (int off = 1; off < 1024; off <<= 1) {
    int v = (t >= off) ? sums[t - off] : 0;
    __syncthreads();
    if (t >= off) sums[t] += v;
    __syncthreads();
  }
  int base = (t == 0) ? 0 : sums[t - 1];
#pragma unroll
  for (int j = 0; j < CH; ++j) {
    int idx = t * CH + j;
    if (idx < N_NODES) {
      int start = base + excl[j];
      row[idx] = start;
      cnt[idx] = start;
      dis[idx] = rsqrtf((float)c[j] + 1.0f);
    }
  }
  if (t == 1023) row[N_NODES] = sums[1023];
}

__global__ void place_kernel(const int* __restrict__ src, const int* __restrict__ dst,
                             int* __restrict__ cursor, int* __restrict__ col) {
  int e = blockIdx.x * 256 + threadIdx.x;
  if (e < E_EDGES) {
    int pos = atomicAdd(&cursor[dst[e]], 1);
    col[pos] = src[e];
  }
}

// ===========================================================================
// pack x: fp32 row-major -> tiled bf16 hi/lo (ktTot=16). 128 thr/node.
// ===========================================================================
__global__ __launch_bounds__(128) void pack_x_kernel(
    const float* __restrict__ x, u16* __restrict__ hi, u16* __restrict__ lo) {
  int i = blockIdx.x, t = threadIdx.x;
  int k0 = t * 4;
  float4 v = *reinterpret_cast<const float4*>(x + (size_t)i * IN_DIM + k0);
  float a[4] = {v.x, v.y, v.z, v.w};
  ushort4 h4, l4;
  u16* hp = &h4.x; u16* lp = &l4.x;
#pragma unroll
  for (int j = 0; j < 4; ++j) {
    u16 hh = f2bh(a[j]);
    hp[j] = hh;
    lp[j] = f2bh(a[j] - bh2f(hh));
  }
  int mb = i >> 6, rl = i & 63;
  int kt = k0 >> 5, si = (k0 >> 4) & 1, kh = (k0 >> 3) & 1;
  int c = (rl >> 5) * 128 + si * 64 + kh * 32 + (rl & 31);
  size_t idx = tidx(mb, IN_DIM / 32, kt, c) + (k0 & 7);
  *reinterpret_cast<ushort4*>(hi + idx) = h4;
  *reinterpret_cast<ushort4*>(lo + idx) = l4;
}

// ===========================================================================
// GIN gather -> tiled bf16 hi/lo agg. 4-way edge unroll for MLP.
// ===========================================================================
__global__ __launch_bounds__(128) void gin_gather_bf(
    const float* __restrict__ x, const int* __restrict__ row,
    const int* __restrict__ col, u16* __restrict__ agg_hi,
    u16* __restrict__ agg_lo) {
  int i = blockIdx.x, t = threadIdx.x;
  int beg = row[i], end = row[i + 1];
  int k0 = t * 4;
  const float* xk = x + k0;
  float4 a0{0.f, 0.f, 0.f, 0.f}, a1{0.f, 0.f, 0.f, 0.f};
  float4 a2{0.f, 0.f, 0.f, 0.f}, a3{0.f, 0.f, 0.f, 0.f};
  int e = beg;
  for (; e + 4 <= end; e += 4) {
    int s0 = col[e], s1 = col[e + 1], s2 = col[e + 2], s3 = col[e + 3];
    float4 v0 = *reinterpret_cast<const float4*>(xk + (size_t)s0 * IN_DIM);
    float4 v1 = *reinterpret_cast<const float4*>(xk + (size_t)s1 * IN_DIM);
    float4 v2 = *reinterpret_cast<const float4*>(xk + (size_t)s2 * IN_DIM);
    float4 v3 = *reinterpret_cast<const float4*>(xk + (size_t)s3 * IN_DIM);
    a0.x += v0.x; a0.y += v0.y; a0.z += v0.z; a0.w += v0.w;
    a1.x += v1.x; a1.y += v1.y; a1.z += v1.z; a1.w += v1.w;
    a2.x += v2.x; a2.y += v2.y; a2.z += v2.z; a2.w += v2.w;
    a3.x += v3.x; a3.y += v3.y; a3.z += v3.z; a3.w += v3.w;
  }
  for (; e < end; ++e) {
    int s = col[e];
    float4 v = *reinterpret_cast<const float4*>(xk + (size_t)s * IN_DIM);
    a0.x += v.x; a0.y += v.y; a0.z += v.z; a0.w += v.w;
  }
  float a[4] = {a0.x + a1.x + a2.x + a3.x, a0.y + a1.y + a2.y + a3.y,
                a0.z + a1.z + a2.z + a3.z, a0.w + a1.w + a2.w + a3.w};
  ushort4 h4, l4;
  u16* hp = &h4.x; u16* lp = &l4.x;
#pragma unroll
  for (int j = 0; j < 4; ++j) {
    u16 hh = f2bh(a[j]);
    hp[j] = hh;
    lp[j] = f2bh(a[j] - bh2f(hh));
  }
  int mb = i >> 6, rl = i & 63;
  int kt = k0 >> 5, si = (k0 >> 4) & 1, kh = (k0 >> 3) & 1;
  int c = (rl >> 5) * 128 + si * 64 + kh * 32 + (rl & 31);
  size_t idx = tidx(mb, IN_DIM / 32, kt, c) + (k0 & 7);
  *reinterpret_cast<ushort4*>(agg_hi + idx) = h4;
  *reinterpret_cast<ushort4*>(agg_lo + idx) = l4;
}

// ===========================================================================
// GCN gather (fp32 h), fused self-loop + bias. 4-way edge unroll.
// ===========================================================================
__global__ __launch_bounds__(64) void gcn_gather_kernel(
    const float* __restrict__ h, const int* __restrict__ row,
    const int* __restrict__ col, const float* __restrict__ dis,
    const float* __restrict__ gcn_b, float* __restrict__ outg) {
  int i = blockIdx.x, t = threadIdx.x;
  int beg = row[i], end = row[i + 1];
  float di = dis[i];
  const float* hk = h + t * 4;
  float4 a0{0.f, 0.f, 0.f, 0.f}, a1{0.f, 0.f, 0.f, 0.f};
  float4 a2{0.f, 0.f, 0.f, 0.f}, a3{0.f, 0.f, 0.f, 0.f};
  int e = beg;
  for (; e + 4 <= end; e += 4) {
    int s0 = col[e], s1 = col[e + 1], s2 = col[e + 2], s3 = col[e + 3];
    float w0 = dis[s0], w1 = dis[s1], w2 = dis[s2], w3 = dis[s3];
    float4 v0 = *reinterpret_cast<const float4*>(hk + (size_t)s0 * OUT_DIM);
    float4 v1 = *reinterpret_cast<const float4*>(hk + (size_t)s1 * OUT_DIM);
    float4 v2 = *reinterpret_cast<const float4*>(hk + (size_t)s2 * OUT_DIM);
    float4 v3 = *reinterpret_cast<const float4*>(hk + (size_t)s3 * OUT_DIM);
    a0.x += w0 * v0.x; a0.y += w0 * v0.y; a0.z += w0 * v0.z; a0.w += w0 * v0.w;
    a1.x += w1 * v1.x; a1.y += w1 * v1.y; a1.z += w1 * v1.z; a1.w += w1 * v1.w;
    a2.x += w2 * v2.x; a2.y += w2 * v2.y; a2.z += w2 * v2.z; a2.w += w2 * v2.w;
    a3.x += w3 * v3.x; a3.y += w3 * v3.y; a3.z += w3 * v3.z; a3.w += w3 * v3.w;
  }
  for (; e < end; ++e) {
    int s = col[e];
    float w = dis[s];
    float4 v = *reinterpret_cast<const float4*>(hk + (size_t)s * OUT_DIM);
    a0.x += w * v.x; a0.y += w * v.y; a0.z += w * v.z; a0.w += w * v.w;
  }
  float4 acc{a0.x + a1.x + a2.x + a3.x, a0.y + a1.y + a2.y + a3.y,
             a0.z + a1.z + a2.z + a3.z, a0.w + a1.w + a2.w + a3.w};
  float4 hv = *reinterpret_cast<const float4*>(h + (size_t)i * OUT_DIM + t * 4);
  float4 bv = *reinterpret_cast<const float4*>(gcn_b + t * 4);
  float self = di * di;
  float4 o{di * acc.x + self * hv.x + bv.x, di * acc.y + self * hv.y + bv.y,
           di * acc.z + self * hv.z + bv.z, di * acc.w + self * hv.w + bv.w};
  *reinterpret_cast<float4*>(outg + (size_t)i * OUT_DIM + t * 4) = o;
}

// ===========================================================================
// Weight transpose + split -> tiled: W [K][N] fp32 -> Wt tiled by col.
// ===========================================================================
__global__ __launch_bounds__(256) void convT_tiled(
    const float* __restrict__ W, u16* __restrict__ hi, u16* __restrict__ lo,
    int K, int N) {
  __shared__ float tile[64][65];
  int k0g = blockIdx.x * 64, n0 = blockIdx.y * 64;
  int t = threadIdx.x;
  int lk = t >> 4, ln = (t & 15) * 4;
#pragma unroll
  for (int p = 0; p < 4; ++p) {
    float4 v = *reinterpret_cast<const float4*>(W + (size_t)(k0g + p * 16 + lk) * N + n0 + ln);
    tile[p * 16 + lk][ln + 0] = v.x;
    tile[p * 16 + lk][ln + 1] = v.y;
    tile[p * 16 + lk][ln + 2] = v.z;
    tile[p * 16 + lk][ln + 3] = v.w;
  }
  __syncthreads();
  int on = t >> 2;
  int ok = (t & 3) * 16;
  int colg = n0 + on;
  int nb = colg >> 6, rl = colg & 63;
  int ktTot = K >> 5;
#pragma unroll
  for (int q = 0; q < 4; ++q) {
    int kg = k0g + ok + q * 4;
    ushort4 h4, l4;
    u16* hq = &h4.x; u16* lq = &l4.x;
#pragma unroll
    for (int j = 0; j < 4; ++j) {
      float v = tile[ok + q * 4 + j][on];
      u16 hh = f2bh(v);
      hq[j] = hh;
      lq[j] = f2bh(v - bh2f(hh));
    }
    int kt = kg >> 5, si = (kg >> 4) & 1, kh = (kg >> 3) & 1;
    int c = (rl >> 5) * 128 + si * 64 + kh * 32 + (rl & 31);
    size_t idx = tidx(nb, ktTot, kt, c) + (kg & 7);
    *reinterpret_cast<ushort4*>(hi + idx) = h4;
    *reinterpret_cast<ushort4*>(lo + idx) = l4;
  }
}

// ===========================================================================
// MFMA GEMM v4: tiled bf16 inputs, contiguous global_load_lds staging,
// double-buffered. BM=64 BN=64 BK=32, 4 waves 2x2. 2 acc chains.
// ===========================================================================
template <bool BIAS, bool OUT_TILED>
__global__ __launch_bounds__(256) void mfma_gemm4(
    const u16* __restrict__ Ah0, const u16* __restrict__ Al0,
    const u16* __restrict__ Ah1, const u16* __restrict__ Al1, int kSplit,
    const u16* __restrict__ Bh, const u16* __restrict__ Bl,
    const float* __restrict__ bias, float* __restrict__ C,
    u16* __restrict__ Ch, u16* __restrict__ Cl, int M, int K, int N) {
  __shared__ short8 S[2][1024];  // 32 KB

  int t = threadIdx.x, w = t >> 6, l = t & 63;
  int wr = w >> 1, wc = w & 1;
  int mb = blockIdx.y, nb = blockIdx.x;
  int brow = mb * 64, bcol = nb * 64;
  int cid = w * 64 + l;

  f32x16 acc0, acc1;
#pragma unroll
  for (int r = 0; r < 16; ++r) { acc0[r] = 0.f; acc1[r] = 0.f; }

  int nt = K / 32;
  int ktTotB = K >> 5;
  int ktTot0 = kSplit >> 5;
  int ktTot1 = (K - kSplit) >> 5;

#define STAGE(BUF, K0)                                                         \
  {                                                                            \
    const u16 *Ah, *Al; size_t abase;                                          \
    if ((K0) < kSplit) {                                                       \
      Ah = Ah0; Al = Al0; abase = tidx(mb, ktTot0, (K0) >> 5, cid);            \
    } else {                                                                   \
      Ah = Ah1; Al = Al1; abase = tidx(mb, ktTot1, ((K0) - kSplit) >> 5, cid); \
    }                                                                          \
    size_t bbase = tidx(nb, ktTotB, (K0) >> 5, cid);                           \
    short8* base = &S[BUF][0] + w * 64;                                        \
    GL_LDS(Ah + abase, base);                                                  \
    GL_LDS(Al + abase, base + 256);                                            \
    GL_LDS(Bh + bbase, base + 512);                                            \
    GL_LDS(Bl + bbase, base + 768);                                            \
  }

  STAGE(0, 0)
  for (int ti = 0; ti < nt; ++ti) {
    int b = ti & 1;
    __syncthreads();
    if (ti + 1 < nt) STAGE(b ^ 1, (ti + 1) * 32)
    {
      short8 ah = S[b][wr * 128 + l];
      short8 al = S[b][256 + wr * 128 + l];
      short8 bh = S[b][512 + wc * 128 + l];
      short8 bl = S[b][768 + wc * 128 + l];
      acc0 = __builtin_amdgcn_mfma_f32_32x32x16_bf16(ah, bh, acc0, 0, 0, 0);
      acc0 = __builtin_amdgcn_mfma_f32_32x32x16_bf16(al, bh, acc0, 0, 0, 0);
      acc0 = __builtin_amdgcn_mfma_f32_32x32x16_bf16(ah, bl, acc0, 0, 0, 0);
    }
    {
      short8 ah = S[b][wr * 128 + 64 + l];
      short8 al = S[b][256 + wr * 128 + 64 + l];
      short8 bh = S[b][512 + wc * 128 + 64 + l];
      short8 bl = S[b][768 + wc * 128 + 64 + l];
      acc1 = __builtin_amdgcn_mfma_f32_32x32x16_bf16(ah, bh, acc1, 0, 0, 0);
      acc1 = __builtin_amdgcn_mfma_f32_32x32x16_bf16(al, bh, acc1, 0, 0, 0);
      acc1 = __builtin_amdgcn_mfma_f32_32x32x16_bf16(ah, bl, acc1, 0, 0, 0);
    }
  }
#undef STAGE

  f32x16 acc = acc0 + acc1;

  int r0l = wr * 32 + 4 * (l >> 5);
  int c0l = wc * 32 + (l & 31);

  if (OUT_TILED) {
    __syncthreads();
    u16* Hhi = (u16*)&S[0][0];
    u16* Hlo = Hhi + 4096;
    float badd = BIAS ? bias[bcol + c0l] : 0.f;
#pragma unroll
    for (int r = 0; r < 16; ++r) {
      int rl = r0l + (r & 3) + 8 * (r >> 2);
      float v = acc[r] + badd;
      u16 hh = f2bh(v);
      Hhi[rl * 64 + c0l] = hh;
      Hlo[rl * 64 + c0l] = f2bh(v - bh2f(hh));
    }
    __syncthreads();
    int ktTot = N >> 5;
#pragma unroll
    for (int pl = 0; pl < 2; ++pl) {
      const u16* Hs = pl ? Hlo : Hhi;
      u16* dA = pl ? Cl : Ch;
#pragma unroll
      for (int j = 0; j < 2; ++j) {
        int ci = t + j * 256;
        int ktl = ci >> 8;
        int c = ci & 255;
        int r = ((c >> 7) & 1) * 32 + (c & 31);
        int kloc = ktl * 32 + ((c >> 6) & 1) * 16 + ((c >> 5) & 1) * 8;
        short8 v = *reinterpret_cast<const short8*>(Hs + r * 64 + kloc);
        size_t db = tidx(mb, ktTot, (bcol >> 5) + ktl, c);
        *reinterpret_cast<short8*>(dA + db) = v;
      }
    }
  } else {
    int colg = bcol + c0l;
    float badd = BIAS ? bias[colg] : 0.f;
#pragma unroll
    for (int r = 0; r < 16; ++r) {
      int rowg = brow + r0l + (r & 3) + 8 * (r >> 2);
      if (rowg < M) C[(size_t)rowg * N + colg] = acc[r] + badd;
    }
  }
}

// ===========================================================================
// decode MLP: 8 nodes per block
// ===========================================================================
#define DEC_NODES 8
__global__ __launch_bounds__(128) void decode_kernel(
    const float* __restrict__ outg, const float* __restrict__ d1_W,
    const float* __restrict__ d1_b, const float* __restrict__ d2_W,
    const float* __restrict__ d2_b, float* __restrict__ z1) {
  __shared__ float rows[DEC_NODES][OUT_DIM];
  __shared__ float s0[128], s1[128];
  int t = threadIdx.x;
  int n0 = blockIdx.x * DEC_NODES;
#pragma unroll
  for (int j = 0; j < 4; ++j) {
    int idx = j * 512 + t * 4;
    *reinterpret_cast<float4*>(&rows[0][idx]) =
        *reinterpret_cast<const float4*>(outg + (size_t)n0 * OUT_DIM + idx);
  }
  __syncthreads();
  float acc[DEC_NODES];
  float b1 = d1_b[t];
#pragma unroll
  for (int n = 0; n < DEC_NODES; ++n) acc[n] = b1;
#pragma unroll 4
  for (int k = 0; k < OUT_DIM; ++k) {
    float wv = d1_W[k * 128 + t];
#pragma unroll
    for (int n = 0; n < DEC_NODES; ++n) acc[n] += rows[n][k] * wv;
  }
  float w0 = d2_W[t * 2 + 0], w1 = d2_W[t * 2 + 1];
  for (int n = 0; n < DEC_NODES; ++n) {
    float a = fmaxf(acc[n], 0.f);
    s0[t] = a * w0;
    s1[t] = a * w1;
    __syncthreads();
    for (int off = 64; off > 0; off >>= 1) {
      if (t < off) {
        s0[t] += s0[t + off];
        s1[t] += s1[t + off];
      }
      __syncthreads();
    }
    if (t == 0) {
      z1[(size_t)(n0 + n) * 2 + 0] = s0[0] + d2_b[0];
      z1[(size_t)(n0 + n) * 2 + 1] = s1[0] + d2_b[1];
    }
    __syncthreads();
  }
}

// ===========================================================================
// Tier-2 fallback (round-5 proven path)
// ===========================================================================
__global__ __launch_bounds__(128) void gin_gather_kernel(
    const float* __restrict__ x, const int* __restrict__ row,
    const int* __restrict__ col, float* __restrict__ agg) {
  int i = blockIdx.x, t = threadIdx.x;
  int beg = row[i], end = row[i + 1];
  float4 acc{0.f, 0.f, 0.f, 0.f};
  for (int e = beg; e < end; ++e) {
    int s = col[e];
    float4 v = *reinterpret_cast<const float4*>(x + (size_t)s * IN_DIM + t * 4);
    acc.x += v.x; acc.y += v.y; acc.z += v.z; acc.w += v.w;
  }
  *reinterpret_cast<float4*>(agg + (size_t)i * IN_DIM + t * 4) = acc;
}

__global__ void convT_kernel(const float* __restrict__ W, u16* __restrict__ hi,
                             u16* __restrict__ lo, int K, int N) {
  int k = blockIdx.x * 256 + threadIdx.x;
  int n = blockIdx.y;
  float a = W[(size_t)k * N + n];
  u16 h = f2bh(a);
  hi[(size_t)n * K + k] = h;
  lo[(size_t)n * K + k] = f2bh(a - bh2f(h));
}

template <bool BIAS, int NW>
__global__ __launch_bounds__(256) void mfma_gemm_kernel(
    const float* __restrict__ A0, const float* __restrict__ A1, int kSplit,
    const u16* __restrict__ Wt_hi, const u16* __restrict__ Wt_lo,
    const float* __restrict__ bias, float* __restrict__ C,
    int M, int K, int N) {
  __shared__ short8 Ahi[512];
  __shared__ short8 Alo[512];
  __shared__ short8 Bhi[NW * 256];
  __shared__ short8 Blo[NW * 256];
  int t = threadIdx.x;
  int w = t >> 6, l = t & 63;
  int wr = w >> 1, wc = w & 1;
  int brow = blockIdx.y * 128, bcol = blockIdx.x * (NW * 64);
  f32x16 acc[2][NW];
#pragma unroll
  for (int m = 0; m < 2; ++m)
#pragma unroll
    for (int n = 0; n < NW; ++n)
#pragma unroll
      for (int r = 0; r < 16; ++r) acc[m][n][r] = 0.f;
  for (int k0 = 0; k0 < K; k0 += 32) {
    const float* Ap; int kk, lda;
    if (k0 < kSplit) { Ap = A0; kk = k0; lda = kSplit; }
    else             { Ap = A1; kk = k0 - kSplit; lda = K - kSplit; }
#pragma unroll
    for (int cc = 0; cc < 2; ++cc) {
      int c = t + cc * 256;
      int mt = c >> 7, si = (c >> 6) & 1, kh = (c >> 5) & 1, lr = c & 31;
      int arow = brow + mt * 32 + lr;
      int ak = kk + si * 16 + kh * 8;
      short8 ph, pl;
      if (arow < M) {
        const float* p = Ap + (size_t)arow * lda + ak;
        float4 u0 = *reinterpret_cast<const float4*>(p);
        float4 u1 = *reinterpret_cast<const float4*>(p + 4);
        float va[8] = {u0.x, u0.y, u0.z, u0.w, u1.x, u1.y, u1.z, u1.w};
#pragma unroll
        for (int j = 0; j < 8; ++j) {
          u16 hh = f2bh(va[j]);
          ph[j] = (short)hh;
          pl[j] = (short)f2bh(va[j] - bh2f(hh));
        }
      } else {
#pragma unroll
        for (int j = 0; j < 8; ++j) { ph[j] = 0; pl[j] = 0; }
      }
      Ahi[c] = ph;
      Alo[c] = pl;
    }
#pragma unroll
    for (int cc = 0; cc < NW; ++cc) {
      int c = t + cc * 256;
      int nt2 = c >> 7, si = (c >> 6) & 1, kh = (c >> 5) & 1, lc = c & 31;
      int bcl = bcol + nt2 * 32 + lc;
      size_t off = (size_t)bcl * K + k0 + si * 16 + kh * 8;
      Bhi[c] = *reinterpret_cast<const short8*>(Wt_hi + off);
      Blo[c] = *reinterpret_cast<const short8*>(Wt_lo + off);
    }
    __syncthreads();
#pragma unroll
    for (int si = 0; si < 2; ++si) {
      short8 ah[2], al[2], bh[NW], bl[NW];
#pragma unroll
      for (int m = 0; m < 2; ++m) {
        int c = (wr * 2 + m) * 128 + si * 64 + l;
        ah[m] = Ahi[c];
        al[m] = Alo[c];
      }
#pragma unroll
      for (int n = 0; n < NW; ++n) {
        int c = (wc * NW + n) * 128 + si * 64 + l;
        bh[n] = Bhi[c];
        bl[n] = Blo[c];
      }
#pragma unroll
      for (int m = 0; m < 2; ++m)
#pragma unroll
        for (int n = 0; n < NW; ++n) {
          acc[m][n] = __builtin_amdgcn_mfma_f32_32x32x16_bf16(ah[m], bh[n], acc[m][n], 0, 0, 0);
          acc[m][n] = __builtin_amdgcn_mfma_f32_32x32x16_bf16(al[m], bh[n], acc[m][n], 0, 0, 0);
          acc[m][n] = __builtin_amdgcn_mfma_f32_32x32x16_bf16(ah[m], bl[n], acc[m][n], 0, 0, 0);
        }
    }
    __syncthreads();
  }
#pragma unroll
  for (int m = 0; m < 2; ++m) {
    int r0 = brow + (wr * 2 + m) * 32 + 4 * (l >> 5);
#pragma unroll
    for (int n = 0; n < NW; ++n) {
      int colg = bcol + (wc * NW + n) * 32 + (l & 31);
      float badd = BIAS ? bias[colg] : 0.f;
#pragma unroll
      for (int r = 0; r < 16; ++r) {
        int rowg = r0 + (r & 3) + 8 * (r >> 2);
        if (rowg < M) C[(size_t)rowg * N + colg] = acc[m][n][r] + badd;
      }
    }
  }
}

// ===========================================================================
extern "C" void kernel_launch(void* const* d_in, const int* in_sizes, int n_in,
                              void* d_out, int out_size, void* d_ws, size_t ws_size,
                              hipStream_t stream) {
  const float* x     = (const float*)d_in[0];
  const int*   edge  = (const int*)d_in[1];
  const float* f_W   = (const float*)d_in[2];
  const float* f_b   = (const float*)d_in[3];
  const float* gcn_W = (const float*)d_in[4];
  const float* gcn_b = (const float*)d_in[5];
  const float* d1_W  = (const float*)d_in[6];
  const float* d1_b  = (const float*)d_in[7];
  const float* d2_W  = (const float*)d_in[8];
  const float* d2_b  = (const float*)d_in[9];
  float* out = (float*)d_out;
  char*  wsb = (char*)d_ws;

  const int* src = edge;
  const int* dst = edge + E_EDGES;

  // -------- v4 layout (bytes) --------
  const size_t TS = (size_t)MB_T * 16 * 256 * 8 * sizeof(u16);
  u16* x_hi   = (u16*)(wsb + 0 * TS);
  u16* x_lo   = (u16*)(wsb + 1 * TS);
  u16* agg_hi = (u16*)(wsb + 2 * TS);
  u16* agg_lo = (u16*)(wsb + 3 * TS);
  u16* h1_hi  = (u16*)(wsb + 4 * TS);
  u16* h1_lo  = (u16*)(wsb + 5 * TS);
  float* hbuf4 = (float*)(wsb + 2 * TS);
  float* outg4 = (float*)(wsb + 3 * TS);
  size_t o = 6 * TS;
  float* dis4  = (float*)(wsb + o); o += (size_t)N_NODES * 4;
  int*   icnt4 = (int*)(wsb + o);   o += (size_t)N_NODES * 4;
  int*   irow4 = (int*)(wsb + o);   o += (size_t)(N_NODES + 1) * 4 + 12;
  int*   icol4 = (int*)(wsb + o);   o += (size_t)E_EDGES * 4;
  u16*   fWt_hi4 = (u16*)(wsb + o); o += (size_t)8 * 16 * 256 * 8 * 2;
  u16*   fWt_lo4 = (u16*)(wsb + o); o += (size_t)8 * 16 * 256 * 8 * 2;
  u16*   gWt_hi4 = (u16*)(wsb + o); o += (size_t)4 * 32 * 256 * 8 * 2;
  u16*   gWt_lo4 = (u16*)(wsb + o); o += (size_t)4 * 32 * 256 * 8 * 2;
  const size_t v4_needed = o;

  // -------- tier-2 layout --------
  float* ws = (float*)d_ws;
  float* agg  = ws;
  float* h1   = ws + (size_t)512 * N_NODES;
  float* dis  = ws + (size_t)1024 * N_NODES;
  float* h    = ws;
  float* outg = ws + (size_t)256 * N_NODES;
  int* icount = (int*)(ws + (size_t)1025 * N_NODES);
  int* irow   = icount + N_NODES;
  int* icol   = irow + N_NODES + 1;
  size_t csr_needed = (size_t)1025 * N_NODES * sizeof(float) +
                      (size_t)(2 * N_NODES + 1 + E_EDGES) * sizeof(int);
  const size_t WELEMS = 512 * 512;
  size_t usOff = (csr_needed + 15) & ~(size_t)15;
  u16* fWt_hi = (u16*)(wsb + usOff);
  u16* fWt_lo = fWt_hi + WELEMS;
  u16* gWt_hi = fWt_lo + WELEMS;
  u16* gWt_lo = gWt_hi + WELEMS;
  size_t t2_needed = usOff + 4 * WELEMS * sizeof(u16);

  if (ws_size >= v4_needed) {
    // ======== v4 path ========
    hipMemsetAsync(icnt4, 0, (size_t)N_NODES * sizeof(int), stream);
    count_kernel<<<(E_EDGES + 255) / 256, 256, 0, stream>>>(dst, icnt4);
    scan_kernel<<<1, 1024, 0, stream>>>(icnt4, irow4, dis4);
    place_kernel<<<(E_EDGES + 255) / 256, 256, 0, stream>>>(src, dst, icnt4, icol4);

    pack_x_kernel<<<N_NODES, 128, 0, stream>>>(x, x_hi, x_lo);
    convT_tiled<<<dim3(IN_DIM / 64, HID_DIM / 64), 256, 0, stream>>>(
        f_W, fWt_hi4, fWt_lo4, IN_DIM, HID_DIM);
    convT_tiled<<<dim3((IN_DIM + HID_DIM) / 64, OUT_DIM / 64), 256, 0, stream>>>(
        gcn_W, gWt_hi4, gWt_lo4, IN_DIM + HID_DIM, OUT_DIM);

    gin_gather_bf<<<N_NODES, 128, 0, stream>>>(x, irow4, icol4, agg_hi, agg_lo);

    mfma_gemm4<true, true><<<dim3(HID_DIM / 64, MB_T), 256, 0, stream>>>(
        agg_hi, agg_lo, agg_hi, agg_lo, IN_DIM, fWt_hi4, fWt_lo4, f_b,
        nullptr, h1_hi, h1_lo, N_NODES, IN_DIM, HID_DIM);

    mfma_gemm4<false, false><<<dim3(OUT_DIM / 64, MB_T), 256, 0, stream>>>(
        x_hi, x_lo, h1_hi, h1_lo, IN_DIM, gWt_hi4, gWt_lo4, nullptr,
        hbuf4, nullptr, nullptr, N_NODES, IN_DIM + HID_DIM, OUT_DIM);

    gcn_gather_kernel<<<N_NODES, 64, 0, stream>>>(hbuf4, irow4, icol4, dis4, gcn_b, outg4);
    decode_kernel<<<N_NODES / DEC_NODES, 128, 0, stream>>>(outg4, d1_W, d1_b, d2_W, d2_b, out);
  } else {
    // ======== tier-2 (round-5 proven) ========
    hipMemsetAsync(icount, 0, (size_t)N_NODES * sizeof(int), stream);
    count_kernel<<<(E_EDGES + 255) / 256, 256, 0, stream>>>(dst, icount);
    scan_kernel<<<1, 1024, 0, stream>>>(icount, irow, dis);
    place_kernel<<<(E_EDGES + 255) / 256, 256, 0, stream>>>(src, dst, icount, icol);
    gin_gather_kernel<<<N_NODES, 128, 0, stream>>>(x, irow, icol, agg);
    if (ws_size >= t2_needed) {
      convT_kernel<<<dim3(IN_DIM / 256, HID_DIM), 256, 0, stream>>>(
          f_W, fWt_hi, fWt_lo, IN_DIM, HID_DIM);
      convT_kernel<<<dim3((IN_DIM + HID_DIM) / 256, OUT_DIM), 256, 0, stream>>>(
          gcn_W, gWt_hi, gWt_lo, IN_DIM + HID_DIM, OUT_DIM);
      mfma_gemm_kernel<true, 2><<<dim3(HID_DIM / 128, (N_NODES + 127) / 128), 256, 0, stream>>>(
          agg, agg, IN_DIM, fWt_hi, fWt_lo, f_b, h1, N_NODES, IN_DIM, HID_DIM);
      mfma_gemm_kernel<false, 1><<<dim3(OUT_DIM / 64, (N_NODES + 127) / 128), 256, 0, stream>>>(
          x, h1, IN_DIM, gWt_hi, gWt_lo, nullptr, h, N_NODES, IN_DIM + HID_DIM, OUT_DIM);
    }
    gcn_gather_kernel<<<N_NODES, 64, 0, stream>>>(h, irow, icol, dis, gcn_b, outg);
    decode_kernel<<<N_NODES / DEC_NODES, 128, 0, stream>>>(outg, d1_W, d1_b, d2_W, d2_b, out);
  }
}

// Round 9
// 197.619 us; speedup vs baseline: 1.3229x; 1.1705x over previous
//
#include <hip/hip_runtime.h>

#define N_NODES 10000
#define E_EDGES 160000
#define IN_DIM  512
#define HID_DIM 512
#define OUT_DIM 256
#define MB_T    157   // ceil(10000/64) row tiles

typedef __attribute__((ext_vector_type(8))) short short8;
typedef __attribute__((ext_vector_type(16))) float f32x16;
typedef unsigned short u16;

__device__ __forceinline__ u16 f2bh(float f) {
  union { float f; unsigned u; } v; v.f = f;
  return (u16)((v.u + 0x7FFFu + ((v.u >> 16) & 1u)) >> 16);
}
__device__ __forceinline__ float bh2f(u16 h) {
  union { unsigned u; float f; } v; v.u = ((unsigned)h) << 16;
  return v.f;
}

// tiled layout: chunk c within tile (mb,kt): row=(c>>7)*32+(c&31),
// k=((c>>6)&1)*16+((c>>5)&1)*8 (+0..7). u16 index of chunk start:
__device__ __forceinline__ size_t tidx(int mb, int ktTot, int kt, int c) {
  return ((size_t)(mb * ktTot + kt) * 256 + c) * 8;
}

#define GL_LDS(gsrc, ldst)                                                      \
  __builtin_amdgcn_global_load_lds(                                             \
      (const __attribute__((address_space(1))) unsigned int*)(gsrc),            \
      (__attribute__((address_space(3))) unsigned int*)(ldst), 16, 0, 0)

// ===========================================================================
// CSR build
// ===========================================================================
__global__ void count_kernel(const int* __restrict__ dst, int* __restrict__ cnt) {
  int e = blockIdx.x * 256 + threadIdx.x;
  if (e < E_EDGES) atomicAdd(&cnt[dst[e]], 1);
}

__global__ __launch_bounds__(1024) void scan_kernel(
    int* __restrict__ cnt, int* __restrict__ row, float* __restrict__ dis) {
  __shared__ int sums[1024];
  const int CH = 10;
  int t = threadIdx.x;
  int c[CH], excl[CH];
  int s = 0;
#pragma unroll
  for (int j = 0; j < CH; ++j) {
    int idx = t * CH + j;
    c[j] = (idx < N_NODES) ? cnt[idx] : 0;
    excl[j] = s;
    s += c[j];
  }
  sums[t] = s;
  __syncthreads();
  for (int off = 1; off < 1024; off <<= 1) {
    int v = (t >= off) ? sums[t - off] : 0;
    __syncthreads();
    if (t >= off) sums[t] += v;
    __syncthreads();
  }
  int base = (t == 0) ? 0 : sums[t - 1];
#pragma unroll
  for (int j = 0; j < CH; ++j) {
    int idx = t * CH + j;
    if (idx < N_NODES) {
      int start = base + excl[j];
      row[idx] = start;
      cnt[idx] = start;
      dis[idx] = rsqrtf((float)c[j] + 1.0f);
    }
  }
  if (t == 1023) row[N_NODES] = sums[1023];
}

__global__ void place_kernel(const int* __restrict__ src, const int* __restrict__ dst,
                             int* __restrict__ cursor, int* __restrict__ col) {
  int e = blockIdx.x * 256 + threadIdx.x;
  if (e < E_EDGES) {
    int pos = atomicAdd(&cursor[dst[e]], 1);
    col[pos] = src[e];
  }
}

// ===========================================================================
// pack: fp32 row-major [M x 512] -> tiled bf16 hi/lo (ktTot=16). grid=M.
// (used for x and for f_W; yields A-tiling of the array / B-tiling of its ^T)
// ===========================================================================
__global__ __launch_bounds__(128) void pack_x_kernel(
    const float* __restrict__ x, u16* __restrict__ hi, u16* __restrict__ lo) {
  int i = blockIdx.x, t = threadIdx.x;
  int k0 = t * 4;
  float4 v = *reinterpret_cast<const float4*>(x + (size_t)i * IN_DIM + k0);
  float a[4] = {v.x, v.y, v.z, v.w};
  ushort4 h4, l4;
  u16* hp = &h4.x; u16* lp = &l4.x;
#pragma unroll
  for (int j = 0; j < 4; ++j) {
    u16 hh = f2bh(a[j]);
    hp[j] = hh;
    lp[j] = f2bh(a[j] - bh2f(hh));
  }
  int mb = i >> 6, rl = i & 63;
  int kt = k0 >> 5, si = (k0 >> 4) & 1, kh = (k0 >> 3) & 1;
  int c = (rl >> 5) * 128 + si * 64 + kh * 32 + (rl & 31);
  size_t idx = tidx(mb, IN_DIM / 32, kt, c) + (k0 & 7);
  *reinterpret_cast<ushort4*>(hi + idx) = h4;
  *reinterpret_cast<ushort4*>(lo + idx) = l4;
}

// ===========================================================================
// Weight transpose + split -> tiled: W [K][N] fp32 -> tiles over cols of W.
// (also serves as A-tiling of W^T)
// ===========================================================================
__global__ __launch_bounds__(256) void convT_tiled(
    const float* __restrict__ W, u16* __restrict__ hi, u16* __restrict__ lo,
    int K, int N) {
  __shared__ float tile[64][65];
  int k0g = blockIdx.x * 64, n0 = blockIdx.y * 64;
  int t = threadIdx.x;
  int lk = t >> 4, ln = (t & 15) * 4;
#pragma unroll
  for (int p = 0; p < 4; ++p) {
    float4 v = *reinterpret_cast<const float4*>(W + (size_t)(k0g + p * 16 + lk) * N + n0 + ln);
    tile[p * 16 + lk][ln + 0] = v.x;
    tile[p * 16 + lk][ln + 1] = v.y;
    tile[p * 16 + lk][ln + 2] = v.z;
    tile[p * 16 + lk][ln + 3] = v.w;
  }
  __syncthreads();
  int on = t >> 2;
  int ok = (t & 3) * 16;
  int colg = n0 + on;
  int nb = colg >> 6, rl = colg & 63;
  int ktTot = K >> 5;
#pragma unroll
  for (int q = 0; q < 4; ++q) {
    int kg = k0g + ok + q * 4;
    ushort4 h4, l4;
    u16* hq = &h4.x; u16* lq = &l4.x;
#pragma unroll
    for (int j = 0; j < 4; ++j) {
      float v = tile[ok + q * 4 + j][on];
      u16 hh = f2bh(v);
      hq[j] = hh;
      lq[j] = f2bh(v - bh2f(hh));
    }
    int kt = kg >> 5, si = (kg >> 4) & 1, kh = (kg >> 3) & 1;
    int c = (rl >> 5) * 128 + si * 64 + kh * 32 + (rl & 31);
    size_t idx = tidx(nb, ktTot, kt, c) + (kg & 7);
    *reinterpret_cast<ushort4*>(hi + idx) = h4;
    *reinterpret_cast<ushort4*>(lo + idx) = l4;
  }
}

// c2 = f_b @ gcn_W[512:,:]   (256 outputs)
__global__ void c2_kernel(const float* __restrict__ f_b,
                          const float* __restrict__ gcn_W, float* __restrict__ c2) {
  int n = threadIdx.x;
  float s = 0.f;
  for (int k = 0; k < HID_DIM; ++k)
    s += f_b[k] * gcn_W[(size_t)(IN_DIM + k) * OUT_DIM + n];
  c2[n] = s;
}

// ===========================================================================
// MFMA GEMM v4: tiled bf16 inputs, contiguous global_load_lds staging,
// double-buffered. BM=64 BN=64 BK=32, 4 waves 2x2. 2 acc chains.
// OUT_TILED writes result as tiles (mb+mbOff, kt over N) -> usable as B-tiles.
// ===========================================================================
template <bool BIAS, bool OUT_TILED>
__global__ __launch_bounds__(256) void mfma_gemm4(
    const u16* __restrict__ Ah0, const u16* __restrict__ Al0,
    const u16* __restrict__ Ah1, const u16* __restrict__ Al1, int kSplit,
    const u16* __restrict__ Bh, const u16* __restrict__ Bl,
    const float* __restrict__ bias, float* __restrict__ C,
    u16* __restrict__ Ch, u16* __restrict__ Cl, int M, int K, int N,
    int mbOff) {
  __shared__ short8 S[2][1024];  // 32 KB

  int t = threadIdx.x, w = t >> 6, l = t & 63;
  int wr = w >> 1, wc = w & 1;
  int mb = blockIdx.y, nb = blockIdx.x;
  int brow = mb * 64, bcol = nb * 64;
  int cid = w * 64 + l;

  f32x16 acc0, acc1;
#pragma unroll
  for (int r = 0; r < 16; ++r) { acc0[r] = 0.f; acc1[r] = 0.f; }

  int nt = K / 32;
  int ktTotB = K >> 5;
  int ktTot0 = kSplit >> 5;
  int ktTot1 = (K - kSplit) >> 5;

#define STAGE(BUF, K0)                                                         \
  {                                                                            \
    const u16 *Ah, *Al; size_t abase;                                          \
    if ((K0) < kSplit) {                                                       \
      Ah = Ah0; Al = Al0; abase = tidx(mb, ktTot0, (K0) >> 5, cid);            \
    } else {                                                                   \
      Ah = Ah1; Al = Al1; abase = tidx(mb, ktTot1, ((K0) - kSplit) >> 5, cid); \
    }                                                                          \
    size_t bbase = tidx(nb, ktTotB, (K0) >> 5, cid);                           \
    short8* base = &S[BUF][0] + w * 64;                                        \
    GL_LDS(Ah + abase, base);                                                  \
    GL_LDS(Al + abase, base + 256);                                            \
    GL_LDS(Bh + bbase, base + 512);                                            \
    GL_LDS(Bl + bbase, base + 768);                                            \
  }

  STAGE(0, 0)
  for (int ti = 0; ti < nt; ++ti) {
    int b = ti & 1;
    __syncthreads();
    if (ti + 1 < nt) STAGE(b ^ 1, (ti + 1) * 32)
    {
      short8 ah = S[b][wr * 128 + l];
      short8 al = S[b][256 + wr * 128 + l];
      short8 bh = S[b][512 + wc * 128 + l];
      short8 bl = S[b][768 + wc * 128 + l];
      acc0 = __builtin_amdgcn_mfma_f32_32x32x16_bf16(ah, bh, acc0, 0, 0, 0);
      acc0 = __builtin_amdgcn_mfma_f32_32x32x16_bf16(al, bh, acc0, 0, 0, 0);
      acc0 = __builtin_amdgcn_mfma_f32_32x32x16_bf16(ah, bl, acc0, 0, 0, 0);
    }
    {
      short8 ah = S[b][wr * 128 + 64 + l];
      short8 al = S[b][256 + wr * 128 + 64 + l];
      short8 bh = S[b][512 + wc * 128 + 64 + l];
      short8 bl = S[b][768 + wc * 128 + 64 + l];
      acc1 = __builtin_amdgcn_mfma_f32_32x32x16_bf16(ah, bh, acc1, 0, 0, 0);
      acc1 = __builtin_amdgcn_mfma_f32_32x32x16_bf16(al, bh, acc1, 0, 0, 0);
      acc1 = __builtin_amdgcn_mfma_f32_32x32x16_bf16(ah, bl, acc1, 0, 0, 0);
    }
  }
#undef STAGE

  f32x16 acc = acc0 + acc1;

  int r0l = wr * 32 + 4 * (l >> 5);
  int c0l = wc * 32 + (l & 31);

  if (OUT_TILED) {
    __syncthreads();
    u16* Hhi = (u16*)&S[0][0];
    u16* Hlo = Hhi + 4096;
    float badd = BIAS ? bias[bcol + c0l] : 0.f;
#pragma unroll
    for (int r = 0; r < 16; ++r) {
      int rl = r0l + (r & 3) + 8 * (r >> 2);
      float v = acc[r] + badd;
      u16 hh = f2bh(v);
      Hhi[rl * 64 + c0l] = hh;
      Hlo[rl * 64 + c0l] = f2bh(v - bh2f(hh));
    }
    __syncthreads();
    int ktTot = N >> 5;
#pragma unroll
    for (int pl = 0; pl < 2; ++pl) {
      const u16* Hs = pl ? Hlo : Hhi;
      u16* dA = pl ? Cl : Ch;
#pragma unroll
      for (int j = 0; j < 2; ++j) {
        int ci = t + j * 256;
        int ktl = ci >> 8;
        int c = ci & 255;
        int r = ((c >> 7) & 1) * 32 + (c & 31);
        int kloc = ktl * 32 + ((c >> 6) & 1) * 16 + ((c >> 5) & 1) * 8;
        short8 v = *reinterpret_cast<const short8*>(Hs + r * 64 + kloc);
        size_t db = tidx(mb + mbOff, ktTot, (bcol >> 5) + ktl, c);
        *reinterpret_cast<short8*>(dA + db) = v;
      }
    }
  } else {
    int colg = bcol + c0l;
    float badd = BIAS ? bias[colg] : 0.f;
#pragma unroll
    for (int r = 0; r < 16; ++r) {
      int rowg = brow + r0l + (r & 3) + 8 * (r >> 2);
      if (rowg < M) C[(size_t)rowg * N + colg] = acc[r] + badd;
    }
  }
}

// ===========================================================================
// h_build: h[i] = z1[i] + sum_{j in N(i)} z2[j] + c2     (z = [z1|z2], 512-wide)
// ===========================================================================
__global__ __launch_bounds__(64) void h_build_kernel(
    const float* __restrict__ z, const int* __restrict__ row,
    const int* __restrict__ col, const float* __restrict__ c2,
    float* __restrict__ h) {
  int i = blockIdx.x, t = threadIdx.x;
  int beg = row[i], end = row[i + 1];
  const float* z2 = z + 256 + t * 4;
  float4 a0{0.f, 0.f, 0.f, 0.f}, a1{0.f, 0.f, 0.f, 0.f};
  float4 a2{0.f, 0.f, 0.f, 0.f}, a3{0.f, 0.f, 0.f, 0.f};
  int e = beg;
  for (; e + 4 <= end; e += 4) {
    int s0 = col[e], s1 = col[e + 1], s2 = col[e + 2], s3 = col[e + 3];
    float4 v0 = *reinterpret_cast<const float4*>(z2 + (size_t)s0 * 512);
    float4 v1 = *reinterpret_cast<const float4*>(z2 + (size_t)s1 * 512);
    float4 v2 = *reinterpret_cast<const float4*>(z2 + (size_t)s2 * 512);
    float4 v3 = *reinterpret_cast<const float4*>(z2 + (size_t)s3 * 512);
    a0.x += v0.x; a0.y += v0.y; a0.z += v0.z; a0.w += v0.w;
    a1.x += v1.x; a1.y += v1.y; a1.z += v1.z; a1.w += v1.w;
    a2.x += v2.x; a2.y += v2.y; a2.z += v2.z; a2.w += v2.w;
    a3.x += v3.x; a3.y += v3.y; a3.z += v3.z; a3.w += v3.w;
  }
  for (; e < end; ++e) {
    int s = col[e];
    float4 v = *reinterpret_cast<const float4*>(z2 + (size_t)s * 512);
    a0.x += v.x; a0.y += v.y; a0.z += v.z; a0.w += v.w;
  }
  float4 z1v = *reinterpret_cast<const float4*>(z + (size_t)i * 512 + t * 4);
  float4 cv  = *reinterpret_cast<const float4*>(c2 + t * 4);
  float4 o{z1v.x + cv.x + a0.x + a1.x + a2.x + a3.x,
           z1v.y + cv.y + a0.y + a1.y + a2.y + a3.y,
           z1v.z + cv.z + a0.z + a1.z + a2.z + a3.z,
           z1v.w + cv.w + a0.w + a1.w + a2.w + a3.w};
  *reinterpret_cast<float4*>(h + (size_t)i * OUT_DIM + t * 4) = o;
}

// ===========================================================================
// GCN gather (fp32 h), fused self-loop + bias. 4-way edge unroll.
// ===========================================================================
__global__ __launch_bounds__(64) void gcn_gather_kernel(
    const float* __restrict__ h, const int* __restrict__ row,
    const int* __restrict__ col, const float* __restrict__ dis,
    const float* __restrict__ gcn_b, float* __restrict__ outg) {
  int i = blockIdx.x, t = threadIdx.x;
  int beg = row[i], end = row[i + 1];
  float di = dis[i];
  const float* hk = h + t * 4;
  float4 a0{0.f, 0.f, 0.f, 0.f}, a1{0.f, 0.f, 0.f, 0.f};
  float4 a2{0.f, 0.f, 0.f, 0.f}, a3{0.f, 0.f, 0.f, 0.f};
  int e = beg;
  for (; e + 4 <= end; e += 4) {
    int s0 = col[e], s1 = col[e + 1], s2 = col[e + 2], s3 = col[e + 3];
    float w0 = dis[s0], w1 = dis[s1], w2 = dis[s2], w3 = dis[s3];
    float4 v0 = *reinterpret_cast<const float4*>(hk + (size_t)s0 * OUT_DIM);
    float4 v1 = *reinterpret_cast<const float4*>(hk + (size_t)s1 * OUT_DIM);
    float4 v2 = *reinterpret_cast<const float4*>(hk + (size_t)s2 * OUT_DIM);
    float4 v3 = *reinterpret_cast<const float4*>(hk + (size_t)s3 * OUT_DIM);
    a0.x += w0 * v0.x; a0.y += w0 * v0.y; a0.z += w0 * v0.z; a0.w += w0 * v0.w;
    a1.x += w1 * v1.x; a1.y += w1 * v1.y; a1.z += w1 * v1.z; a1.w += w1 * v1.w;
    a2.x += w2 * v2.x; a2.y += w2 * v2.y; a2.z += w2 * v2.z; a2.w += w2 * v2.w;
    a3.x += w3 * v3.x; a3.y += w3 * v3.y; a3.z += w3 * v3.z; a3.w += w3 * v3.w;
  }
  for (; e < end; ++e) {
    int s = col[e];
    float w = dis[s];
    float4 v = *reinterpret_cast<const float4*>(hk + (size_t)s * OUT_DIM);
    a0.x += w * v.x; a0.y += w * v.y; a0.z += w * v.z; a0.w += w * v.w;
  }
  float4 acc{a0.x + a1.x + a2.x + a3.x, a0.y + a1.y + a2.y + a3.y,
             a0.z + a1.z + a2.z + a3.z, a0.w + a1.w + a2.w + a3.w};
  float4 hv = *reinterpret_cast<const float4*>(h + (size_t)i * OUT_DIM + t * 4);
  float4 bv = *reinterpret_cast<const float4*>(gcn_b + t * 4);
  float self = di * di;
  float4 o{di * acc.x + self * hv.x + bv.x, di * acc.y + self * hv.y + bv.y,
           di * acc.z + self * hv.z + bv.z, di * acc.w + self * hv.w + bv.w};
  *reinterpret_cast<float4*>(outg + (size_t)i * OUT_DIM + t * 4) = o;
}

// ===========================================================================
// decode MLP: 8 nodes per block
// ===========================================================================
#define DEC_NODES 8
__global__ __launch_bounds__(128) void decode_kernel(
    const float* __restrict__ outg, const float* __restrict__ d1_W,
    const float* __restrict__ d1_b, const float* __restrict__ d2_W,
    const float* __restrict__ d2_b, float* __restrict__ z1) {
  __shared__ float rows[DEC_NODES][OUT_DIM];
  __shared__ float s0[128], s1[128];
  int t = threadIdx.x;
  int n0 = blockIdx.x * DEC_NODES;
#pragma unroll
  for (int j = 0; j < 4; ++j) {
    int idx = j * 512 + t * 4;
    *reinterpret_cast<float4*>(&rows[0][idx]) =
        *reinterpret_cast<const float4*>(outg + (size_t)n0 * OUT_DIM + idx);
  }
  __syncthreads();
  float acc[DEC_NODES];
  float b1 = d1_b[t];
#pragma unroll
  for (int n = 0; n < DEC_NODES; ++n) acc[n] = b1;
#pragma unroll 4
  for (int k = 0; k < OUT_DIM; ++k) {
    float wv = d1_W[k * 128 + t];
#pragma unroll
    for (int n = 0; n < DEC_NODES; ++n) acc[n] += rows[n][k] * wv;
  }
  float w0 = d2_W[t * 2 + 0], w1 = d2_W[t * 2 + 1];
  for (int n = 0; n < DEC_NODES; ++n) {
    float a = fmaxf(acc[n], 0.f);
    s0[t] = a * w0;
    s1[t] = a * w1;
    __syncthreads();
    for (int off = 64; off > 0; off >>= 1) {
      if (t < off) {
        s0[t] += s0[t + off];
        s1[t] += s1[t + off];
      }
      __syncthreads();
    }
    if (t == 0) {
      z1[(size_t)(n0 + n) * 2 + 0] = s0[0] + d2_b[0];
      z1[(size_t)(n0 + n) * 2 + 1] = s1[0] + d2_b[1];
    }
    __syncthreads();
  }
}

// ===========================================================================
extern "C" void kernel_launch(void* const* d_in, const int* in_sizes, int n_in,
                              void* d_out, int out_size, void* d_ws, size_t ws_size,
                              hipStream_t stream) {
  const float* x     = (const float*)d_in[0];
  const int*   edge  = (const int*)d_in[1];
  const float* f_W   = (const float*)d_in[2];
  const float* f_b   = (const float*)d_in[3];
  const float* gcn_W = (const float*)d_in[4];
  const float* gcn_b = (const float*)d_in[5];
  const float* d1_W  = (const float*)d_in[6];
  const float* d1_b  = (const float*)d_in[7];
  const float* d2_W  = (const float*)d_in[8];
  const float* d2_b  = (const float*)d_in[9];
  float* out = (float*)d_out;
  char*  wsb = (char*)d_ws;

  const int* src = edge;
  const int* dst = edge + E_EDGES;

  // -------- v5 layout (bytes) --------
  const size_t TS   = (size_t)MB_T * 16 * 256 * 8 * sizeof(u16);  // x tiles/plane
  const size_t ZB   = (size_t)N_NODES * 512 * sizeof(float);      // z
  const size_t HB   = (size_t)N_NODES * OUT_DIM * sizeof(float);  // h
  const size_t WTLE = (size_t)16 * 256 * 8 * sizeof(u16);         // one (mb,*) tile row

  size_t o = 0;
  u16*   x_hi = (u16*)(wsb + o); o += TS;
  u16*   x_lo = (u16*)(wsb + o); o += TS;
  float* z    = (float*)(wsb + o); o += ZB;
  float* h    = (float*)(wsb + o); o += HB;
  float* dis5 = (float*)(wsb + o); o += (size_t)N_NODES * 4;
  int*   icnt5 = (int*)(wsb + o);  o += (size_t)N_NODES * 4;
  int*   irow5 = (int*)(wsb + o);  o += (size_t)(N_NODES + 1) * 4 + 12;
  int*   icol5 = (int*)(wsb + o);  o += (size_t)E_EDGES * 4;
  u16*   Wcomb_hi = (u16*)(wsb + o); o += 8 * WTLE;   // [Wtop | W2^T] B-tiles, N=512
  u16*   Wcomb_lo = (u16*)(wsb + o); o += 8 * WTLE;
  u16*   WbotT_hi = (u16*)(wsb + o); o += 4 * WTLE;   // Wbot^T A-tiles, M=256
  u16*   WbotT_lo = (u16*)(wsb + o); o += 4 * WTLE;
  u16*   fWp_hi   = (u16*)(wsb + o); o += 8 * WTLE;   // f_W packed = f_W^T B-tiles
  u16*   fWp_lo   = (u16*)(wsb + o); o += 8 * WTLE;
  float* c2   = (float*)(wsb + o); o += OUT_DIM * 4;
  float* outg = (float*)(wsb + 0);  // overlays x_hi (dead after Z GEMM)
  const size_t v5_needed = o;

  if (ws_size >= v5_needed) {
    // ---- CSR build
    hipMemsetAsync(icnt5, 0, (size_t)N_NODES * sizeof(int), stream);
    count_kernel<<<(E_EDGES + 255) / 256, 256, 0, stream>>>(dst, icnt5);
    scan_kernel<<<1, 1024, 0, stream>>>(icnt5, irow5, dis5);
    place_kernel<<<(E_EDGES + 255) / 256, 256, 0, stream>>>(src, dst, icnt5, icol5);

    // ---- operand prep
    pack_x_kernel<<<N_NODES, 128, 0, stream>>>(x, x_hi, x_lo);
    pack_x_kernel<<<HID_DIM, 128, 0, stream>>>(f_W, fWp_hi, fWp_lo);  // f_W^T B-tiles
    convT_tiled<<<dim3(IN_DIM / 64, OUT_DIM / 64), 256, 0, stream>>>(
        gcn_W, Wcomb_hi, Wcomb_lo, IN_DIM, OUT_DIM);                  // Wtop -> nb 0..3
    convT_tiled<<<dim3(HID_DIM / 64, OUT_DIM / 64), 256, 0, stream>>>(
        gcn_W + (size_t)IN_DIM * OUT_DIM, WbotT_hi, WbotT_lo, HID_DIM, OUT_DIM);
    c2_kernel<<<1, OUT_DIM, 0, stream>>>(f_b, gcn_W, c2);

    // ---- W2^T = Wbot^T @ f_W^T   [256 x 512] -> Wcomb tiles nb 4..7
    mfma_gemm4<false, true><<<dim3(512 / 64, 256 / 64), 256, 0, stream>>>(
        WbotT_hi, WbotT_lo, WbotT_hi, WbotT_lo, HID_DIM,
        fWp_hi, fWp_lo, nullptr, nullptr, Wcomb_hi, Wcomb_lo,
        256, HID_DIM, 512, /*mbOff=*/4);

    // ---- Z = x @ [Wtop | W2]    [10000 x 512] fp32
    mfma_gemm4<false, false><<<dim3(512 / 64, MB_T), 256, 0, stream>>>(
        x_hi, x_lo, x_hi, x_lo, IN_DIM,
        Wcomb_hi, Wcomb_lo, nullptr, z, nullptr, nullptr,
        N_NODES, IN_DIM, 512, 0);

    // ---- h = z1 + gather(z2) + c2 ; then GCN gather ; decode
    h_build_kernel<<<N_NODES, 64, 0, stream>>>(z, irow5, icol5, c2, h);
    gcn_gather_kernel<<<N_NODES, 64, 0, stream>>>(h, irow5, icol5, dis5, gcn_b, outg);
    decode_kernel<<<N_NODES / DEC_NODES, 128, 0, stream>>>(outg, d1_W, d1_b, d2_W, d2_b, out);
  }
  // (workspace is known to exceed v5_needed on this harness; no fallback tier)
}

// Round 10
// 178.682 us; speedup vs baseline: 1.4631x; 1.1060x over previous
//
#include <hip/hip_runtime.h>

#define N_NODES 10000
#define E_EDGES 160000
#define IN_DIM  512
#define HID_DIM 512
#define OUT_DIM 256
#define MB_T    157   // ceil(10000/64) row tiles

typedef __attribute__((ext_vector_type(8))) short short8;
typedef __attribute__((ext_vector_type(16))) float f32x16;
typedef unsigned short u16;

__device__ __forceinline__ u16 f2bh(float f) {
  union { float f; unsigned u; } v; v.f = f;
  return (u16)((v.u + 0x7FFFu + ((v.u >> 16) & 1u)) >> 16);
}
__device__ __forceinline__ float bh2f(u16 h) {
  union { unsigned u; float f; } v; v.u = ((unsigned)h) << 16;
  return v.f;
}

// tiled layout: chunk c within tile (mb,kt): row=(c>>7)*32+(c&31),
// k=((c>>6)&1)*16+((c>>5)&1)*8 (+0..7). u16 index of chunk start:
__device__ __forceinline__ size_t tidx(int mb, int ktTot, int kt, int c) {
  return ((size_t)(mb * ktTot + kt) * 256 + c) * 8;
}

#define GL_LDS(gsrc, ldst)                                                      \
  __builtin_amdgcn_global_load_lds(                                             \
      (const __attribute__((address_space(1))) unsigned int*)(gsrc),            \
      (__attribute__((address_space(3))) unsigned int*)(ldst), 16, 0, 0)

// ===========================================================================
// CSR build
// ===========================================================================
__global__ void count_kernel(const int* __restrict__ dst, int* __restrict__ cnt) {
  int e = blockIdx.x * 256 + threadIdx.x;
  if (e < E_EDGES) atomicAdd(&cnt[dst[e]], 1);
}

__global__ __launch_bounds__(1024) void scan_kernel(
    int* __restrict__ cnt, int* __restrict__ row, float* __restrict__ dis) {
  __shared__ int sums[1024];
  const int CH = 10;
  int t = threadIdx.x;
  int c[CH], excl[CH];
  int s = 0;
#pragma unroll
  for (int j = 0; j < CH; ++j) {
    int idx = t * CH + j;
    c[j] = (idx < N_NODES) ? cnt[idx] : 0;
    excl[j] = s;
    s += c[j];
  }
  sums[t] = s;
  __syncthreads();
  for (int off = 1; off < 1024; off <<= 1) {
    int v = (t >= off) ? sums[t - off] : 0;
    __syncthreads();
    if (t >= off) sums[t] += v;
    __syncthreads();
  }
  int base = (t == 0) ? 0 : sums[t - 1];
#pragma unroll
  for (int j = 0; j < CH; ++j) {
    int idx = t * CH + j;
    if (idx < N_NODES) {
      int start = base + excl[j];
      row[idx] = start;
      cnt[idx] = start;
      dis[idx] = rsqrtf((float)c[j] + 1.0f);
    }
  }
  if (t == 1023) row[N_NODES] = sums[1023];
}

__global__ void place_kernel(const int* __restrict__ src, const int* __restrict__ dst,
                             int* __restrict__ cursor, int* __restrict__ col) {
  int e = blockIdx.x * 256 + threadIdx.x;
  if (e < E_EDGES) {
    int pos = atomicAdd(&cursor[dst[e]], 1);
    col[pos] = src[e];
  }
}

// ===========================================================================
// pack: fp32 row-major [M x 512] -> tiled bf16 hi/lo (ktTot=16). grid=M.
// ===========================================================================
__global__ __launch_bounds__(128) void pack_x_kernel(
    const float* __restrict__ x, u16* __restrict__ hi, u16* __restrict__ lo) {
  int i = blockIdx.x, t = threadIdx.x;
  int k0 = t * 4;
  float4 v = *reinterpret_cast<const float4*>(x + (size_t)i * IN_DIM + k0);
  float a[4] = {v.x, v.y, v.z, v.w};
  ushort4 h4, l4;
  u16* hp = &h4.x; u16* lp = &l4.x;
#pragma unroll
  for (int j = 0; j < 4; ++j) {
    u16 hh = f2bh(a[j]);
    hp[j] = hh;
    lp[j] = f2bh(a[j] - bh2f(hh));
  }
  int mb = i >> 6, rl = i & 63;
  int kt = k0 >> 5, si = (k0 >> 4) & 1, kh = (k0 >> 3) & 1;
  int c = (rl >> 5) * 128 + si * 64 + kh * 32 + (rl & 31);
  size_t idx = tidx(mb, IN_DIM / 32, kt, c) + (k0 & 7);
  *reinterpret_cast<ushort4*>(hi + idx) = h4;
  *reinterpret_cast<ushort4*>(lo + idx) = l4;
}

// ===========================================================================
// Weight transpose + split -> tiled (cols of W as tile rows)
// ===========================================================================
__global__ __launch_bounds__(256) void convT_tiled(
    const float* __restrict__ W, u16* __restrict__ hi, u16* __restrict__ lo,
    int K, int N) {
  __shared__ float tile[64][65];
  int k0g = blockIdx.x * 64, n0 = blockIdx.y * 64;
  int t = threadIdx.x;
  int lk = t >> 4, ln = (t & 15) * 4;
#pragma unroll
  for (int p = 0; p < 4; ++p) {
    float4 v = *reinterpret_cast<const float4*>(W + (size_t)(k0g + p * 16 + lk) * N + n0 + ln);
    tile[p * 16 + lk][ln + 0] = v.x;
    tile[p * 16 + lk][ln + 1] = v.y;
    tile[p * 16 + lk][ln + 2] = v.z;
    tile[p * 16 + lk][ln + 3] = v.w;
  }
  __syncthreads();
  int on = t >> 2;
  int ok = (t & 3) * 16;
  int colg = n0 + on;
  int nb = colg >> 6, rl = colg & 63;
  int ktTot = K >> 5;
#pragma unroll
  for (int q = 0; q < 4; ++q) {
    int kg = k0g + ok + q * 4;
    ushort4 h4, l4;
    u16* hq = &h4.x; u16* lq = &l4.x;
#pragma unroll
    for (int j = 0; j < 4; ++j) {
      float v = tile[ok + q * 4 + j][on];
      u16 hh = f2bh(v);
      hq[j] = hh;
      lq[j] = f2bh(v - bh2f(hh));
    }
    int kt = kg >> 5, si = (kg >> 4) & 1, kh = (kg >> 3) & 1;
    int c = (rl >> 5) * 128 + si * 64 + kh * 32 + (rl & 31);
    size_t idx = tidx(nb, ktTot, kt, c) + (kg & 7);
    *reinterpret_cast<ushort4*>(hi + idx) = h4;
    *reinterpret_cast<ushort4*>(lo + idx) = l4;
  }
}

// c2 = f_b @ gcn_W[512:,:]   (256 outputs)
__global__ void c2_kernel(const float* __restrict__ f_b,
                          const float* __restrict__ gcn_W, float* __restrict__ c2) {
  int n = threadIdx.x;
  float s = 0.f;
  for (int k = 0; k < HID_DIM; ++k)
    s += f_b[k] * gcn_W[(size_t)(IN_DIM + k) * OUT_DIM + n];
  c2[n] = s;
}

// ===========================================================================
// MFMA GEMM (round-9 proven; used for W2^T prep): BM=64 BN=64 BK=32.
// OUT_TILED writes result as B-tiles (mb+mbOff, kt over N).
// ===========================================================================
template <bool BIAS, bool OUT_TILED>
__global__ __launch_bounds__(256) void mfma_gemm4(
    const u16* __restrict__ Ah0, const u16* __restrict__ Al0,
    const u16* __restrict__ Ah1, const u16* __restrict__ Al1, int kSplit,
    const u16* __restrict__ Bh, const u16* __restrict__ Bl,
    const float* __restrict__ bias, float* __restrict__ C,
    u16* __restrict__ Ch, u16* __restrict__ Cl, int M, int K, int N,
    int mbOff) {
  __shared__ short8 S[2][1024];

  int t = threadIdx.x, w = t >> 6, l = t & 63;
  int wr = w >> 1, wc = w & 1;
  int mb = blockIdx.y, nb = blockIdx.x;
  int brow = mb * 64, bcol = nb * 64;
  int cid = w * 64 + l;

  f32x16 acc0, acc1;
#pragma unroll
  for (int r = 0; r < 16; ++r) { acc0[r] = 0.f; acc1[r] = 0.f; }

  int nt = K / 32;
  int ktTotB = K >> 5;
  int ktTot0 = kSplit >> 5;
  int ktTot1 = (K - kSplit) >> 5;

#define STAGE(BUF, K0)                                                         \
  {                                                                            \
    const u16 *Ah, *Al; size_t abase;                                          \
    if ((K0) < kSplit) {                                                       \
      Ah = Ah0; Al = Al0; abase = tidx(mb, ktTot0, (K0) >> 5, cid);            \
    } else {                                                                   \
      Ah = Ah1; Al = Al1; abase = tidx(mb, ktTot1, ((K0) - kSplit) >> 5, cid); \
    }                                                                          \
    size_t bbase = tidx(nb, ktTotB, (K0) >> 5, cid);                           \
    short8* base = &S[BUF][0] + w * 64;                                        \
    GL_LDS(Ah + abase, base);                                                  \
    GL_LDS(Al + abase, base + 256);                                            \
    GL_LDS(Bh + bbase, base + 512);                                            \
    GL_LDS(Bl + bbase, base + 768);                                            \
  }

  STAGE(0, 0)
  for (int ti = 0; ti < nt; ++ti) {
    int b = ti & 1;
    __syncthreads();
    if (ti + 1 < nt) STAGE(b ^ 1, (ti + 1) * 32)
    {
      short8 ah = S[b][wr * 128 + l];
      short8 al = S[b][256 + wr * 128 + l];
      short8 bh = S[b][512 + wc * 128 + l];
      short8 bl = S[b][768 + wc * 128 + l];
      acc0 = __builtin_amdgcn_mfma_f32_32x32x16_bf16(ah, bh, acc0, 0, 0, 0);
      acc0 = __builtin_amdgcn_mfma_f32_32x32x16_bf16(al, bh, acc0, 0, 0, 0);
      acc0 = __builtin_amdgcn_mfma_f32_32x32x16_bf16(ah, bl, acc0, 0, 0, 0);
    }
    {
      short8 ah = S[b][wr * 128 + 64 + l];
      short8 al = S[b][256 + wr * 128 + 64 + l];
      short8 bh = S[b][512 + wc * 128 + 64 + l];
      short8 bl = S[b][768 + wc * 128 + 64 + l];
      acc1 = __builtin_amdgcn_mfma_f32_32x32x16_bf16(ah, bh, acc1, 0, 0, 0);
      acc1 = __builtin_amdgcn_mfma_f32_32x32x16_bf16(al, bh, acc1, 0, 0, 0);
      acc1 = __builtin_amdgcn_mfma_f32_32x32x16_bf16(ah, bl, acc1, 0, 0, 0);
    }
  }
#undef STAGE

  f32x16 acc = acc0 + acc1;

  int r0l = wr * 32 + 4 * (l >> 5);
  int c0l = wc * 32 + (l & 31);

  if (OUT_TILED) {
    __syncthreads();
    u16* Hhi = (u16*)&S[0][0];
    u16* Hlo = Hhi + 4096;
    float badd = BIAS ? bias[bcol + c0l] : 0.f;
#pragma unroll
    for (int r = 0; r < 16; ++r) {
      int rl = r0l + (r & 3) + 8 * (r >> 2);
      float v = acc[r] + badd;
      u16 hh = f2bh(v);
      Hhi[rl * 64 + c0l] = hh;
      Hlo[rl * 64 + c0l] = f2bh(v - bh2f(hh));
    }
    __syncthreads();
    int ktTot = N >> 5;
#pragma unroll
    for (int pl = 0; pl < 2; ++pl) {
      const u16* Hs = pl ? Hlo : Hhi;
      u16* dA = pl ? Cl : Ch;
#pragma unroll
      for (int j = 0; j < 2; ++j) {
        int ci = t + j * 256;
        int ktl = ci >> 8;
        int c = ci & 255;
        int r = ((c >> 7) & 1) * 32 + (c & 31);
        int kloc = ktl * 32 + ((c >> 6) & 1) * 16 + ((c >> 5) & 1) * 8;
        short8 v = *reinterpret_cast<const short8*>(Hs + r * 64 + kloc);
        size_t db = tidx(mb + mbOff, ktTot, (bcol >> 5) + ktl, c);
        *reinterpret_cast<short8*>(dA + db) = v;
      }
    }
  } else {
    int colg = bcol + c0l;
    float badd = BIAS ? bias[colg] : 0.f;
#pragma unroll
    for (int r = 0; r < 16; ++r) {
      int rowg = brow + r0l + (r & 3) + 8 * (r >> 2);
      if (rowg < M) C[(size_t)rowg * N + colg] = acc[r] + badd;
    }
  }
}

// ===========================================================================
// Z-GEMM: Z = x @ Wcomb  [M x 512], BM=64, BN=NB*64, 4 waves 2x2.
// Epilogue: cols<256 -> z1 fp32 ; cols>=256 -> z2b bf16 (single plane).
// ===========================================================================
template <int NB>
__global__ __launch_bounds__(256) void zgemm_kernel(
    const u16* __restrict__ Ah, const u16* __restrict__ Al,
    const u16* __restrict__ Bh, const u16* __restrict__ Bl,
    float* __restrict__ z1, u16* __restrict__ z2b, int M, int K) {
  constexpr int BCH = NB * 256;
  __shared__ short8 S[2][512 + 2 * BCH];

  int t = threadIdx.x, w = t >> 6, l = t & 63;
  int wr = w >> 1, wc = w & 1;
  int mb = blockIdx.y, nbB = blockIdx.x;
  int cid = t;
  int ktTot = K >> 5;

  f32x16 acc[NB][2];
#pragma unroll
  for (int n = 0; n < NB; ++n)
#pragma unroll
    for (int si = 0; si < 2; ++si)
#pragma unroll
      for (int r = 0; r < 16; ++r) acc[n][si][r] = 0.f;

  int nt = K / 32;

#define ZSTAGE(BUF, K0)                                                        \
  {                                                                            \
    size_t ab = tidx(mb, ktTot, (K0) >> 5, cid);                               \
    short8* base = &S[BUF][0] + w * 64;                                        \
    GL_LDS(Ah + ab, base);                                                     \
    GL_LDS(Al + ab, base + 256);                                               \
    _Pragma("unroll") for (int j = 0; j < NB; ++j) {                           \
      size_t bb = tidx(nbB * NB + j, ktTot, (K0) >> 5, cid);                   \
      GL_LDS(Bh + bb, base + 512 + j * 256);                                   \
      GL_LDS(Bl + bb, base + 512 + BCH + j * 256);                             \
    }                                                                          \
  }

  ZSTAGE(0, 0)
  for (int ti = 0; ti < nt; ++ti) {
    int b = ti & 1;
    __syncthreads();
    if (ti + 1 < nt) ZSTAGE(b ^ 1, (ti + 1) * 32)
#pragma unroll
    for (int si = 0; si < 2; ++si) {
      short8 ah = S[b][wr * 128 + si * 64 + l];
      short8 al = S[b][256 + wr * 128 + si * 64 + l];
#pragma unroll
      for (int n2 = 0; n2 < NB; ++n2) {
        // wave wc owns B LDS tile wc; its 32-col subtiles n2 = 0..NB-1 map to
        // chunk region: tile wc, subtile n2.
        short8 bh = S[b][512 + wc * 256 + n2 * 128 + si * 64 + l];
        short8 bl = S[b][512 + BCH + wc * 256 + n2 * 128 + si * 64 + l];
        acc[n2][si] = __builtin_amdgcn_mfma_f32_32x32x16_bf16(ah, bh, acc[n2][si], 0, 0, 0);
        acc[n2][si] = __builtin_amdgcn_mfma_f32_32x32x16_bf16(al, bh, acc[n2][si], 0, 0, 0);
        acc[n2][si] = __builtin_amdgcn_mfma_f32_32x32x16_bf16(ah, bl, acc[n2][si], 0, 0, 0);
      }
    }
  }
#undef ZSTAGE

  int r0 = mb * 64 + wr * 32 + 4 * (l >> 5);
#pragma unroll
  for (int n2 = 0; n2 < NB; ++n2) {
    f32x16 a = acc[n2][0] + acc[n2][1];
    int colg = nbB * (NB * 64) + wc * 64 + n2 * 32 + (l & 31);
#pragma unroll
    for (int r = 0; r < 16; ++r) {
      int rowg = r0 + (r & 3) + 8 * (r >> 2);
      if (rowg < M) {
        float v = a[r];
        if (colg < 256) z1[(size_t)rowg * 256 + colg] = v;
        else            z2b[(size_t)rowg * 256 + colg - 256] = f2bh(v);
      }
    }
  }
}

// ===========================================================================
// h_build: h[i] = z1[i] + sum_{j in N(i)} z2[j] + c2.
// bf16 z2 gather: 2 edges per wave (lane>>5 selects edge), 4-way unroll.
// Writes h fp32 + h_bf bf16 shadow.
// ===========================================================================
__global__ __launch_bounds__(64) void h_build_kernel(
    const float* __restrict__ z1, const u16* __restrict__ z2b,
    const int* __restrict__ row, const int* __restrict__ col,
    const float* __restrict__ c2, float* __restrict__ h,
    u16* __restrict__ h_bf) {
  int i = blockIdx.x, t = threadIdx.x;
  int half = t >> 5, sl = t & 31;
  int beg = row[i], end = row[i + 1];

  float a0[8] = {}, a1[8] = {}, a2[8] = {}, a3[8] = {};
  int e = beg + half;
  for (; e + 6 < end; e += 8) {
    int s0 = col[e], s1 = col[e + 2], s2 = col[e + 4], s3 = col[e + 6];
    short8 v0 = *reinterpret_cast<const short8*>(z2b + (size_t)s0 * 256 + sl * 8);
    short8 v1 = *reinterpret_cast<const short8*>(z2b + (size_t)s1 * 256 + sl * 8);
    short8 v2 = *reinterpret_cast<const short8*>(z2b + (size_t)s2 * 256 + sl * 8);
    short8 v3 = *reinterpret_cast<const short8*>(z2b + (size_t)s3 * 256 + sl * 8);
#pragma unroll
    for (int j = 0; j < 8; ++j) {
      a0[j] += bh2f((u16)v0[j]);
      a1[j] += bh2f((u16)v1[j]);
      a2[j] += bh2f((u16)v2[j]);
      a3[j] += bh2f((u16)v3[j]);
    }
  }
  for (; e < end; e += 2) {
    int s = col[e];
    short8 v = *reinterpret_cast<const short8*>(z2b + (size_t)s * 256 + sl * 8);
#pragma unroll
    for (int j = 0; j < 8; ++j) a0[j] += bh2f((u16)v[j]);
  }
  float acc[8];
#pragma unroll
  for (int j = 0; j < 8; ++j) {
    acc[j] = a0[j] + a1[j] + a2[j] + a3[j];
    acc[j] += __shfl_xor(acc[j], 32);
  }
  // self + c2
  float4 z1a = *reinterpret_cast<const float4*>(z1 + (size_t)i * 256 + sl * 8);
  float4 z1b = *reinterpret_cast<const float4*>(z1 + (size_t)i * 256 + sl * 8 + 4);
  float4 ca = *reinterpret_cast<const float4*>(c2 + sl * 8);
  float4 cb = *reinterpret_cast<const float4*>(c2 + sl * 8 + 4);
  float hv[8] = {z1a.x + ca.x + acc[0], z1a.y + ca.y + acc[1],
                 z1a.z + ca.z + acc[2], z1a.w + ca.w + acc[3],
                 z1b.x + cb.x + acc[4], z1b.y + cb.y + acc[5],
                 z1b.z + cb.z + acc[6], z1b.w + cb.w + acc[7]};
  if (half == 0) {
    float4 o0{hv[0], hv[1], hv[2], hv[3]};
    float4 o1{hv[4], hv[5], hv[6], hv[7]};
    *reinterpret_cast<float4*>(h + (size_t)i * 256 + sl * 8) = o0;
    *reinterpret_cast<float4*>(h + (size_t)i * 256 + sl * 8 + 4) = o1;
    short8 hb;
#pragma unroll
    for (int j = 0; j < 8; ++j) hb[j] = (short)f2bh(hv[j]);
    *reinterpret_cast<short8*>(h_bf + (size_t)i * 256 + sl * 8) = hb;
  }
}

// ===========================================================================
// GCN gather: out[i] = dis_i * sum dis_j h_j (bf16 gather) + dis_i^2 h_i + b
// ===========================================================================
__global__ __launch_bounds__(64) void gcn_gather_kernel(
    const float* __restrict__ h, const u16* __restrict__ h_bf,
    const int* __restrict__ row, const int* __restrict__ col,
    const float* __restrict__ dis, const float* __restrict__ gcn_b,
    float* __restrict__ outg) {
  int i = blockIdx.x, t = threadIdx.x;
  int half = t >> 5, sl = t & 31;
  int beg = row[i], end = row[i + 1];
  float di = dis[i];

  float a0[8] = {}, a1[8] = {}, a2[8] = {}, a3[8] = {};
  int e = beg + half;
  for (; e + 6 < end; e += 8) {
    int s0 = col[e], s1 = col[e + 2], s2 = col[e + 4], s3 = col[e + 6];
    float w0 = dis[s0], w1 = dis[s1], w2 = dis[s2], w3 = dis[s3];
    short8 v0 = *reinterpret_cast<const short8*>(h_bf + (size_t)s0 * 256 + sl * 8);
    short8 v1 = *reinterpret_cast<const short8*>(h_bf + (size_t)s1 * 256 + sl * 8);
    short8 v2 = *reinterpret_cast<const short8*>(h_bf + (size_t)s2 * 256 + sl * 8);
    short8 v3 = *reinterpret_cast<const short8*>(h_bf + (size_t)s3 * 256 + sl * 8);
#pragma unroll
    for (int j = 0; j < 8; ++j) {
      a0[j] += w0 * bh2f((u16)v0[j]);
      a1[j] += w1 * bh2f((u16)v1[j]);
      a2[j] += w2 * bh2f((u16)v2[j]);
      a3[j] += w3 * bh2f((u16)v3[j]);
    }
  }
  for (; e < end; e += 2) {
    int s = col[e];
    float wv = dis[s];
    short8 v = *reinterpret_cast<const short8*>(h_bf + (size_t)s * 256 + sl * 8);
#pragma unroll
    for (int j = 0; j < 8; ++j) a0[j] += wv * bh2f((u16)v[j]);
  }
  float acc[8];
#pragma unroll
  for (int j = 0; j < 8; ++j) {
    acc[j] = a0[j] + a1[j] + a2[j] + a3[j];
    acc[j] += __shfl_xor(acc[j], 32);
  }
  if (half == 0) {
    float4 ha = *reinterpret_cast<const float4*>(h + (size_t)i * 256 + sl * 8);
    float4 hb = *reinterpret_cast<const float4*>(h + (size_t)i * 256 + sl * 8 + 4);
    float4 ba = *reinterpret_cast<const float4*>(gcn_b + sl * 8);
    float4 bb = *reinterpret_cast<const float4*>(gcn_b + sl * 8 + 4);
    float self = di * di;
    float4 o0{di * acc[0] + self * ha.x + ba.x, di * acc[1] + self * ha.y + ba.y,
              di * acc[2] + self * ha.z + ba.z, di * acc[3] + self * ha.w + ba.w};
    float4 o1{di * acc[4] + self * hb.x + bb.x, di * acc[5] + self * hb.y + bb.y,
              di * acc[6] + self * hb.z + bb.z, di * acc[7] + self * hb.w + bb.w};
    *reinterpret_cast<float4*>(outg + (size_t)i * 256 + sl * 8) = o0;
    *reinterpret_cast<float4*>(outg + (size_t)i * 256 + sl * 8 + 4) = o1;
  }
}

// ===========================================================================
// decode MLP: 8 nodes per block
// ===========================================================================
#define DEC_NODES 8
__global__ __launch_bounds__(128) void decode_kernel(
    const float* __restrict__ outg, const float* __restrict__ d1_W,
    const float* __restrict__ d1_b, const float* __restrict__ d2_W,
    const float* __restrict__ d2_b, float* __restrict__ z1) {
  __shared__ float rows[DEC_NODES][OUT_DIM];
  __shared__ float s0[128], s1[128];
  int t = threadIdx.x;
  int n0 = blockIdx.x * DEC_NODES;
#pragma unroll
  for (int j = 0; j < 4; ++j) {
    int idx = j * 512 + t * 4;
    *reinterpret_cast<float4*>(&rows[0][idx]) =
        *reinterpret_cast<const float4*>(outg + (size_t)n0 * OUT_DIM + idx);
  }
  __syncthreads();
  float acc[DEC_NODES];
  float b1 = d1_b[t];
#pragma unroll
  for (int n = 0; n < DEC_NODES; ++n) acc[n] = b1;
#pragma unroll 4
  for (int k = 0; k < OUT_DIM; ++k) {
    float wv = d1_W[k * 128 + t];
#pragma unroll
    for (int n = 0; n < DEC_NODES; ++n) acc[n] += rows[n][k] * wv;
  }
  float w0 = d2_W[t * 2 + 0], w1 = d2_W[t * 2 + 1];
  for (int n = 0; n < DEC_NODES; ++n) {
    float a = fmaxf(acc[n], 0.f);
    s0[t] = a * w0;
    s1[t] = a * w1;
    __syncthreads();
    for (int off = 64; off > 0; off >>= 1) {
      if (t < off) {
        s0[t] += s0[t + off];
        s1[t] += s1[t + off];
      }
      __syncthreads();
    }
    if (t == 0) {
      z1[(size_t)(n0 + n) * 2 + 0] = s0[0] + d2_b[0];
      z1[(size_t)(n0 + n) * 2 + 1] = s1[0] + d2_b[1];
    }
    __syncthreads();
  }
}

// ===========================================================================
extern "C" void kernel_launch(void* const* d_in, const int* in_sizes, int n_in,
                              void* d_out, int out_size, void* d_ws, size_t ws_size,
                              hipStream_t stream) {
  const float* x     = (const float*)d_in[0];
  const int*   edge  = (const int*)d_in[1];
  const float* f_W   = (const float*)d_in[2];
  const float* f_b   = (const float*)d_in[3];
  const float* gcn_W = (const float*)d_in[4];
  const float* gcn_b = (const float*)d_in[5];
  const float* d1_W  = (const float*)d_in[6];
  const float* d1_b  = (const float*)d_in[7];
  const float* d2_W  = (const float*)d_in[8];
  const float* d2_b  = (const float*)d_in[9];
  float* out = (float*)d_out;
  char*  wsb = (char*)d_ws;

  const int* src = edge;
  const int* dst = edge + E_EDGES;

  // -------- v6 layout (bytes) --------
  const size_t TS   = (size_t)MB_T * 16 * 256 * 8 * sizeof(u16);
  const size_t WTLE = (size_t)16 * 256 * 8 * sizeof(u16);

  size_t o = 0;
  u16*   x_hi = (u16*)(wsb + o); o += TS;
  u16*   x_lo = (u16*)(wsb + o); o += TS;
  float* z1   = (float*)(wsb + o); o += (size_t)N_NODES * 256 * 4;
  u16*   z2b  = (u16*)(wsb + o);   o += (size_t)N_NODES * 256 * 2;
  float* h    = (float*)(wsb + o); o += (size_t)N_NODES * 256 * 4;
  u16*   h_bf = (u16*)(wsb + o);   o += (size_t)N_NODES * 256 * 2;
  float* dis6 = (float*)(wsb + o); o += (size_t)N_NODES * 4;
  int*   icnt6 = (int*)(wsb + o);  o += (size_t)N_NODES * 4;
  int*   irow6 = (int*)(wsb + o);  o += (size_t)(N_NODES + 1) * 4 + 12;
  int*   icol6 = (int*)(wsb + o);  o += (size_t)E_EDGES * 4;
  u16*   Wcomb_hi = (u16*)(wsb + o); o += 8 * WTLE;
  u16*   Wcomb_lo = (u16*)(wsb + o); o += 8 * WTLE;
  u16*   WbotT_hi = (u16*)(wsb + o); o += 4 * WTLE;
  u16*   WbotT_lo = (u16*)(wsb + o); o += 4 * WTLE;
  u16*   fWp_hi   = (u16*)(wsb + o); o += 8 * WTLE;
  u16*   fWp_lo   = (u16*)(wsb + o); o += 8 * WTLE;
  float* c2   = (float*)(wsb + o); o += OUT_DIM * 4;
  float* outg = (float*)(wsb + 0);  // overlays x_hi (dead after Z-GEMM)
  const size_t v6_needed = o;

  if (ws_size >= v6_needed) {
    // ---- CSR build
    hipMemsetAsync(icnt6, 0, (size_t)N_NODES * sizeof(int), stream);
    count_kernel<<<(E_EDGES + 255) / 256, 256, 0, stream>>>(dst, icnt6);
    scan_kernel<<<1, 1024, 0, stream>>>(icnt6, irow6, dis6);
    place_kernel<<<(E_EDGES + 255) / 256, 256, 0, stream>>>(src, dst, icnt6, icol6);

    // ---- operand prep
    pack_x_kernel<<<N_NODES, 128, 0, stream>>>(x, x_hi, x_lo);
    pack_x_kernel<<<HID_DIM, 128, 0, stream>>>(f_W, fWp_hi, fWp_lo);
    convT_tiled<<<dim3(IN_DIM / 64, OUT_DIM / 64), 256, 0, stream>>>(
        gcn_W, Wcomb_hi, Wcomb_lo, IN_DIM, OUT_DIM);
    convT_tiled<<<dim3(HID_DIM / 64, OUT_DIM / 64), 256, 0, stream>>>(
        gcn_W + (size_t)IN_DIM * OUT_DIM, WbotT_hi, WbotT_lo, HID_DIM, OUT_DIM);
    c2_kernel<<<1, OUT_DIM, 0, stream>>>(f_b, gcn_W, c2);

    // ---- W2^T = Wbot^T @ f_W^T   [256 x 512] -> Wcomb tiles nb 4..7
    mfma_gemm4<false, true><<<dim3(512 / 64, 256 / 64), 256, 0, stream>>>(
        WbotT_hi, WbotT_lo, WbotT_hi, WbotT_lo, HID_DIM,
        fWp_hi, fWp_lo, nullptr, nullptr, Wcomb_hi, Wcomb_lo,
        256, HID_DIM, 512, /*mbOff=*/4);

    // ---- Z = x @ [Wtop | W2] : z1 fp32, z2 bf16
    zgemm_kernel<2><<<dim3(512 / 128, MB_T), 256, 0, stream>>>(
        x_hi, x_lo, Wcomb_hi, Wcomb_lo, z1, z2b, N_NODES, IN_DIM);

    // ---- h = z1 + gather(z2) + c2 (fp32 + bf16 shadow)
    h_build_kernel<<<N_NODES, 64, 0, stream>>>(z1, z2b, irow6, icol6, c2, h, h_bf);

    // ---- GCN gather (bf16 neighbors, fp32 self) + decode
    gcn_gather_kernel<<<N_NODES, 64, 0, stream>>>(h, h_bf, irow6, icol6, dis6, gcn_b, outg);
    decode_kernel<<<N_NODES / DEC_NODES, 128, 0, stream>>>(outg, d1_W, d1_b, d2_W, d2_b, out);
  }
}

// Round 11
// 150.187 us; speedup vs baseline: 1.7407x; 1.1897x over previous
//
#include <hip/hip_runtime.h>

#define N_NODES 10000
#define E_EDGES 160000
#define IN_DIM  512
#define HID_DIM 512
#define OUT_DIM 256
#define MB_T    157   // ceil(10000/64) row tiles

typedef __attribute__((ext_vector_type(8))) short short8;
typedef __attribute__((ext_vector_type(16))) float f32x16;
typedef unsigned short u16;

__device__ __forceinline__ u16 f2bh(float f) {
  union { float f; unsigned u; } v; v.f = f;
  return (u16)((v.u + 0x7FFFu + ((v.u >> 16) & 1u)) >> 16);
}
__device__ __forceinline__ float bh2f(u16 h) {
  union { unsigned u; float f; } v; v.u = ((unsigned)h) << 16;
  return v.f;
}

// tiled layout: chunk c within tile (mb,kt): row=(c>>7)*32+(c&31),
// k=((c>>6)&1)*16+((c>>5)&1)*8 (+0..7). u16 index of chunk start:
__device__ __forceinline__ size_t tidx(int mb, int ktTot, int kt, int c) {
  return ((size_t)(mb * ktTot + kt) * 256 + c) * 8;
}

#define GL_LDS(gsrc, ldst)                                                      \
  __builtin_amdgcn_global_load_lds(                                             \
      (const __attribute__((address_space(1))) unsigned int*)(gsrc),            \
      (__attribute__((address_space(3))) unsigned int*)(ldst), 16, 0, 0)

// ===========================================================================
// CSR build
// ===========================================================================
__global__ void count_kernel(const int* __restrict__ dst, int* __restrict__ cnt) {
  int e = blockIdx.x * 256 + threadIdx.x;
  if (e < E_EDGES) atomicAdd(&cnt[dst[e]], 1);
}

__global__ __launch_bounds__(1024) void scan_kernel(
    int* __restrict__ cnt, int* __restrict__ row, float* __restrict__ dis) {
  __shared__ int sums[1024];
  const int CH = 10;
  int t = threadIdx.x;
  int c[CH], excl[CH];
  int s = 0;
#pragma unroll
  for (int j = 0; j < CH; ++j) {
    int idx = t * CH + j;
    c[j] = (idx < N_NODES) ? cnt[idx] : 0;
    excl[j] = s;
    s += c[j];
  }
  sums[t] = s;
  __syncthreads();
  for (int off = 1; off < 1024; off <<= 1) {
    int v = (t >= off) ? sums[t - off] : 0;
    __syncthreads();
    if (t >= off) sums[t] += v;
    __syncthreads();
  }
  int base = (t == 0) ? 0 : sums[t - 1];
#pragma unroll
  for (int j = 0; j < CH; ++j) {
    int idx = t * CH + j;
    if (idx < N_NODES) {
      int start = base + excl[j];
      row[idx] = start;
      cnt[idx] = start;
      dis[idx] = rsqrtf((float)c[j] + 1.0f);
    }
  }
  if (t == 1023) row[N_NODES] = sums[1023];
}

__global__ void place_kernel(const int* __restrict__ src, const int* __restrict__ dst,
                             int* __restrict__ cursor, int* __restrict__ col) {
  int e = blockIdx.x * 256 + threadIdx.x;
  if (e < E_EDGES) {
    int pos = atomicAdd(&cursor[dst[e]], 1);
    col[pos] = src[e];
  }
}

// ===========================================================================
// Fused prep kernel (256 threads):
//  blocks [0,5000)        : pack x rows 2b, 2b+1      -> x_hi/x_lo tiles
//  blocks [5000,5256)     : pack f_W rows ...         -> fWp tiles (f_W^T B-tiles)
//  blocks [5256,5320)     : convT Wtop / Wbot         -> Wcomb nb0..3 / WbotT
//  blocks [5320,5336)     : c2 partial (k-chunk 32)   -> atomicAdd c2
// ===========================================================================
#define PREP_PACKX  5000
#define PREP_PACKFW 5256
#define PREP_CONVT  5320
#define PREP_TOTAL  5336

__device__ __forceinline__ void pack_row(const float* __restrict__ src,
                                         u16* __restrict__ hi, u16* __restrict__ lo,
                                         int i, int tt) {
  int k0 = tt * 4;
  float4 v = *reinterpret_cast<const float4*>(src + (size_t)i * 512 + k0);
  float a[4] = {v.x, v.y, v.z, v.w};
  ushort4 h4, l4;
  u16* hp = &h4.x; u16* lp = &l4.x;
#pragma unroll
  for (int j = 0; j < 4; ++j) {
    u16 hh = f2bh(a[j]);
    hp[j] = hh;
    lp[j] = f2bh(a[j] - bh2f(hh));
  }
  int mb = i >> 6, rl = i & 63;
  int kt = k0 >> 5, si = (k0 >> 4) & 1, kh = (k0 >> 3) & 1;
  int c = (rl >> 5) * 128 + si * 64 + kh * 32 + (rl & 31);
  size_t idx = tidx(mb, 16, kt, c) + (k0 & 7);
  *reinterpret_cast<ushort4*>(hi + idx) = h4;
  *reinterpret_cast<ushort4*>(lo + idx) = l4;
}

__global__ __launch_bounds__(256) void prep_kernel(
    const float* __restrict__ x, const float* __restrict__ f_W,
    const float* __restrict__ gcn_W, const float* __restrict__ f_b,
    u16* __restrict__ x_hi, u16* __restrict__ x_lo,
    u16* __restrict__ fWp_hi, u16* __restrict__ fWp_lo,
    u16* __restrict__ Wcomb_hi, u16* __restrict__ Wcomb_lo,
    u16* __restrict__ WbotT_hi, u16* __restrict__ WbotT_lo,
    float* __restrict__ c2) {
  __shared__ float tile[64][65];
  int b = blockIdx.x, t = threadIdx.x;

  if (b < PREP_PACKX) {
    int i = b * 2 + (t >> 7);
    pack_row(x, x_hi, x_lo, i, t & 127);
  } else if (b < PREP_PACKFW) {
    int i = (b - PREP_PACKX) * 2 + (t >> 7);
    pack_row(f_W, fWp_hi, fWp_lo, i, t & 127);
  } else if (b < PREP_CONVT) {
    int lb = b - PREP_PACKFW;           // 0..63
    int part = lb >> 5;                 // 0: Wtop, 1: Wbot
    int li = lb & 31;                   // 0..31
    int k0g = (li >> 2) * 64;           // 8 k-blocks
    int n0 = (li & 3) * 64;             // 4 n-blocks
    const float* W = part ? (gcn_W + (size_t)IN_DIM * OUT_DIM) : gcn_W;
    u16* hi = part ? WbotT_hi : Wcomb_hi;
    u16* lo = part ? WbotT_lo : Wcomb_lo;
    int lk = t >> 4, ln = (t & 15) * 4;
#pragma unroll
    for (int p = 0; p < 4; ++p) {
      float4 v = *reinterpret_cast<const float4*>(W + (size_t)(k0g + p * 16 + lk) * 256 + n0 + ln);
      tile[p * 16 + lk][ln + 0] = v.x;
      tile[p * 16 + lk][ln + 1] = v.y;
      tile[p * 16 + lk][ln + 2] = v.z;
      tile[p * 16 + lk][ln + 3] = v.w;
    }
    __syncthreads();
    int on = t >> 2;
    int ok = (t & 3) * 16;
    int colg = n0 + on;
    int nb = colg >> 6, rl = colg & 63;
#pragma unroll
    for (int q = 0; q < 4; ++q) {
      int kg = k0g + ok + q * 4;
      ushort4 h4, l4;
      u16* hq = &h4.x; u16* lq = &l4.x;
#pragma unroll
      for (int j = 0; j < 4; ++j) {
        float v = tile[ok + q * 4 + j][on];
        u16 hh = f2bh(v);
        hq[j] = hh;
        lq[j] = f2bh(v - bh2f(hh));
      }
      int kt = kg >> 5, si = (kg >> 4) & 1, kh = (kg >> 3) & 1;
      int c = (rl >> 5) * 128 + si * 64 + kh * 32 + (rl & 31);
      size_t idx = tidx(nb, 16, kt, c) + (kg & 7);
      *reinterpret_cast<ushort4*>(hi + idx) = h4;
      *reinterpret_cast<ushort4*>(lo + idx) = l4;
    }
  } else {
    int cb = b - PREP_CONVT;            // 0..15
    float s = 0.f;
    int kb = cb * 32;
#pragma unroll 8
    for (int k = kb; k < kb + 32; ++k)
      s += f_b[k] * gcn_W[(size_t)(IN_DIM + k) * OUT_DIM + t];
    atomicAdd(&c2[t], s);
  }
}

// ===========================================================================
// MFMA GEMM (round-9 proven; used for W2^T prep): BM=64 BN=64 BK=32.
// OUT_TILED writes result as B-tiles (mb+mbOff, kt over N).
// ===========================================================================
template <bool BIAS, bool OUT_TILED>
__global__ __launch_bounds__(256) void mfma_gemm4(
    const u16* __restrict__ Ah0, const u16* __restrict__ Al0,
    const u16* __restrict__ Ah1, const u16* __restrict__ Al1, int kSplit,
    const u16* __restrict__ Bh, const u16* __restrict__ Bl,
    const float* __restrict__ bias, float* __restrict__ C,
    u16* __restrict__ Ch, u16* __restrict__ Cl, int M, int K, int N,
    int mbOff) {
  __shared__ short8 S[2][1024];

  int t = threadIdx.x, w = t >> 6, l = t & 63;
  int wr = w >> 1, wc = w & 1;
  int mb = blockIdx.y, nb = blockIdx.x;
  int brow = mb * 64, bcol = nb * 64;
  int cid = w * 64 + l;

  f32x16 acc0, acc1;
#pragma unroll
  for (int r = 0; r < 16; ++r) { acc0[r] = 0.f; acc1[r] = 0.f; }

  int nt = K / 32;
  int ktTotB = K >> 5;
  int ktTot0 = kSplit >> 5;
  int ktTot1 = (K - kSplit) >> 5;

#define STAGE(BUF, K0)                                                         \
  {                                                                            \
    const u16 *Ah, *Al; size_t abase;                                          \
    if ((K0) < kSplit) {                                                       \
      Ah = Ah0; Al = Al0; abase = tidx(mb, ktTot0, (K0) >> 5, cid);            \
    } else {                                                                   \
      Ah = Ah1; Al = Al1; abase = tidx(mb, ktTot1, ((K0) - kSplit) >> 5, cid); \
    }                                                                          \
    size_t bbase = tidx(nb, ktTotB, (K0) >> 5, cid);                           \
    short8* base = &S[BUF][0] + w * 64;                                        \
    GL_LDS(Ah + abase, base);                                                  \
    GL_LDS(Al + abase, base + 256);                                            \
    GL_LDS(Bh + bbase, base + 512);                                            \
    GL_LDS(Bl + bbase, base + 768);                                            \
  }

  STAGE(0, 0)
  for (int ti = 0; ti < nt; ++ti) {
    int b = ti & 1;
    __syncthreads();
    if (ti + 1 < nt) STAGE(b ^ 1, (ti + 1) * 32)
    {
      short8 ah = S[b][wr * 128 + l];
      short8 al = S[b][256 + wr * 128 + l];
      short8 bh = S[b][512 + wc * 128 + l];
      short8 bl = S[b][768 + wc * 128 + l];
      acc0 = __builtin_amdgcn_mfma_f32_32x32x16_bf16(ah, bh, acc0, 0, 0, 0);
      acc0 = __builtin_amdgcn_mfma_f32_32x32x16_bf16(al, bh, acc0, 0, 0, 0);
      acc0 = __builtin_amdgcn_mfma_f32_32x32x16_bf16(ah, bl, acc0, 0, 0, 0);
    }
    {
      short8 ah = S[b][wr * 128 + 64 + l];
      short8 al = S[b][256 + wr * 128 + 64 + l];
      short8 bh = S[b][512 + wc * 128 + 64 + l];
      short8 bl = S[b][768 + wc * 128 + 64 + l];
      acc1 = __builtin_amdgcn_mfma_f32_32x32x16_bf16(ah, bh, acc1, 0, 0, 0);
      acc1 = __builtin_amdgcn_mfma_f32_32x32x16_bf16(al, bh, acc1, 0, 0, 0);
      acc1 = __builtin_amdgcn_mfma_f32_32x32x16_bf16(ah, bl, acc1, 0, 0, 0);
    }
  }
#undef STAGE

  f32x16 acc = acc0 + acc1;

  int r0l = wr * 32 + 4 * (l >> 5);
  int c0l = wc * 32 + (l & 31);

  if (OUT_TILED) {
    __syncthreads();
    u16* Hhi = (u16*)&S[0][0];
    u16* Hlo = Hhi + 4096;
    float badd = BIAS ? bias[bcol + c0l] : 0.f;
#pragma unroll
    for (int r = 0; r < 16; ++r) {
      int rl = r0l + (r & 3) + 8 * (r >> 2);
      float v = acc[r] + badd;
      u16 hh = f2bh(v);
      Hhi[rl * 64 + c0l] = hh;
      Hlo[rl * 64 + c0l] = f2bh(v - bh2f(hh));
    }
    __syncthreads();
    int ktTot = N >> 5;
#pragma unroll
    for (int pl = 0; pl < 2; ++pl) {
      const u16* Hs = pl ? Hlo : Hhi;
      u16* dA = pl ? Cl : Ch;
#pragma unroll
      for (int j = 0; j < 2; ++j) {
        int ci = t + j * 256;
        int ktl = ci >> 8;
        int c = ci & 255;
        int r = ((c >> 7) & 1) * 32 + (c & 31);
        int kloc = ktl * 32 + ((c >> 6) & 1) * 16 + ((c >> 5) & 1) * 8;
        short8 v = *reinterpret_cast<const short8*>(Hs + r * 64 + kloc);
        size_t db = tidx(mb + mbOff, ktTot, (bcol >> 5) + ktl, c);
        *reinterpret_cast<short8*>(dA + db) = v;
      }
    }
  } else {
    int colg = bcol + c0l;
    float badd = BIAS ? bias[colg] : 0.f;
#pragma unroll
    for (int r = 0; r < 16; ++r) {
      int rowg = brow + r0l + (r & 3) + 8 * (r >> 2);
      if (rowg < M) C[(size_t)rowg * N + colg] = acc[r] + badd;
    }
  }
}

// ===========================================================================
// Z-GEMM: Z = x @ Wcomb  [M x 512], BM=64, BN=NB*64, 4 waves 2x2.
// 1D grid with XCD-aware remap: xcd = mb % 8 so all col-blocks of one mb
// share one XCD L2 (A-panel fetched once per XCD instead of 4x).
// Epilogue: cols<256 -> z1 fp32 ; cols>=256 -> z2b bf16.
// ===========================================================================
template <int NB>
__global__ __launch_bounds__(256) void zgemm_kernel(
    const u16* __restrict__ Ah, const u16* __restrict__ Al,
    const u16* __restrict__ Bh, const u16* __restrict__ Bl,
    float* __restrict__ z1, u16* __restrict__ z2b, int M, int K) {
  constexpr int BCH = NB * 256;
  __shared__ short8 S[2][512 + 2 * BCH];

  // XCD remap: blocks [0,640): X = b&7 (target XCD), s = b>>3;
  // mb = X + 8*(s>>2), nbB = s&3.
  int bid = blockIdx.x;
  int X = bid & 7, sslot = bid >> 3;
  int mb = X + 8 * (sslot >> 2);
  int nbB = sslot & 3;
  if (mb >= MB_T) return;

  int t = threadIdx.x, w = t >> 6, l = t & 63;
  int wr = w >> 1, wc = w & 1;
  int cid = t;
  int ktTot = K >> 5;

  f32x16 acc[NB][2];
#pragma unroll
  for (int n = 0; n < NB; ++n)
#pragma unroll
    for (int si = 0; si < 2; ++si)
#pragma unroll
      for (int r = 0; r < 16; ++r) acc[n][si][r] = 0.f;

  int nt = K / 32;

#define ZSTAGE(BUF, K0)                                                        \
  {                                                                            \
    size_t ab = tidx(mb, ktTot, (K0) >> 5, cid);                               \
    short8* base = &S[BUF][0] + w * 64;                                        \
    GL_LDS(Ah + ab, base);                                                     \
    GL_LDS(Al + ab, base + 256);                                               \
    _Pragma("unroll") for (int j = 0; j < NB; ++j) {                           \
      size_t bb = tidx(nbB * NB + j, ktTot, (K0) >> 5, cid);                   \
      GL_LDS(Bh + bb, base + 512 + j * 256);                                   \
      GL_LDS(Bl + bb, base + 512 + BCH + j * 256);                             \
    }                                                                          \
  }

  ZSTAGE(0, 0)
  for (int ti = 0; ti < nt; ++ti) {
    int b = ti & 1;
    __syncthreads();
    if (ti + 1 < nt) ZSTAGE(b ^ 1, (ti + 1) * 32)
#pragma unroll
    for (int si = 0; si < 2; ++si) {
      short8 ah = S[b][wr * 128 + si * 64 + l];
      short8 al = S[b][256 + wr * 128 + si * 64 + l];
#pragma unroll
      for (int n2 = 0; n2 < NB; ++n2) {
        short8 bh = S[b][512 + wc * 256 + n2 * 128 + si * 64 + l];
        short8 bl = S[b][512 + BCH + wc * 256 + n2 * 128 + si * 64 + l];
        acc[n2][si] = __builtin_amdgcn_mfma_f32_32x32x16_bf16(ah, bh, acc[n2][si], 0, 0, 0);
        acc[n2][si] = __builtin_amdgcn_mfma_f32_32x32x16_bf16(al, bh, acc[n2][si], 0, 0, 0);
        acc[n2][si] = __builtin_amdgcn_mfma_f32_32x32x16_bf16(ah, bl, acc[n2][si], 0, 0, 0);
      }
    }
  }
#undef ZSTAGE

  int r0 = mb * 64 + wr * 32 + 4 * (l >> 5);
#pragma unroll
  for (int n2 = 0; n2 < NB; ++n2) {
    f32x16 a = acc[n2][0] + acc[n2][1];
    int colg = nbB * (NB * 64) + wc * 64 + n2 * 32 + (l & 31);
#pragma unroll
    for (int r = 0; r < 16; ++r) {
      int rowg = r0 + (r & 3) + 8 * (r >> 2);
      if (rowg < M) {
        float v = a[r];
        if (colg < 256) z1[(size_t)rowg * 256 + colg] = v;
        else            z2b[(size_t)rowg * 256 + colg - 256] = f2bh(v);
      }
    }
  }
}

// ===========================================================================
// h_build: h[i] = z1[i] + sum_{j in N(i)} z2[j] + c2.
// ===========================================================================
__global__ __launch_bounds__(64) void h_build_kernel(
    const float* __restrict__ z1, const u16* __restrict__ z2b,
    const int* __restrict__ row, const int* __restrict__ col,
    const float* __restrict__ c2, float* __restrict__ h,
    u16* __restrict__ h_bf) {
  int i = blockIdx.x, t = threadIdx.x;
  int half = t >> 5, sl = t & 31;
  int beg = row[i], end = row[i + 1];

  float a0[8] = {}, a1[8] = {}, a2[8] = {}, a3[8] = {};
  int e = beg + half;
  for (; e + 6 < end; e += 8) {
    int s0 = col[e], s1 = col[e + 2], s2 = col[e + 4], s3 = col[e + 6];
    short8 v0 = *reinterpret_cast<const short8*>(z2b + (size_t)s0 * 256 + sl * 8);
    short8 v1 = *reinterpret_cast<const short8*>(z2b + (size_t)s1 * 256 + sl * 8);
    short8 v2 = *reinterpret_cast<const short8*>(z2b + (size_t)s2 * 256 + sl * 8);
    short8 v3 = *reinterpret_cast<const short8*>(z2b + (size_t)s3 * 256 + sl * 8);
#pragma unroll
    for (int j = 0; j < 8; ++j) {
      a0[j] += bh2f((u16)v0[j]);
      a1[j] += bh2f((u16)v1[j]);
      a2[j] += bh2f((u16)v2[j]);
      a3[j] += bh2f((u16)v3[j]);
    }
  }
  for (; e < end; e += 2) {
    int s = col[e];
    short8 v = *reinterpret_cast<const short8*>(z2b + (size_t)s * 256 + sl * 8);
#pragma unroll
    for (int j = 0; j < 8; ++j) a0[j] += bh2f((u16)v[j]);
  }
  float acc[8];
#pragma unroll
  for (int j = 0; j < 8; ++j) {
    acc[j] = a0[j] + a1[j] + a2[j] + a3[j];
    acc[j] += __shfl_xor(acc[j], 32);
  }
  float4 z1a = *reinterpret_cast<const float4*>(z1 + (size_t)i * 256 + sl * 8);
  float4 z1b = *reinterpret_cast<const float4*>(z1 + (size_t)i * 256 + sl * 8 + 4);
  float4 ca = *reinterpret_cast<const float4*>(c2 + sl * 8);
  float4 cb = *reinterpret_cast<const float4*>(c2 + sl * 8 + 4);
  float hv[8] = {z1a.x + ca.x + acc[0], z1a.y + ca.y + acc[1],
                 z1a.z + ca.z + acc[2], z1a.w + ca.w + acc[3],
                 z1b.x + cb.x + acc[4], z1b.y + cb.y + acc[5],
                 z1b.z + cb.z + acc[6], z1b.w + cb.w + acc[7]};
  if (half == 0) {
    float4 o0{hv[0], hv[1], hv[2], hv[3]};
    float4 o1{hv[4], hv[5], hv[6], hv[7]};
    *reinterpret_cast<float4*>(h + (size_t)i * 256 + sl * 8) = o0;
    *reinterpret_cast<float4*>(h + (size_t)i * 256 + sl * 8 + 4) = o1;
    short8 hb;
#pragma unroll
    for (int j = 0; j < 8; ++j) hb[j] = (short)f2bh(hv[j]);
    *reinterpret_cast<short8*>(h_bf + (size_t)i * 256 + sl * 8) = hb;
  }
}

// ===========================================================================
// GCN gather: out[i] = dis_i * sum dis_j h_j (bf16 gather) + dis_i^2 h_i + b
// ===========================================================================
__global__ __launch_bounds__(64) void gcn_gather_kernel(
    const float* __restrict__ h, const u16* __restrict__ h_bf,
    const int* __restrict__ row, const int* __restrict__ col,
    const float* __restrict__ dis, const float* __restrict__ gcn_b,
    float* __restrict__ outg) {
  int i = blockIdx.x, t = threadIdx.x;
  int half = t >> 5, sl = t & 31;
  int beg = row[i], end = row[i + 1];
  float di = dis[i];

  float a0[8] = {}, a1[8] = {}, a2[8] = {}, a3[8] = {};
  int e = beg + half;
  for (; e + 6 < end; e += 8) {
    int s0 = col[e], s1 = col[e + 2], s2 = col[e + 4], s3 = col[e + 6];
    float w0 = dis[s0], w1 = dis[s1], w2 = dis[s2], w3 = dis[s3];
    short8 v0 = *reinterpret_cast<const short8*>(h_bf + (size_t)s0 * 256 + sl * 8);
    short8 v1 = *reinterpret_cast<const short8*>(h_bf + (size_t)s1 * 256 + sl * 8);
    short8 v2 = *reinterpret_cast<const short8*>(h_bf + (size_t)s2 * 256 + sl * 8);
    short8 v3 = *reinterpret_cast<const short8*>(h_bf + (size_t)s3 * 256 + sl * 8);
#pragma unroll
    for (int j = 0; j < 8; ++j) {
      a0[j] += w0 * bh2f((u16)v0[j]);
      a1[j] += w1 * bh2f((u16)v1[j]);
      a2[j] += w2 * bh2f((u16)v2[j]);
      a3[j] += w3 * bh2f((u16)v3[j]);
    }
  }
  for (; e < end; e += 2) {
    int s = col[e];
    float wv = dis[s];
    short8 v = *reinterpret_cast<const short8*>(h_bf + (size_t)s * 256 + sl * 8);
#pragma unroll
    for (int j = 0; j < 8; ++j) a0[j] += wv * bh2f((u16)v[j]);
  }
  float acc[8];
#pragma unroll
  for (int j = 0; j < 8; ++j) {
    acc[j] = a0[j] + a1[j] + a2[j] + a3[j];
    acc[j] += __shfl_xor(acc[j], 32);
  }
  if (half == 0) {
    float4 ha = *reinterpret_cast<const float4*>(h + (size_t)i * 256 + sl * 8);
    float4 hb = *reinterpret_cast<const float4*>(h + (size_t)i * 256 + sl * 8 + 4);
    float4 ba = *reinterpret_cast<const float4*>(gcn_b + sl * 8);
    float4 bb = *reinterpret_cast<const float4*>(gcn_b + sl * 8 + 4);
    float self = di * di;
    float4 o0{di * acc[0] + self * ha.x + ba.x, di * acc[1] + self * ha.y + ba.y,
              di * acc[2] + self * ha.z + ba.z, di * acc[3] + self * ha.w + ba.w};
    float4 o1{di * acc[4] + self * hb.x + bb.x, di * acc[5] + self * hb.y + bb.y,
              di * acc[6] + self * hb.z + bb.z, di * acc[7] + self * hb.w + bb.w};
    *reinterpret_cast<float4*>(outg + (size_t)i * 256 + sl * 8) = o0;
    *reinterpret_cast<float4*>(outg + (size_t)i * 256 + sl * 8 + 4) = o1;
  }
}

// ===========================================================================
// decode MLP: 8 nodes per block
// ===========================================================================
#define DEC_NODES 8
__global__ __launch_bounds__(128) void decode_kernel(
    const float* __restrict__ outg, const float* __restrict__ d1_W,
    const float* __restrict__ d1_b, const float* __restrict__ d2_W,
    const float* __restrict__ d2_b, float* __restrict__ z1) {
  __shared__ float rows[DEC_NODES][OUT_DIM];
  __shared__ float s0[128], s1[128];
  int t = threadIdx.x;
  int n0 = blockIdx.x * DEC_NODES;
#pragma unroll
  for (int j = 0; j < 4; ++j) {
    int idx = j * 512 + t * 4;
    *reinterpret_cast<float4*>(&rows[0][idx]) =
        *reinterpret_cast<const float4*>(outg + (size_t)n0 * OUT_DIM + idx);
  }
  __syncthreads();
  float acc[DEC_NODES];
  float b1 = d1_b[t];
#pragma unroll
  for (int n = 0; n < DEC_NODES; ++n) acc[n] = b1;
#pragma unroll 4
  for (int k = 0; k < OUT_DIM; ++k) {
    float wv = d1_W[k * 128 + t];
#pragma unroll
    for (int n = 0; n < DEC_NODES; ++n) acc[n] += rows[n][k] * wv;
  }
  float w0 = d2_W[t * 2 + 0], w1 = d2_W[t * 2 + 1];
  for (int n = 0; n < DEC_NODES; ++n) {
    float a = fmaxf(acc[n], 0.f);
    s0[t] = a * w0;
    s1[t] = a * w1;
    __syncthreads();
    for (int off = 64; off > 0; off >>= 1) {
      if (t < off) {
        s0[t] += s0[t + off];
        s1[t] += s1[t + off];
      }
      __syncthreads();
    }
    if (t == 0) {
      z1[(size_t)(n0 + n) * 2 + 0] = s0[0] + d2_b[0];
      z1[(size_t)(n0 + n) * 2 + 1] = s1[0] + d2_b[1];
    }
    __syncthreads();
  }
}

// ===========================================================================
extern "C" void kernel_launch(void* const* d_in, const int* in_sizes, int n_in,
                              void* d_out, int out_size, void* d_ws, size_t ws_size,
                              hipStream_t stream) {
  const float* x     = (const float*)d_in[0];
  const int*   edge  = (const int*)d_in[1];
  const float* f_W   = (const float*)d_in[2];
  const float* f_b   = (const float*)d_in[3];
  const float* gcn_W = (const float*)d_in[4];
  const float* gcn_b = (const float*)d_in[5];
  const float* d1_W  = (const float*)d_in[6];
  const float* d1_b  = (const float*)d_in[7];
  const float* d2_W  = (const float*)d_in[8];
  const float* d2_b  = (const float*)d_in[9];
  float* out = (float*)d_out;
  char*  wsb = (char*)d_ws;

  const int* src = edge;
  const int* dst = edge + E_EDGES;

  // -------- v7 layout (bytes) --------
  const size_t TS   = (size_t)MB_T * 16 * 256 * 8 * sizeof(u16);
  const size_t WTLE = (size_t)16 * 256 * 8 * sizeof(u16);

  size_t o = 0;
  u16*   x_hi = (u16*)(wsb + o); o += TS;
  u16*   x_lo = (u16*)(wsb + o); o += TS;
  float* z1   = (float*)(wsb + o); o += (size_t)N_NODES * 256 * 4;
  u16*   z2b  = (u16*)(wsb + o);   o += (size_t)N_NODES * 256 * 2;
  float* h    = (float*)(wsb + o); o += (size_t)N_NODES * 256 * 4;
  u16*   h_bf = (u16*)(wsb + o);   o += (size_t)N_NODES * 256 * 2;
  float* dis7 = (float*)(wsb + o); o += (size_t)N_NODES * 4;
  int*   icnt7 = (int*)(wsb + o);  o += (size_t)N_NODES * 4;
  float* c2   = (float*)(wsb + o); o += OUT_DIM * 4;   // adjacent to icnt7: one memset
  int*   irow7 = (int*)(wsb + o);  o += (size_t)(N_NODES + 1) * 4 + 12;
  int*   icol7 = (int*)(wsb + o);  o += (size_t)E_EDGES * 4;
  u16*   Wcomb_hi = (u16*)(wsb + o); o += 8 * WTLE;
  u16*   Wcomb_lo = (u16*)(wsb + o); o += 8 * WTLE;
  u16*   WbotT_hi = (u16*)(wsb + o); o += 4 * WTLE;
  u16*   WbotT_lo = (u16*)(wsb + o); o += 4 * WTLE;
  u16*   fWp_hi   = (u16*)(wsb + o); o += 8 * WTLE;
  u16*   fWp_lo   = (u16*)(wsb + o); o += 8 * WTLE;
  float* outg = (float*)(wsb + 0);  // overlays x_hi (dead after Z-GEMM)
  const size_t v7_needed = o;

  if (ws_size >= v7_needed) {
    // ---- CSR build (memset covers icnt7 + c2, contiguous)
    hipMemsetAsync(icnt7, 0, (size_t)N_NODES * sizeof(int) + OUT_DIM * sizeof(float), stream);
    count_kernel<<<(E_EDGES + 255) / 256, 256, 0, stream>>>(dst, icnt7);
    scan_kernel<<<1, 1024, 0, stream>>>(icnt7, irow7, dis7);
    place_kernel<<<(E_EDGES + 255) / 256, 256, 0, stream>>>(src, dst, icnt7, icol7);

    // ---- fused prep (pack x, pack f_W, convT Wtop/Wbot, c2)
    prep_kernel<<<PREP_TOTAL, 256, 0, stream>>>(
        x, f_W, gcn_W, f_b, x_hi, x_lo, fWp_hi, fWp_lo,
        Wcomb_hi, Wcomb_lo, WbotT_hi, WbotT_lo, c2);

    // ---- W2^T = Wbot^T @ f_W^T   [256 x 512] -> Wcomb tiles nb 4..7
    mfma_gemm4<false, true><<<dim3(512 / 64, 256 / 64), 256, 0, stream>>>(
        WbotT_hi, WbotT_lo, WbotT_hi, WbotT_lo, HID_DIM,
        fWp_hi, fWp_lo, nullptr, nullptr, Wcomb_hi, Wcomb_lo,
        256, HID_DIM, 512, /*mbOff=*/4);

    // ---- Z = x @ [Wtop | W2] : z1 fp32, z2 bf16  (XCD-remapped 1D grid)
    zgemm_kernel<2><<<640, 256, 0, stream>>>(
        x_hi, x_lo, Wcomb_hi, Wcomb_lo, z1, z2b, N_NODES, IN_DIM);

    // ---- h = z1 + gather(z2) + c2 (fp32 + bf16 shadow)
    h_build_kernel<<<N_NODES, 64, 0, stream>>>(z1, z2b, irow7, icol7, c2, h, h_bf);

    // ---- GCN gather (bf16 neighbors, fp32 self) + decode
    gcn_gather_kernel<<<N_NODES, 64, 0, stream>>>(h, h_bf, irow7, icol7, dis7, gcn_b, outg);
    decode_kernel<<<N_NODES / DEC_NODES, 128, 0, stream>>>(outg, d1_W, d1_b, d2_W, d2_b, out);
  }
}

// Round 12
// 142.474 us; speedup vs baseline: 1.8349x; 1.0541x over previous
//
#include <hip/hip_runtime.h>

#define N_NODES 10000
#define E_EDGES 160000
#define IN_DIM  512
#define HID_DIM 512
#define OUT_DIM 256
#define MB_T    157   // ceil(10000/64) row tiles

typedef __attribute__((ext_vector_type(8))) short short8;
typedef __attribute__((ext_vector_type(16))) float f32x16;
typedef unsigned short u16;

__device__ __forceinline__ u16 f2bh(float f) {
  union { float f; unsigned u; } v; v.f = f;
  return (u16)((v.u + 0x7FFFu + ((v.u >> 16) & 1u)) >> 16);
}
__device__ __forceinline__ float bh2f(u16 h) {
  union { unsigned u; float f; } v; v.u = ((unsigned)h) << 16;
  return v.f;
}

// tiled layout: chunk c within tile (mb,kt): row=(c>>7)*32+(c&31),
// k=((c>>6)&1)*16+((c>>5)&1)*8 (+0..7). u16 index of chunk start:
__device__ __forceinline__ size_t tidx(int mb, int ktTot, int kt, int c) {
  return ((size_t)(mb * ktTot + kt) * 256 + c) * 8;
}
__device__ __forceinline__ short8 g16(const u16* p) {
  return *reinterpret_cast<const short8*>(p);
}

#define GL_LDS(gsrc, ldst)                                                      \
  __builtin_amdgcn_global_load_lds(                                             \
      (const __attribute__((address_space(1))) unsigned int*)(gsrc),            \
      (__attribute__((address_space(3))) unsigned int*)(ldst), 16, 0, 0)

// ===========================================================================
// scan: exclusive scan of cnt -> row/cursor + dis. shfl-based, 2 barriers.
// ===========================================================================
__global__ __launch_bounds__(1024) void scan_kernel(
    int* __restrict__ cnt, int* __restrict__ row, float* __restrict__ dis) {
  __shared__ int wsum[16];
  const int CH = 10;
  int t = threadIdx.x;
  int lane = t & 63, wid = t >> 6;
  int c[CH], excl[CH];
  int s = 0;
#pragma unroll
  for (int j = 0; j < CH; ++j) {
    int idx = t * CH + j;
    c[j] = (idx < N_NODES) ? cnt[idx] : 0;
    excl[j] = s;
    s += c[j];
  }
  int incl = s;
#pragma unroll
  for (int off = 1; off < 64; off <<= 1) {
    int v = __shfl_up(incl, off);
    if (lane >= off) incl += v;
  }
  if (lane == 63) wsum[wid] = incl;
  __syncthreads();
  if (t < 16) {
    int v = wsum[t];
#pragma unroll
    for (int off = 1; off < 16; off <<= 1) {
      int u = __shfl_up(v, off);
      if (t >= off) v += u;
    }
    wsum[t] = v;  // inclusive wave sums
  }
  __syncthreads();
  int waveBase = (wid == 0) ? 0 : wsum[wid - 1];
  int base = waveBase + incl - s;  // exclusive prefix for this thread
#pragma unroll
  for (int j = 0; j < CH; ++j) {
    int idx = t * CH + j;
    if (idx < N_NODES) {
      int start = base + excl[j];
      row[idx] = start;
      cnt[idx] = start;  // cursor
      dis[idx] = rsqrtf((float)c[j] + 1.0f);
    }
  }
  if (t == 1023) row[N_NODES] = wsum[15];
}

// ===========================================================================
// Fused prep kernel (256 threads):
//  [0,5000)      : pack x rows 2b,2b+1 -> x tiles
//  [5000,5256)   : pack f_W rows       -> fWp tiles (f_W^T B-tiles)
//  [5256,5320)   : convT Wtop / Wbot   -> Wcomb nb0..3 / WbotT
//  [5320,5336)   : c2 partials         -> atomicAdd c2
//  [5336,5961)   : CSR count           -> atomicAdd icnt
// ===========================================================================
#define PREP_PACKX  5000
#define PREP_PACKFW 5256
#define PREP_CONVT  5320
#define PREP_C2END  5336
#define PREP_TOTAL  5961

__device__ __forceinline__ void pack_row(const float* __restrict__ src,
                                         u16* __restrict__ hi, u16* __restrict__ lo,
                                         int i, int tt) {
  int k0 = tt * 4;
  float4 v = *reinterpret_cast<const float4*>(src + (size_t)i * 512 + k0);
  float a[4] = {v.x, v.y, v.z, v.w};
  ushort4 h4, l4;
  u16* hp = &h4.x; u16* lp = &l4.x;
#pragma unroll
  for (int j = 0; j < 4; ++j) {
    u16 hh = f2bh(a[j]);
    hp[j] = hh;
    lp[j] = f2bh(a[j] - bh2f(hh));
  }
  int mb = i >> 6, rl = i & 63;
  int kt = k0 >> 5, si = (k0 >> 4) & 1, kh = (k0 >> 3) & 1;
  int c = (rl >> 5) * 128 + si * 64 + kh * 32 + (rl & 31);
  size_t idx = tidx(mb, 16, kt, c) + (k0 & 7);
  *reinterpret_cast<ushort4*>(hi + idx) = h4;
  *reinterpret_cast<ushort4*>(lo + idx) = l4;
}

__global__ __launch_bounds__(256) void prep_kernel(
    const float* __restrict__ x, const float* __restrict__ f_W,
    const float* __restrict__ gcn_W, const float* __restrict__ f_b,
    const int* __restrict__ dst, int* __restrict__ icnt,
    u16* __restrict__ x_hi, u16* __restrict__ x_lo,
    u16* __restrict__ fWp_hi, u16* __restrict__ fWp_lo,
    u16* __restrict__ Wcomb_hi, u16* __restrict__ Wcomb_lo,
    u16* __restrict__ WbotT_hi, u16* __restrict__ WbotT_lo,
    float* __restrict__ c2) {
  __shared__ float tile[64][65];
  int b = blockIdx.x, t = threadIdx.x;

  if (b < PREP_PACKX) {
    int i = b * 2 + (t >> 7);
    pack_row(x, x_hi, x_lo, i, t & 127);
  } else if (b < PREP_PACKFW) {
    int i = (b - PREP_PACKX) * 2 + (t >> 7);
    pack_row(f_W, fWp_hi, fWp_lo, i, t & 127);
  } else if (b < PREP_CONVT) {
    int lb = b - PREP_PACKFW;
    int part = lb >> 5;
    int li = lb & 31;
    int k0g = (li >> 2) * 64;
    int n0 = (li & 3) * 64;
    const float* W = part ? (gcn_W + (size_t)IN_DIM * OUT_DIM) : gcn_W;
    u16* hi = part ? WbotT_hi : Wcomb_hi;
    u16* lo = part ? WbotT_lo : Wcomb_lo;
    int lk = t >> 4, ln = (t & 15) * 4;
#pragma unroll
    for (int p = 0; p < 4; ++p) {
      float4 v = *reinterpret_cast<const float4*>(W + (size_t)(k0g + p * 16 + lk) * 256 + n0 + ln);
      tile[p * 16 + lk][ln + 0] = v.x;
      tile[p * 16 + lk][ln + 1] = v.y;
      tile[p * 16 + lk][ln + 2] = v.z;
      tile[p * 16 + lk][ln + 3] = v.w;
    }
    __syncthreads();
    int on = t >> 2;
    int ok = (t & 3) * 16;
    int colg = n0 + on;
    int nb = colg >> 6, rl = colg & 63;
#pragma unroll
    for (int q = 0; q < 4; ++q) {
      int kg = k0g + ok + q * 4;
      ushort4 h4, l4;
      u16* hq = &h4.x; u16* lq = &l4.x;
#pragma unroll
      for (int j = 0; j < 4; ++j) {
        float v = tile[ok + q * 4 + j][on];
        u16 hh = f2bh(v);
        hq[j] = hh;
        lq[j] = f2bh(v - bh2f(hh));
      }
      int kt = kg >> 5, si = (kg >> 4) & 1, kh = (kg >> 3) & 1;
      int c = (rl >> 5) * 128 + si * 64 + kh * 32 + (rl & 31);
      size_t idx = tidx(nb, 16, kt, c) + (kg & 7);
      *reinterpret_cast<ushort4*>(hi + idx) = h4;
      *reinterpret_cast<ushort4*>(lo + idx) = l4;
    }
  } else if (b < PREP_C2END) {
    int cb = b - PREP_CONVT;
    float s = 0.f;
    int kb = cb * 32;
#pragma unroll 8
    for (int k = kb; k < kb + 32; ++k)
      s += f_b[k] * gcn_W[(size_t)(IN_DIM + k) * OUT_DIM + t];
    atomicAdd(&c2[t], s);
  } else {
    int e = (b - PREP_C2END) * 256 + t;
    if (e < E_EDGES) atomicAdd(&icnt[dst[e]], 1);
  }
}

// ===========================================================================
// pw_kernel: fused CSR-place (625 blocks) + W2 register GEMM (32 blocks).
// W2^T[256x512] = WbotT @ fWp, barrier-free reg pipeline, epilogue repack
// into Wcomb B-tiles (mbOff=4).
// ===========================================================================
#define PW_PLACE 625
#define PW_TOTAL 657

__global__ __launch_bounds__(256) void pw_kernel(
    const int* __restrict__ src, const int* __restrict__ dst,
    int* __restrict__ cursor, int* __restrict__ col,
    const u16* __restrict__ WbotT_hi, const u16* __restrict__ WbotT_lo,
    const u16* __restrict__ fWp_hi, const u16* __restrict__ fWp_lo,
    u16* __restrict__ Wcomb_hi, u16* __restrict__ Wcomb_lo) {
  __shared__ u16 H[8192];
  int b = blockIdx.x, t = threadIdx.x;

  if (b < PW_PLACE) {
    int e = b * 256 + t;
    if (e < E_EDGES) {
      int pos = atomicAdd(&cursor[dst[e]], 1);
      col[pos] = src[e];
    }
    return;
  }

  int lb = b - PW_PLACE;          // 0..31
  int nb = lb & 7;                // col tile over N=512
  int mbw = lb >> 3;              // row tile over M=256
  int w = t >> 6, l = t & 63;
  int wr = w >> 1, wc = w & 1;
  int cA = wr * 128 + l;
  int cB = wc * 128 + l;

  f32x16 acc0, acc1;
#pragma unroll
  for (int r = 0; r < 16; ++r) { acc0[r] = 0.f; acc1[r] = 0.f; }

#define W2LOAD(KT, AH0, AL0, BH0, BL0, AH1, AL1, BH1, BL1)                     \
  {                                                                            \
    size_t a0 = tidx(mbw, 16, (KT), cA);                                       \
    size_t a1 = tidx(mbw, 16, (KT), cA + 64);                                  \
    size_t b0 = tidx(nb, 16, (KT), cB);                                        \
    size_t b1 = tidx(nb, 16, (KT), cB + 64);                                   \
    AH0 = g16(WbotT_hi + a0); AL0 = g16(WbotT_lo + a0);                        \
    BH0 = g16(fWp_hi + b0);   BL0 = g16(fWp_lo + b0);                          \
    AH1 = g16(WbotT_hi + a1); AL1 = g16(WbotT_lo + a1);                        \
    BH1 = g16(fWp_hi + b1);   BL1 = g16(fWp_lo + b1);                          \
  }
#define W2MMA(AH0, AL0, BH0, BL0, AH1, AL1, BH1, BL1)                          \
  {                                                                            \
    acc0 = __builtin_amdgcn_mfma_f32_32x32x16_bf16(AH0, BH0, acc0, 0, 0, 0);   \
    acc0 = __builtin_amdgcn_mfma_f32_32x32x16_bf16(AL0, BH0, acc0, 0, 0, 0);   \
    acc0 = __builtin_amdgcn_mfma_f32_32x32x16_bf16(AH0, BL0, acc0, 0, 0, 0);   \
    acc1 = __builtin_amdgcn_mfma_f32_32x32x16_bf16(AH1, BH1, acc1, 0, 0, 0);   \
    acc1 = __builtin_amdgcn_mfma_f32_32x32x16_bf16(AL1, BH1, acc1, 0, 0, 0);   \
    acc1 = __builtin_amdgcn_mfma_f32_32x32x16_bf16(AH1, BL1, acc1, 0, 0, 0);   \
  }

  short8 xah0, xal0, xbh0, xbl0, xah1, xal1, xbh1, xbl1;
  short8 yah0, yal0, ybh0, ybl0, yah1, yal1, ybh1, ybl1;
  W2LOAD(0, xah0, xal0, xbh0, xbl0, xah1, xal1, xbh1, xbl1)
#pragma unroll
  for (int kt = 0; kt < 16; kt += 2) {
    W2LOAD(kt + 1, yah0, yal0, ybh0, ybl0, yah1, yal1, ybh1, ybl1)
    W2MMA(xah0, xal0, xbh0, xbl0, xah1, xal1, xbh1, xbl1)
    if (kt + 2 < 16)
      W2LOAD(kt + 2, xah0, xal0, xbh0, xbl0, xah1, xal1, xbh1, xbl1)
    W2MMA(yah0, yal0, ybh0, ybl0, yah1, yal1, ybh1, ybl1)
  }
#undef W2LOAD
#undef W2MMA

  f32x16 acc = acc0 + acc1;
  u16* Hhi = H;
  u16* Hlo = H + 4096;
  int r0l = wr * 32 + 4 * (l >> 5);
  int c0l = wc * 32 + (l & 31);
#pragma unroll
  for (int r = 0; r < 16; ++r) {
    int rl = r0l + (r & 3) + 8 * (r >> 2);
    float v = acc[r];
    u16 hh = f2bh(v);
    Hhi[rl * 64 + c0l] = hh;
    Hlo[rl * 64 + c0l] = f2bh(v - bh2f(hh));
  }
  __syncthreads();
#pragma unroll
  for (int pl = 0; pl < 2; ++pl) {
    const u16* Hs = pl ? Hlo : Hhi;
    u16* dA = pl ? Wcomb_lo : Wcomb_hi;
#pragma unroll
    for (int j = 0; j < 2; ++j) {
      int ci = t + j * 256;
      int ktl = ci >> 8;
      int c = ci & 255;
      int r = ((c >> 7) & 1) * 32 + (c & 31);
      int kloc = ktl * 32 + ((c >> 6) & 1) * 16 + ((c >> 5) & 1) * 8;
      short8 v = *reinterpret_cast<const short8*>(Hs + r * 64 + kloc);
      size_t db = tidx(mbw + 4, 16, nb * 2 + ktl, c);
      *reinterpret_cast<short8*>(dA + db) = v;
    }
  }
}

// ===========================================================================
// Z-GEMM: Z = x @ Wcomb  [M x 512], BM=64, BN=NB*64, 4 waves 2x2.
// XCD-aware remap: all col-blocks of one mb share one XCD L2.
// Epilogue: cols<256 -> z1 fp32 ; cols>=256 -> z2b bf16.
// ===========================================================================
template <int NB>
__global__ __launch_bounds__(256) void zgemm_kernel(
    const u16* __restrict__ Ah, const u16* __restrict__ Al,
    const u16* __restrict__ Bh, const u16* __restrict__ Bl,
    float* __restrict__ z1, u16* __restrict__ z2b, int M, int K) {
  constexpr int BCH = NB * 256;
  __shared__ short8 S[2][512 + 2 * BCH];

  int bid = blockIdx.x;
  int X = bid & 7, sslot = bid >> 3;
  int mb = X + 8 * (sslot >> 2);
  int nbB = sslot & 3;
  if (mb >= MB_T) return;

  int t = threadIdx.x, w = t >> 6, l = t & 63;
  int wr = w >> 1, wc = w & 1;
  int cid = t;
  int ktTot = K >> 5;

  f32x16 acc[NB][2];
#pragma unroll
  for (int n = 0; n < NB; ++n)
#pragma unroll
    for (int si = 0; si < 2; ++si)
#pragma unroll
      for (int r = 0; r < 16; ++r) acc[n][si][r] = 0.f;

  int nt = K / 32;

#define ZSTAGE(BUF, K0)                                                        \
  {                                                                            \
    size_t ab = tidx(mb, ktTot, (K0) >> 5, cid);                               \
    short8* base = &S[BUF][0] + w * 64;                                        \
    GL_LDS(Ah + ab, base);                                                     \
    GL_LDS(Al + ab, base + 256);                                               \
    _Pragma("unroll") for (int j = 0; j < NB; ++j) {                           \
      size_t bb = tidx(nbB * NB + j, ktTot, (K0) >> 5, cid);                   \
      GL_LDS(Bh + bb, base + 512 + j * 256);                                   \
      GL_LDS(Bl + bb, base + 512 + BCH + j * 256);                             \
    }                                                                          \
  }

  ZSTAGE(0, 0)
  for (int ti = 0; ti < nt; ++ti) {
    int b = ti & 1;
    __syncthreads();
    if (ti + 1 < nt) ZSTAGE(b ^ 1, (ti + 1) * 32)
#pragma unroll
    for (int si = 0; si < 2; ++si) {
      short8 ah = S[b][wr * 128 + si * 64 + l];
      short8 al = S[b][256 + wr * 128 + si * 64 + l];
#pragma unroll
      for (int n2 = 0; n2 < NB; ++n2) {
        short8 bh = S[b][512 + wc * 256 + n2 * 128 + si * 64 + l];
        short8 bl = S[b][512 + BCH + wc * 256 + n2 * 128 + si * 64 + l];
        acc[n2][si] = __builtin_amdgcn_mfma_f32_32x32x16_bf16(ah, bh, acc[n2][si], 0, 0, 0);
        acc[n2][si] = __builtin_amdgcn_mfma_f32_32x32x16_bf16(al, bh, acc[n2][si], 0, 0, 0);
        acc[n2][si] = __builtin_amdgcn_mfma_f32_32x32x16_bf16(ah, bl, acc[n2][si], 0, 0, 0);
      }
    }
  }
#undef ZSTAGE

  int r0 = mb * 64 + wr * 32 + 4 * (l >> 5);
#pragma unroll
  for (int n2 = 0; n2 < NB; ++n2) {
    f32x16 a = acc[n2][0] + acc[n2][1];
    int colg = nbB * (NB * 64) + wc * 64 + n2 * 32 + (l & 31);
#pragma unroll
    for (int r = 0; r < 16; ++r) {
      int rowg = r0 + (r & 3) + 8 * (r >> 2);
      if (rowg < M) {
        float v = a[r];
        if (colg < 256) z1[(size_t)rowg * 256 + colg] = v;
        else            z2b[(size_t)rowg * 256 + colg - 256] = f2bh(v);
      }
    }
  }
}

// ===========================================================================
// h_build: h[i] = z1[i] + sum_{j in N(i)} z2[j] + c2.  2 nodes/block.
// ===========================================================================
__global__ __launch_bounds__(128) void h_build_kernel(
    const float* __restrict__ z1, const u16* __restrict__ z2b,
    const int* __restrict__ row, const int* __restrict__ col,
    const float* __restrict__ c2, float* __restrict__ h,
    u16* __restrict__ h_bf) {
  int i = blockIdx.x * 2 + (threadIdx.x >> 6);
  int t = threadIdx.x & 63;
  int half = t >> 5, sl = t & 31;
  int beg = row[i], end = row[i + 1];

  float a0[8] = {}, a1[8] = {}, a2[8] = {}, a3[8] = {};
  int e = beg + half;
  for (; e + 6 < end; e += 8) {
    int s0 = col[e], s1 = col[e + 2], s2 = col[e + 4], s3 = col[e + 6];
    short8 v0 = *reinterpret_cast<const short8*>(z2b + (size_t)s0 * 256 + sl * 8);
    short8 v1 = *reinterpret_cast<const short8*>(z2b + (size_t)s1 * 256 + sl * 8);
    short8 v2 = *reinterpret_cast<const short8*>(z2b + (size_t)s2 * 256 + sl * 8);
    short8 v3 = *reinterpret_cast<const short8*>(z2b + (size_t)s3 * 256 + sl * 8);
#pragma unroll
    for (int j = 0; j < 8; ++j) {
      a0[j] += bh2f((u16)v0[j]);
      a1[j] += bh2f((u16)v1[j]);
      a2[j] += bh2f((u16)v2[j]);
      a3[j] += bh2f((u16)v3[j]);
    }
  }
  for (; e < end; e += 2) {
    int s = col[e];
    short8 v = *reinterpret_cast<const short8*>(z2b + (size_t)s * 256 + sl * 8);
#pragma unroll
    for (int j = 0; j < 8; ++j) a0[j] += bh2f((u16)v[j]);
  }
  float acc[8];
#pragma unroll
  for (int j = 0; j < 8; ++j) {
    acc[j] = a0[j] + a1[j] + a2[j] + a3[j];
    acc[j] += __shfl_xor(acc[j], 32);
  }
  float4 z1a = *reinterpret_cast<const float4*>(z1 + (size_t)i * 256 + sl * 8);
  float4 z1b = *reinterpret_cast<const float4*>(z1 + (size_t)i * 256 + sl * 8 + 4);
  float4 ca = *reinterpret_cast<const float4*>(c2 + sl * 8);
  float4 cb = *reinterpret_cast<const float4*>(c2 + sl * 8 + 4);
  float hv[8] = {z1a.x + ca.x + acc[0], z1a.y + ca.y + acc[1],
                 z1a.z + ca.z + acc[2], z1a.w + ca.w + acc[3],
                 z1b.x + cb.x + acc[4], z1b.y + cb.y + acc[5],
                 z1b.z + cb.z + acc[6], z1b.w + cb.w + acc[7]};
  if (half == 0) {
    float4 o0{hv[0], hv[1], hv[2], hv[3]};
    float4 o1{hv[4], hv[5], hv[6], hv[7]};
    *reinterpret_cast<float4*>(h + (size_t)i * 256 + sl * 8) = o0;
    *reinterpret_cast<float4*>(h + (size_t)i * 256 + sl * 8 + 4) = o1;
    short8 hb;
#pragma unroll
    for (int j = 0; j < 8; ++j) hb[j] = (short)f2bh(hv[j]);
    *reinterpret_cast<short8*>(h_bf + (size_t)i * 256 + sl * 8) = hb;
  }
}

// ===========================================================================
// GCN gather: out[i] = dis_i*sum dis_j h_j (bf16) + dis_i^2 h_i + b. 2 nodes/blk.
// ===========================================================================
__global__ __launch_bounds__(128) void gcn_gather_kernel(
    const float* __restrict__ h, const u16* __restrict__ h_bf,
    const int* __restrict__ row, const int* __restrict__ col,
    const float* __restrict__ dis, const float* __restrict__ gcn_b,
    float* __restrict__ outg) {
  int i = blockIdx.x * 2 + (threadIdx.x >> 6);
  int t = threadIdx.x & 63;
  int half = t >> 5, sl = t & 31;
  int beg = row[i], end = row[i + 1];
  float di = dis[i];

  float a0[8] = {}, a1[8] = {}, a2[8] = {}, a3[8] = {};
  int e = beg + half;
  for (; e + 6 < end; e += 8) {
    int s0 = col[e], s1 = col[e + 2], s2 = col[e + 4], s3 = col[e + 6];
    float w0 = dis[s0], w1 = dis[s1], w2 = dis[s2], w3 = dis[s3];
    short8 v0 = *reinterpret_cast<const short8*>(h_bf + (size_t)s0 * 256 + sl * 8);
    short8 v1 = *reinterpret_cast<const short8*>(h_bf + (size_t)s1 * 256 + sl * 8);
    short8 v2 = *reinterpret_cast<const short8*>(h_bf + (size_t)s2 * 256 + sl * 8);
    short8 v3 = *reinterpret_cast<const short8*>(h_bf + (size_t)s3 * 256 + sl * 8);
#pragma unroll
    for (int j = 0; j < 8; ++j) {
      a0[j] += w0 * bh2f((u16)v0[j]);
      a1[j] += w1 * bh2f((u16)v1[j]);
      a2[j] += w2 * bh2f((u16)v2[j]);
      a3[j] += w3 * bh2f((u16)v3[j]);
    }
  }
  for (; e < end; e += 2) {
    int s = col[e];
    float wv = dis[s];
    short8 v = *reinterpret_cast<const short8*>(h_bf + (size_t)s * 256 + sl * 8);
#pragma unroll
    for (int j = 0; j < 8; ++j) a0[j] += wv * bh2f((u16)v[j]);
  }
  float acc[8];
#pragma unroll
  for (int j = 0; j < 8; ++j) {
    acc[j] = a0[j] + a1[j] + a2[j] + a3[j];
    acc[j] += __shfl_xor(acc[j], 32);
  }
  if (half == 0) {
    float4 ha = *reinterpret_cast<const float4*>(h + (size_t)i * 256 + sl * 8);
    float4 hb = *reinterpret_cast<const float4*>(h + (size_t)i * 256 + sl * 8 + 4);
    float4 ba = *reinterpret_cast<const float4*>(gcn_b + sl * 8);
    float4 bb = *reinterpret_cast<const float4*>(gcn_b + sl * 8 + 4);
    float self = di * di;
    float4 o0{di * acc[0] + self * ha.x + ba.x, di * acc[1] + self * ha.y + ba.y,
              di * acc[2] + self * ha.z + ba.z, di * acc[3] + self * ha.w + ba.w};
    float4 o1{di * acc[4] + self * hb.x + bb.x, di * acc[5] + self * hb.y + bb.y,
              di * acc[6] + self * hb.z + bb.z, di * acc[7] + self * hb.w + bb.w};
    *reinterpret_cast<float4*>(outg + (size_t)i * 256 + sl * 8) = o0;
    *reinterpret_cast<float4*>(outg + (size_t)i * 256 + sl * 8 + 4) = o1;
  }
}

// ===========================================================================
// decode MLP: 8 nodes per block
// ===========================================================================
#define DEC_NODES 8
__global__ __launch_bounds__(128) void decode_kernel(
    const float* __restrict__ outg, const float* __restrict__ d1_W,
    const float* __restrict__ d1_b, const float* __restrict__ d2_W,
    const float* __restrict__ d2_b, float* __restrict__ z1) {
  __shared__ float rows[DEC_NODES][OUT_DIM];
  __shared__ float s0[128], s1[128];
  int t = threadIdx.x;
  int n0 = blockIdx.x * DEC_NODES;
#pragma unroll
  for (int j = 0; j < 4; ++j) {
    int idx = j * 512 + t * 4;
    *reinterpret_cast<float4*>(&rows[0][idx]) =
        *reinterpret_cast<const float4*>(outg + (size_t)n0 * OUT_DIM + idx);
  }
  __syncthreads();
  float acc[DEC_NODES];
  float b1 = d1_b[t];
#pragma unroll
  for (int n = 0; n < DEC_NODES; ++n) acc[n] = b1;
#pragma unroll 4
  for (int k = 0; k < OUT_DIM; ++k) {
    float wv = d1_W[k * 128 + t];
#pragma unroll
    for (int n = 0; n < DEC_NODES; ++n) acc[n] += rows[n][k] * wv;
  }
  float w0 = d2_W[t * 2 + 0], w1 = d2_W[t * 2 + 1];
  for (int n = 0; n < DEC_NODES; ++n) {
    float a = fmaxf(acc[n], 0.f);
    s0[t] = a * w0;
    s1[t] = a * w1;
    __syncthreads();
    for (int off = 64; off > 0; off >>= 1) {
      if (t < off) {
        s0[t] += s0[t + off];
        s1[t] += s1[t + off];
      }
      __syncthreads();
    }
    if (t == 0) {
      z1[(size_t)(n0 + n) * 2 + 0] = s0[0] + d2_b[0];
      z1[(size_t)(n0 + n) * 2 + 1] = s1[0] + d2_b[1];
    }
    __syncthreads();
  }
}

// ===========================================================================
extern "C" void kernel_launch(void* const* d_in, const int* in_sizes, int n_in,
                              void* d_out, int out_size, void* d_ws, size_t ws_size,
                              hipStream_t stream) {
  const float* x     = (const float*)d_in[0];
  const int*   edge  = (const int*)d_in[1];
  const float* f_W   = (const float*)d_in[2];
  const float* f_b   = (const float*)d_in[3];
  const float* gcn_W = (const float*)d_in[4];
  const float* gcn_b = (const float*)d_in[5];
  const float* d1_W  = (const float*)d_in[6];
  const float* d1_b  = (const float*)d_in[7];
  const float* d2_W  = (const float*)d_in[8];
  const float* d2_b  = (const float*)d_in[9];
  float* out = (float*)d_out;
  char*  wsb = (char*)d_ws;

  const int* src = edge;
  const int* dst = edge + E_EDGES;

  // -------- v8 layout (bytes) --------
  const size_t TS   = (size_t)MB_T * 16 * 256 * 8 * sizeof(u16);
  const size_t WTLE = (size_t)16 * 256 * 8 * sizeof(u16);

  size_t o = 0;
  u16*   x_hi = (u16*)(wsb + o); o += TS;
  u16*   x_lo = (u16*)(wsb + o); o += TS;
  float* z1   = (float*)(wsb + o); o += (size_t)N_NODES * 256 * 4;
  u16*   z2b  = (u16*)(wsb + o);   o += (size_t)N_NODES * 256 * 2;
  float* h    = (float*)(wsb + o); o += (size_t)N_NODES * 256 * 4;
  u16*   h_bf = (u16*)(wsb + o);   o += (size_t)N_NODES * 256 * 2;
  float* dis8 = (float*)(wsb + o); o += (size_t)N_NODES * 4;
  int*   icnt8 = (int*)(wsb + o);  o += (size_t)N_NODES * 4;
  float* c2   = (float*)(wsb + o); o += OUT_DIM * 4;   // adjacent to icnt8: one memset
  int*   irow8 = (int*)(wsb + o);  o += (size_t)(N_NODES + 1) * 4 + 12;
  int*   icol8 = (int*)(wsb + o);  o += (size_t)E_EDGES * 4;
  u16*   Wcomb_hi = (u16*)(wsb + o); o += 8 * WTLE;
  u16*   Wcomb_lo = (u16*)(wsb + o); o += 8 * WTLE;
  u16*   WbotT_hi = (u16*)(wsb + o); o += 4 * WTLE;
  u16*   WbotT_lo = (u16*)(wsb + o); o += 4 * WTLE;
  u16*   fWp_hi   = (u16*)(wsb + o); o += 8 * WTLE;
  u16*   fWp_lo   = (u16*)(wsb + o); o += 8 * WTLE;
  float* outg = (float*)(wsb + 0);  // overlays x_hi (dead after Z-GEMM)
  const size_t v8_needed = o;

  if (ws_size >= v8_needed) {
    // ---- memset covers icnt8 + c2 (contiguous)
    hipMemsetAsync(icnt8, 0, (size_t)N_NODES * sizeof(int) + OUT_DIM * sizeof(float), stream);

    // ---- fused prep (pack x, pack f_W, convT, c2, CSR count)
    prep_kernel<<<PREP_TOTAL, 256, 0, stream>>>(
        x, f_W, gcn_W, f_b, dst, icnt8, x_hi, x_lo, fWp_hi, fWp_lo,
        Wcomb_hi, Wcomb_lo, WbotT_hi, WbotT_lo, c2);

    // ---- scan (shfl-based, 2 barriers)
    scan_kernel<<<1, 1024, 0, stream>>>(icnt8, irow8, dis8);

    // ---- fused place + W2 register GEMM
    pw_kernel<<<PW_TOTAL, 256, 0, stream>>>(
        src, dst, icnt8, icol8, WbotT_hi, WbotT_lo, fWp_hi, fWp_lo,
        Wcomb_hi, Wcomb_lo);

    // ---- Z = x @ [Wtop | W2] : z1 fp32, z2 bf16  (XCD-remapped)
    zgemm_kernel<2><<<640, 256, 0, stream>>>(
        x_hi, x_lo, Wcomb_hi, Wcomb_lo, z1, z2b, N_NODES, IN_DIM);

    // ---- h = z1 + gather(z2) + c2 (fp32 + bf16 shadow)
    h_build_kernel<<<N_NODES / 2, 128, 0, stream>>>(z1, z2b, irow8, icol8, c2, h, h_bf);

    // ---- GCN gather + decode
    gcn_gather_kernel<<<N_NODES / 2, 128, 0, stream>>>(h, h_bf, irow8, icol8, dis8, gcn_b, outg);
    decode_kernel<<<N_NODES / DEC_NODES, 128, 0, stream>>>(outg, d1_W, d1_b, d2_W, d2_b, out);
  }
}